// Round 1
// baseline (3032.958 us; speedup 1.0000x reference)
//
#include <hip/hip_runtime.h>
#include <math.h>

// Problem constants
// B=4 S=1024 DM=256 H=8 HD=32 CIN=23 E=16 D2=512 HE=1365 2HE=2730 CAP=128
#define NTOK 4096      // B*S
#define NSLOT 8192     // E*B*CAP
#define CAPN 128

__device__ __forceinline__ float gelu_f(float x){
  return 0.5f*x*(1.0f+erff(x*0.7071067811865476f));
}

// ---------------- topo: gelu(cat([K,Q],axis=1) @ w_topo + b_topo) -> keys, queries
__global__ __launch_bounds__(256) void topo_kernel(
    const float* __restrict__ K, const float* __restrict__ Q,
    const float* __restrict__ w, const float* __restrict__ b,
    float* __restrict__ keys, float* __restrict__ queries)
{
  int idx = blockIdx.x*256 + threadIdx.x;   // 2*4*1024*256 = 2097152
  int d = idx & 255;
  int r = idx >> 8;          // 0..8191
  int bb = r >> 11;          // batch
  int n  = r & 2047;
  const float* src = (n < 1024) ? (K + ((bb<<10) + n)*3)
                                : (Q + ((bb<<10) + (n-1024))*3);
  float v = b[d] + src[0]*w[d] + src[1]*w[256+d] + src[2]*w[512+d];
  v = gelu_f(v);
  float* dst = (n < 1024) ? keys : queries;
  dst[(((bb<<10) + (n & 1023))<<8) + d] = v;
}

// ---------------- values: gelu(V @ w_val + b_val)
__global__ __launch_bounds__(256) void values_kernel(
    const float* __restrict__ V, const float* __restrict__ w,
    const float* __restrict__ b, float* __restrict__ out)
{
  int idx = blockIdx.x*256 + threadIdx.x;  // 1048576
  int d = idx & 255; int r = idx >> 8;
  const float* src = V + r*23;
  float acc = b[d];
  #pragma unroll
  for (int c=0;c<23;c++) acc += src[c]*w[c*256+d];
  out[idx] = gelu_f(acc);
}

// ---------------- generic tiled GEMM: C = act(A@W + bias) (+ R), batched over z
// A: M x K (lda), W: K x N (ldw) row-major. act: 0 none, 1 gelu, 2 leaky_relu(0.01)
__global__ __launch_bounds__(256) void gemm_kernel(
    const float* __restrict__ A, int lda, long sA,
    const float* __restrict__ W, int ldw, long sW,
    const float* __restrict__ bias, long sB,
    const float* __restrict__ R, int ldr, long sR,
    float* __restrict__ C, int ldc, long sC,
    int M, int N, int K, int act)
{
  int z = blockIdx.z;
  A += (long)z*sA; W += (long)z*sW; C += (long)z*sC;
  if (bias) bias += (long)z*sB;
  if (R)    R    += (long)z*sR;

  __shared__ float As[16][68];   // [k][m], row stride 68 floats (16B-aligned rows)
  __shared__ float Ws[16][68];   // [k][n]
  int tid = threadIdx.x;
  int bm = blockIdx.y*64, bn = blockIdx.x*64;
  int tm = (tid >> 4) << 2;      // 0..60
  int tn = (tid & 15) << 2;      // 0..60
  float acc[4][4] = {};

  for (int k0 = 0; k0 < K; k0 += 16){
    #pragma unroll
    for (int i=0;i<4;i++){
      int e = tid + i*256;
      int m = e >> 4, k = e & 15;
      int gm = bm + m, gk = k0 + k;
      As[k][m] = (gm < M && gk < K) ? A[(long)gm*lda + gk] : 0.f;
    }
    #pragma unroll
    for (int i=0;i<4;i++){
      int e = tid + i*256;
      int k = e >> 6, n = e & 63;
      int gk = k0 + k, gn = bn + n;
      Ws[k][n] = (gk < K && gn < N) ? W[(long)gk*ldw + gn] : 0.f;
    }
    __syncthreads();
    #pragma unroll
    for (int kk=0;kk<16;kk++){
      float a0=As[kk][tm+0], a1=As[kk][tm+1], a2=As[kk][tm+2], a3=As[kk][tm+3];
      float w0=Ws[kk][tn+0], w1=Ws[kk][tn+1], w2=Ws[kk][tn+2], w3=Ws[kk][tn+3];
      acc[0][0]+=a0*w0; acc[0][1]+=a0*w1; acc[0][2]+=a0*w2; acc[0][3]+=a0*w3;
      acc[1][0]+=a1*w0; acc[1][1]+=a1*w1; acc[1][2]+=a1*w2; acc[1][3]+=a1*w3;
      acc[2][0]+=a2*w0; acc[2][1]+=a2*w1; acc[2][2]+=a2*w2; acc[2][3]+=a2*w3;
      acc[3][0]+=a3*w0; acc[3][1]+=a3*w1; acc[3][2]+=a3*w2; acc[3][3]+=a3*w3;
    }
    __syncthreads();
  }
  #pragma unroll
  for (int i=0;i<4;i++){
    int gm = bm + tm + i;
    if (gm >= M) continue;
    #pragma unroll
    for (int j=0;j<4;j++){
      int gn = bn + tn + j;
      if (gn >= N) continue;
      float v = acc[i][j];
      if (bias) v += bias[gn];
      if (act == 1) v = gelu_f(v);
      else if (act == 2) v = (v > 0.f) ? v : 0.01f*v;
      if (R) v += R[(long)gm*ldr + gn];
      C[(long)gm*ldc + gn] = v;
    }
  }
}

// ---------------- attention: flash-style online softmax, one q-row per thread
__global__ __launch_bounds__(256) void attn_kernel(
    const float* __restrict__ qp, const float* __restrict__ kp,
    const float* __restrict__ vp, float* __restrict__ out)
{
  int bh = blockIdx.y; int bb = bh >> 3; int h = bh & 7;
  int qi = blockIdx.x*256 + threadIdx.x;      // 0..1023
  const float scale = 0.17677669529663687f;   // 1/sqrt(32)
  float qreg[32];
  const float* qptr = qp + (((bb<<10)+qi)<<8) + (h<<5);
  #pragma unroll
  for (int d=0;d<32;d++) qreg[d] = qptr[d];
  float m = -INFINITY, l = 0.f;
  float oacc[32];
  #pragma unroll
  for (int d=0;d<32;d++) oacc[d] = 0.f;

  __shared__ float Ks[64][32];
  __shared__ float Vs[64][32];
  for (int j0=0; j0<1024; j0+=64){
    __syncthreads();
    #pragma unroll
    for (int i=0;i<8;i++){
      int e = threadIdx.x + i*256;
      int j = e >> 5, d = e & 31;
      int base = (((bb<<10)+j0+j)<<8) + (h<<5) + d;
      Ks[j][d] = kp[base];
      Vs[j][d] = vp[base];
    }
    __syncthreads();
    for (int j=0;j<64;j++){
      float s = 0.f;
      #pragma unroll
      for (int d=0;d<32;d++) s += qreg[d]*Ks[j][d];
      s *= scale;
      if (s > m){
        float corr = expf(m - s);
        l = l*corr + 1.f;
        #pragma unroll
        for (int d=0;d<32;d++) oacc[d] = oacc[d]*corr + Vs[j][d];
        m = s;
      } else {
        float p = expf(s - m);
        l += p;
        #pragma unroll
        for (int d=0;d<32;d++) oacc[d] += p*Vs[j][d];
      }
    }
  }
  float inv = 1.f / l;
  float* optr = out + (((bb<<10)+qi)<<8) + (h<<5);
  #pragma unroll
  for (int d=0;d<32;d++) optr[d] = oacc[d]*inv;
}

// ---------------- concat queries into x[:, 256:512]
__global__ __launch_bounds__(256) void concat_kernel(
    const float* __restrict__ queries, float* __restrict__ x)
{
  int idx = blockIdx.x*256 + threadIdx.x;  // 1048576
  int d = idx & 255; int r = idx >> 8;
  x[(r<<9) + 256 + d] = queries[idx];
}

// ---------------- rmsnorm over D=512: y = x / max(||x||,1e-12) * sqrt(512) * g
__global__ __launch_bounds__(256) void rmsnorm_kernel(
    const float* __restrict__ x, const float* __restrict__ g, float* __restrict__ y)
{
  int r = blockIdx.x; int tid = threadIdx.x;
  float v0 = x[(r<<9) + tid];
  float v1 = x[(r<<9) + 256 + tid];
  float ss = v0*v0 + v1*v1;
  #pragma unroll
  for (int off=32; off>0; off>>=1) ss += __shfl_down(ss, off, 64);
  __shared__ float wsum[4];
  if ((tid & 63) == 0) wsum[tid>>6] = ss;
  __syncthreads();
  float tot = wsum[0]+wsum[1]+wsum[2]+wsum[3];
  float scale = 22.62741699796952f / fmaxf(sqrtf(tot), 1e-12f);  // sqrt(512)
  y[(r<<9) + tid]       = v0*scale*g[tid];
  y[(r<<9) + 256 + tid] = v1*scale*g[256+tid];
}

// ---------------- geglu gate: t = gelu(h[:,1365:]) * h[:,:1365] * mult
__global__ __launch_bounds__(256) void glu_kernel(
    const float* __restrict__ h, const float* __restrict__ mult, float* __restrict__ t)
{
  int idx = blockIdx.x*256 + threadIdx.x;  // 4096*1365
  int r = idx / 1365; int j = idx - r*1365;
  float a = h[(long)r*2730 + j];
  float gt = h[(long)r*2730 + 1365 + j];
  t[idx] = gelu_f(gt) * a * mult[j];
}

// ---------------- MoE init
__global__ __launch_bounds__(256) void moe_init_kernel(
    int* ts1, int* ts2, int* slot_token, float* sum_raw, float* z_sum)
{
  int i = blockIdx.x*256 + threadIdx.x;
  if (i < 4096){ ts1[i] = -1; ts2[i] = -1; }
  if (i < 8192) slot_token[i] = -1;
  if (i < 64)  sum_raw[i] = 0.f;
  if (i == 0)  *z_sum = 0.f;
}

// ---------------- gating: logits, softmax, top-2, z-loss
__global__ __launch_bounds__(256) void gating_kernel(
    const float* __restrict__ xn, const float* __restrict__ gate_w,
    int* __restrict__ idx1, int* __restrict__ idx2, int* __restrict__ route,
    float* __restrict__ gg1, float* __restrict__ gg2,
    float* __restrict__ sum_raw, float* __restrict__ z_sum)
{
  int t = blockIdx.x; int tid = threadIdx.x;
  __shared__ float xrow[512];
  xrow[tid]     = xn[(t<<9)+tid];
  xrow[256+tid] = xn[(t<<9)+256+tid];
  __syncthreads();
  int e = tid >> 4, l16 = tid & 15;
  float p = 0.f;
  for (int d=l16; d<512; d+=16) p += xrow[d]*gate_w[(e<<9)+d];
  __shared__ float part[16][17];
  part[e][l16] = p;
  __syncthreads();
  __shared__ float raw[16];
  if (tid < 16){
    float s = 0.f;
    #pragma unroll
    for (int i=0;i<16;i++) s += part[tid][i];
    raw[tid] = s;  // logits for now
  }
  __syncthreads();
  if (tid == 0){
    float mx = -1e30f;
    #pragma unroll
    for (int i=0;i<16;i++) mx = fmaxf(mx, raw[i]);
    float r[16]; float sum = 0.f;
    #pragma unroll
    for (int i=0;i<16;i++){ r[i] = expf(raw[i]-mx); sum += r[i]; }
    float lse = mx + logf(sum);
    atomicAdd(z_sum, lse*lse);
    float inv = 1.f/sum;
    #pragma unroll
    for (int i=0;i<16;i++){ r[i] *= inv; raw[i] = r[i]; }
    int i1 = -1; float b1 = -1.f;
    #pragma unroll
    for (int i=0;i<16;i++) if (r[i] > b1){ b1 = r[i]; i1 = i; }
    int i2 = -1; float b2 = -1.f;
    #pragma unroll
    for (int i=0;i<16;i++) if (i != i1 && r[i] > b2){ b2 = r[i]; i2 = i; }
    float s2 = fmaxf(b1 + b2, 1e-9f);
    float g1n = b1/s2, g2n = b2/s2;
    idx1[t] = i1; idx2[t] = i2;
    route[t] = (g2n > 0.2f) ? 1 : 0;
    gg1[t] = g1n; gg2[t] = g2n;
  }
  __syncthreads();
  int bb = t >> 10;
  if (tid < 16) atomicAdd(&sum_raw[(bb<<4)+tid], raw[tid]);
}

// ---------------- capacity scan (matches reference cumsum semantics)
__global__ void scan_kernel(
    const int* __restrict__ idx1, const int* __restrict__ idx2, const int* __restrict__ route,
    int* __restrict__ ts1, int* __restrict__ ts2, int* __restrict__ slot_token,
    int* __restrict__ count1)
{
  int bb = blockIdx.x; int e = threadIdx.x;
  if (e >= 16) return;
  int cnt = 0;
  for (int n=0;n<1024;n++){
    int t = (bb<<10)+n;
    if (idx1[t] == e){
      if (cnt < CAPN){ int slot = ((e<<2)+bb)*CAPN + cnt; ts1[t] = slot; slot_token[slot] = t; }
      else ts1[t] = -1;
      cnt++;
    }
  }
  count1[(bb<<4)+e] = cnt;
  int c2 = cnt;   // choice-2 slots start at UNCAPPED total choice-1 count
  for (int n=0;n<1024;n++){
    int t = (bb<<10)+n;
    if (idx2[t] == e && route[t]){
      if (c2 < CAPN){ int slot = ((e<<2)+bb)*CAPN + c2; ts2[t] = slot; slot_token[slot] = t; }
      c2++;
    }
  }
}

// ---------------- gather + per-expert layernorm -> xin_ln[slot, 512]
__global__ __launch_bounds__(256) void gather_ln_kernel(
    const float* __restrict__ xn, const int* __restrict__ slot_token,
    const float* __restrict__ ln_g, const float* __restrict__ ln_b,
    float* __restrict__ xin)
{
  int s = blockIdx.x; int tid = threadIdx.x;
  int t = slot_token[s];
  int e = s >> 9;   // B*CAP = 512 slots per expert
  if (t < 0){
    xin[(s<<9)+tid] = 0.f;
    xin[(s<<9)+256+tid] = 0.f;
    return;
  }
  float v0 = xn[(t<<9)+tid];
  float v1 = xn[(t<<9)+256+tid];
  float sm = v0+v1, sq = v0*v0+v1*v1;
  #pragma unroll
  for (int off=32; off>0; off>>=1){
    sm += __shfl_down(sm, off, 64);
    sq += __shfl_down(sq, off, 64);
  }
  __shared__ float s1[4], s2buf[4];
  if ((tid & 63) == 0){ s1[tid>>6] = sm; s2buf[tid>>6] = sq; }
  __syncthreads();
  float tsm = s1[0]+s1[1]+s1[2]+s1[3];
  float tsq = s2buf[0]+s2buf[1]+s2buf[2]+s2buf[3];
  float mean = tsm * (1.f/512.f);
  float var = tsq * (1.f/512.f) - mean*mean;
  float rstd = rsqrtf(var + 1e-5f);
  xin[(s<<9)+tid]     = (v0-mean)*rstd*ln_g[(e<<9)+tid]     + ln_b[(e<<9)+tid];
  xin[(s<<9)+256+tid] = (v1-mean)*rstd*ln_g[(e<<9)+256+tid] + ln_b[(e<<9)+256+tid];
}

// ---------------- combine: xout = xres + g1*h2[slot1] + g2*h2[slot2]
__global__ __launch_bounds__(256) void combine_kernel(
    const float* __restrict__ xres, const float* __restrict__ h2,
    const int* __restrict__ ts1, const int* __restrict__ ts2,
    const float* __restrict__ gg1, const float* __restrict__ gg2,
    float* __restrict__ xout)
{
  int idx = blockIdx.x*256 + threadIdx.x;  // 4096*512
  int t = idx >> 9; int d = idx & 511;
  float v = xres[idx];
  int s1 = ts1[t]; if (s1 >= 0) v += gg1[t]*h2[(s1<<9)+d];
  int s2 = ts2[t]; if (s2 >= 0) v += gg2[t]*h2[(s2<<9)+d];
  xout[idx] = v;
}

// ---------------- aux losses
__global__ void aux_kernel(
    const float* __restrict__ sum_raw, const int* __restrict__ count1,
    const float* __restrict__ z_sum, float* __restrict__ out)
{
  int tid = threadIdx.x;  // 64 threads = (b,e) pairs
  float v = (sum_raw[tid] * (1.f/1024.f)) * ((float)count1[tid] * (1.f/1024.f));
  #pragma unroll
  for (int off=32; off>0; off>>=1) v += __shfl_down(v, off, 64);
  if (tid == 0){
    float bal = v * (1.f/64.f) * 256.f * 0.01f;
    float zl = (*z_sum) * (1.f/4096.f) * 0.001f;
    out[0] = bal + zl;
    out[1] = bal;
    out[2] = zl;
  }
}

// ---------------- host
static void launch_gemm(hipStream_t st,
    const float* A, int lda, long sA,
    const float* W, int ldw, long sW,
    const float* bias, long sB,
    const float* R, int ldr, long sR,
    float* C, int ldc, long sC,
    int M, int N, int K, int act, int Z)
{
  dim3 g((N+63)/64, (M+63)/64, Z);
  gemm_kernel<<<g, 256, 0, st>>>(A,lda,sA, W,ldw,sW, bias,sB, R,ldr,sR, C,ldc,sC, M,N,K,act);
}

extern "C" void kernel_launch(void* const* d_in, const int* in_sizes, int n_in,
                              void* d_out, int out_size, void* d_ws, size_t ws_size,
                              hipStream_t stream)
{
  const float* K_in   = (const float*)d_in[0];
  const float* V_in   = (const float*)d_in[1];
  const float* Q_in   = (const float*)d_in[2];
  const float* w_topo = (const float*)d_in[3];
  const float* b_topo = (const float*)d_in[4];
  const float* w_val  = (const float*)d_in[5];
  const float* b_val  = (const float*)d_in[6];
  const float* wq     = (const float*)d_in[7];
  const float* bq     = (const float*)d_in[8];
  const float* wk     = (const float*)d_in[9];
  const float* bk     = (const float*)d_in[10];
  const float* wv     = (const float*)d_in[11];
  const float* bv     = (const float*)d_in[12];
  const float* wo     = (const float*)d_in[13];
  const float* bo     = (const float*)d_in[14];
  const float* ffb_g  = (const float*)d_in[15];
  const float* ffb_w1 = (const float*)d_in[16];
  const float* ffb_b1 = (const float*)d_in[17];
  const float* ffb_mult=(const float*)d_in[18];
  const float* ffb_w2 = (const float*)d_in[19];
  const float* ffb_b2 = (const float*)d_in[20];
  const float* prenorm_g=(const float*)d_in[21];
  const float* gate_w = (const float*)d_in[22];
  const float* exp_ln_g=(const float*)d_in[23];
  const float* exp_ln_b=(const float*)d_in[24];
  const float* exp_w1 = (const float*)d_in[25];
  const float* exp_b1 = (const float*)d_in[26];
  const float* exp_w2 = (const float*)d_in[27];
  const float* exp_b2 = (const float*)d_in[28];
  const float* ffa_g  = (const float*)d_in[29];
  const float* ffa_w1 = (const float*)d_in[30];
  const float* ffa_b1 = (const float*)d_in[31];
  const float* ffa_mult=(const float*)d_in[32];
  const float* ffa_w2 = (const float*)d_in[33];
  const float* ffa_b2 = (const float*)d_in[34];
  const float* w_out  = (const float*)d_in[35];
  const float* b_out  = (const float*)d_in[36];
  float* dout = (float*)d_out;

  float* wsf = (float*)d_ws;
  int*   wsi = (int*)d_ws;

  // workspace layout (floats). Early buffers overlap the big h buffer (dead by then).
  const size_t F_Q  = 0;          // queries 1048576
  const size_t F_K  = 1048576;    // keys
  const size_t F_V  = 2097152;    // values
  const size_t F_QP = 3145728;
  const size_t F_KP = 4194304;
  const size_t F_VP = 5242880;
  const size_t F_AO = 6291456;
  const size_t F_H  = 0;          // 11182080 floats (4096*2730 == 8192*1365)
  const size_t F_T  = 11182080;   // 5591040 (t / xin_ln / h2)
  const size_t F_XA = 16773120;   // 2097152
  const size_t F_XB = 18870272;   // 2097152
  const size_t F_Y  = 20967424;   // 2097152 (rmsnorm out / x_norm)
  const size_t I_M  = 23064576;   // misc region

  int* idx1 = wsi + I_M + 0;
  int* idx2 = wsi + I_M + 4096;
  int* route= wsi + I_M + 8192;
  int* ts1  = wsi + I_M + 12288;
  int* ts2  = wsi + I_M + 16384;
  int* slot_token = wsi + I_M + 20480;   // 8192
  int* count1     = wsi + I_M + 28672;   // 64
  float* sum_raw  = wsf + I_M + 28736;   // 64
  float* z_sum    = wsf + I_M + 28800;   // 1
  float* gg1      = wsf + I_M + 28864;   // 4096
  float* gg2      = wsf + I_M + 32960;   // 4096

  // 1. topo -> keys, queries ; values
  topo_kernel<<<8192, 256, 0, stream>>>(K_in, Q_in, w_topo, b_topo, wsf+F_K, wsf+F_Q);
  values_kernel<<<4096, 256, 0, stream>>>(V_in, w_val, b_val, wsf+F_V);

  // 2. QKV projections
  launch_gemm(stream, wsf+F_Q,256,0, wq,256,0, bq,0, nullptr,0,0, wsf+F_QP,256,0, 4096,256,256, 0, 1);
  launch_gemm(stream, wsf+F_K,256,0, wk,256,0, bk,0, nullptr,0,0, wsf+F_KP,256,0, 4096,256,256, 0, 1);
  launch_gemm(stream, wsf+F_V,256,0, wv,256,0, bv,0, nullptr,0,0, wsf+F_VP,256,0, 4096,256,256, 0, 1);

  // 3. attention
  attn_kernel<<<dim3(4,32), 256, 0, stream>>>(wsf+F_QP, wsf+F_KP, wsf+F_VP, wsf+F_AO);

  // 4. o-proj into x[:, :256], concat queries into x[:, 256:]
  launch_gemm(stream, wsf+F_AO,256,0, wo,256,0, bo,0, nullptr,0,0, wsf+F_XA,512,0, 4096,256,256, 0, 1);
  concat_kernel<<<4096, 256, 0, stream>>>(wsf+F_Q, wsf+F_XA);

  // 5. ffb geglu: XB = glu(rms(XA)@w1+b1)@w2 + b2 + XA
  rmsnorm_kernel<<<4096, 256, 0, stream>>>(wsf+F_XA, ffb_g, wsf+F_Y);
  launch_gemm(stream, wsf+F_Y,512,0, ffb_w1,2730,0, ffb_b1,0, nullptr,0,0, wsf+F_H,2730,0, 4096,2730,512, 0, 1);
  glu_kernel<<<21840, 256, 0, stream>>>(wsf+F_H, ffb_mult, wsf+F_T);
  launch_gemm(stream, wsf+F_T,1365,0, ffb_w2,512,0, ffb_b2,0, wsf+F_XA,512,0, wsf+F_XB,512,0, 4096,512,1365, 0, 1);

  // 6. MoE
  rmsnorm_kernel<<<4096, 256, 0, stream>>>(wsf+F_XB, prenorm_g, wsf+F_Y);
  moe_init_kernel<<<32, 256, 0, stream>>>(ts1, ts2, slot_token, sum_raw, z_sum);
  gating_kernel<<<4096, 256, 0, stream>>>(wsf+F_Y, gate_w, idx1, idx2, route, gg1, gg2, sum_raw, z_sum);
  scan_kernel<<<4, 64, 0, stream>>>(idx1, idx2, route, ts1, ts2, slot_token, count1);
  gather_ln_kernel<<<8192, 256, 0, stream>>>(wsf+F_Y, slot_token, exp_ln_g, exp_ln_b, wsf+F_T);
  // expert GEMM1: leaky_relu(xin @ w1[e] + b1[e])  (h1 in F_H)
  launch_gemm(stream, wsf+F_T,512,(long)512*512, exp_w1,1365,(long)512*1365, exp_b1,1365,
              nullptr,0,0, wsf+F_H,1365,(long)512*1365, 512,1365,512, 2, 16);
  // expert GEMM2: h1 @ w2[e] + b2[e]  (h2 overwrites F_T; xin dead)
  launch_gemm(stream, wsf+F_H,1365,(long)512*1365, exp_w2,512,(long)1365*512, exp_b2,512,
              nullptr,0,0, wsf+F_T,512,(long)512*512, 512,512,1365, 0, 16);
  combine_kernel<<<8192, 256, 0, stream>>>(wsf+F_XB, wsf+F_T, ts1, ts2, gg1, gg2, wsf+F_XA);
  aux_kernel<<<1, 64, 0, stream>>>(sum_raw, count1, z_sum, dout + 4096*256);

  // 7. ffa geglu: XB = glu(rms(XA)@w1+b1)@w2 + b2 + XA
  rmsnorm_kernel<<<4096, 256, 0, stream>>>(wsf+F_XA, ffa_g, wsf+F_Y);
  launch_gemm(stream, wsf+F_Y,512,0, ffa_w1,2730,0, ffa_b1,0, nullptr,0,0, wsf+F_H,2730,0, 4096,2730,512, 0, 1);
  glu_kernel<<<21840, 256, 0, stream>>>(wsf+F_H, ffa_mult, wsf+F_T);
  launch_gemm(stream, wsf+F_T,1365,0, ffa_w2,512,0, ffa_b2,0, wsf+F_XA,512,0, wsf+F_XB,512,0, 4096,512,1365, 0, 1);

  // 8. out = gelu(XB @ w_out + b_out)
  launch_gemm(stream, wsf+F_XB,512,0, w_out,256,0, b_out,0, nullptr,0,0, dout,256,0, 4096,256,512, 1, 1);
}

// Round 2
// 1838.144 us; speedup vs baseline: 1.6500x; 1.6500x over previous
//
#include <hip/hip_runtime.h>
#include <hip/hip_bf16.h>
#include <math.h>

// B=4 S=1024 DM=256 H=8 HD=32 CIN=23 E=16 D2=512 HE=1365 2HE=2730 CAP=128
#define CAPN 128

typedef short short8 __attribute__((ext_vector_type(8)));
typedef float f32x4 __attribute__((ext_vector_type(4)));

__device__ __forceinline__ float gelu_f(float x){
  return 0.5f*x*(1.0f+erff(x*0.7071067811865476f));
}

// ---------------- topo
__global__ __launch_bounds__(256) void topo_kernel(
    const float* __restrict__ K, const float* __restrict__ Q,
    const float* __restrict__ w, const float* __restrict__ b,
    float* __restrict__ keys, float* __restrict__ queries)
{
  int idx = blockIdx.x*256 + threadIdx.x;
  int d = idx & 255;
  int r = idx >> 8;
  int bb = r >> 11;
  int n  = r & 2047;
  const float* src = (n < 1024) ? (K + ((bb<<10) + n)*3)
                                : (Q + ((bb<<10) + (n-1024))*3);
  float v = b[d] + src[0]*w[d] + src[1]*w[256+d] + src[2]*w[512+d];
  v = gelu_f(v);
  float* dst = (n < 1024) ? keys : queries;
  dst[(((bb<<10) + (n & 1023))<<8) + d] = v;
}

// ---------------- values
__global__ __launch_bounds__(256) void values_kernel(
    const float* __restrict__ V, const float* __restrict__ w,
    const float* __restrict__ b, float* __restrict__ out)
{
  int idx = blockIdx.x*256 + threadIdx.x;
  int d = idx & 255; int r = idx >> 8;
  const float* src = V + r*23;
  float acc = b[d];
  #pragma unroll
  for (int c=0;c<23;c++) acc += src[c]*w[c*256+d];
  out[idx] = gelu_f(acc);
}

// ---------------- fp32 tiled GEMM (64x64, 4x4 microtile)
__global__ __launch_bounds__(256) void gemm_kernel(
    const float* __restrict__ A, int lda, long sA,
    const float* __restrict__ W, int ldw, long sW,
    const float* __restrict__ bias, long sB,
    const float* __restrict__ R, int ldr, long sR,
    float* __restrict__ C, int ldc, long sC,
    int M, int N, int K, int act)
{
  int z = blockIdx.z;
  A += (long)z*sA; W += (long)z*sW; C += (long)z*sC;
  if (bias) bias += (long)z*sB;
  if (R)    R    += (long)z*sR;

  __shared__ float As[16][68];
  __shared__ float Ws[16][68];
  int tid = threadIdx.x;
  int bm = blockIdx.y*64, bn = blockIdx.x*64;
  int tm = (tid >> 4) << 2;
  int tn = (tid & 15) << 2;
  float acc[4][4] = {};

  for (int k0 = 0; k0 < K; k0 += 16){
    #pragma unroll
    for (int i=0;i<4;i++){
      int e = tid + i*256;
      int m = e >> 4, k = e & 15;
      int gm = bm + m, gk = k0 + k;
      As[k][m] = (gm < M && gk < K) ? A[(long)gm*lda + gk] : 0.f;
    }
    #pragma unroll
    for (int i=0;i<4;i++){
      int e = tid + i*256;
      int k = e >> 6, n = e & 63;
      int gk = k0 + k, gn = bn + n;
      Ws[k][n] = (gk < K && gn < N) ? W[(long)gk*ldw + gn] : 0.f;
    }
    __syncthreads();
    #pragma unroll
    for (int kk=0;kk<16;kk++){
      float a0=As[kk][tm+0], a1=As[kk][tm+1], a2=As[kk][tm+2], a3=As[kk][tm+3];
      float w0=Ws[kk][tn+0], w1=Ws[kk][tn+1], w2=Ws[kk][tn+2], w3=Ws[kk][tn+3];
      acc[0][0]+=a0*w0; acc[0][1]+=a0*w1; acc[0][2]+=a0*w2; acc[0][3]+=a0*w3;
      acc[1][0]+=a1*w0; acc[1][1]+=a1*w1; acc[1][2]+=a1*w2; acc[1][3]+=a1*w3;
      acc[2][0]+=a2*w0; acc[2][1]+=a2*w1; acc[2][2]+=a2*w2; acc[2][3]+=a2*w3;
      acc[3][0]+=a3*w0; acc[3][1]+=a3*w1; acc[3][2]+=a3*w2; acc[3][3]+=a3*w3;
    }
    __syncthreads();
  }
  #pragma unroll
  for (int i=0;i<4;i++){
    int gm = bm + tm + i;
    if (gm >= M) continue;
    #pragma unroll
    for (int j=0;j<4;j++){
      int gn = bn + tn + j;
      if (gn >= N) continue;
      float v = acc[i][j];
      if (bias) v += bias[gn];
      if (act == 1) v = gelu_f(v);
      else if (act == 2) v = (v > 0.f) ? v : 0.01f*v;
      if (R) v += R[(long)gm*ldr + gn];
      C[(long)gm*ldc + gn] = v;
    }
  }
}

// ---------------- bf16 MFMA GEMM: 128x128 tile, BK=32, 256 thr (2x2 waves, 64x64/wave)
// A: [M][lda] bf16 row-major, WT: [N][ldw] bf16 (pre-transposed weights).
// M,N multiples of 128; K multiple of 32. Epilogue: bias (with optional split
// remap for padded-geglu layout), leaky_relu, residual add, fp32 or bf16 out.
#define LP 56   // LDS row stride in bf16 (112B: 16B aligned, 28-bank step -> 2-way only)
__global__ __launch_bounds__(256) void bgemm_kernel(
    const __hip_bfloat16* __restrict__ A, int lda, long sA,
    const __hip_bfloat16* __restrict__ WT, int ldw, long sW,
    const float* __restrict__ bias, int nbias, int bsplit, int bsplitPad, long sB,
    const float* __restrict__ R, int ldr, long sR,
    void* __restrict__ C, int ldc, long sC, int cIsBf16,
    int K, int act)
{
  int z = blockIdx.z;
  const short* Ab = (const short*)A + (long)z*sA;
  const short* Bb = (const short*)WT + (long)z*sW;
  int bm = blockIdx.y*128, bn = blockIdx.x*128;
  int tid = threadIdx.x, lane = tid & 63, wave = tid >> 6;
  int wm = (wave & 1)*64, wn = (wave >> 1)*64;

  __shared__ short As[128*LP];
  __shared__ short Bs[128*LP];

  f32x4 acc[4][4];
  f32x4 zero4 = {0.f,0.f,0.f,0.f};
  #pragma unroll
  for (int i=0;i<4;i++)
    #pragma unroll
    for (int j=0;j<4;j++) acc[i][j] = zero4;

  int g0 = tid, g1 = tid + 256;
  int r0 = g0 >> 2, c0 = (g0 & 3) * 8;
  int r1 = g1 >> 2, c1 = (g1 & 3) * 8;
  int ml = lane & 15, q = lane >> 4;

  for (int k0 = 0; k0 < K; k0 += 32){
    short8 av0 = *(const short8*)&Ab[(long)(bm+r0)*lda + k0 + c0];
    short8 av1 = *(const short8*)&Ab[(long)(bm+r1)*lda + k0 + c1];
    short8 bv0 = *(const short8*)&Bb[(long)(bn+r0)*ldw + k0 + c0];
    short8 bv1 = *(const short8*)&Bb[(long)(bn+r1)*ldw + k0 + c1];
    __syncthreads();
    *(short8*)&As[r0*LP + c0] = av0;
    *(short8*)&As[r1*LP + c1] = av1;
    *(short8*)&Bs[r0*LP + c0] = bv0;
    *(short8*)&Bs[r1*LP + c1] = bv1;
    __syncthreads();
    short8 af[4], bfv[4];
    #pragma unroll
    for (int i=0;i<4;i++) af[i]  = *(const short8*)&As[(wm + 16*i + ml)*LP + q*8];
    #pragma unroll
    for (int j=0;j<4;j++) bfv[j] = *(const short8*)&Bs[(wn + 16*j + ml)*LP + q*8];
    #pragma unroll
    for (int i=0;i<4;i++)
      #pragma unroll
      for (int j=0;j<4;j++)
        acc[i][j] = __builtin_amdgcn_mfma_f32_16x16x32_bf16(af[i], bfv[j], acc[i][j], 0,0,0);
  }

  const float* biasz = bias ? bias + (long)z*sB : nullptr;
  const float* Rz = R ? R + (long)z*sR : nullptr;
  long coff = (long)z*sC;
  #pragma unroll
  for (int i=0;i<4;i++){
    #pragma unroll
    for (int r=0;r<4;r++){
      int gm = bm + wm + 16*i + q*4 + r;
      #pragma unroll
      for (int j=0;j<4;j++){
        int gn = bn + wn + 16*j + ml;
        float v = acc[i][j][r];
        if (biasz){
          int bi;
          if (bsplit){
            if (gn < bsplit) bi = gn;
            else if (gn >= bsplitPad && gn < bsplitPad + (nbias - bsplit)) bi = gn - (bsplitPad - bsplit);
            else bi = -1;
          } else bi = (gn < nbias) ? gn : -1;
          if (bi >= 0) v += biasz[bi];
        }
        if (act == 2) v = (v > 0.f) ? v : 0.01f*v;
        if (Rz) v += Rz[(long)gm*ldr + gn];
        if (cIsBf16) ((__hip_bfloat16*)C)[coff + (long)gm*ldc + gn] = __float2bfloat16(v);
        else         ((float*)C)[coff + (long)gm*ldc + gn] = v;
      }
    }
  }
}

// ---------------- weight transpose+convert: W [K][N] fp32 -> WT [Npad][Kpad] bf16
// optional split remap (geglu halves padded independently); zero-fills pads.
__global__ __launch_bounds__(256) void convT_kernel(
    const float* __restrict__ W, int N, int K, long sW,
    __hip_bfloat16* __restrict__ out, int Npad, int Kpad, long sO,
    int split, int splitPad)
{
  int z = blockIdx.z;
  int n0 = blockIdx.x*64, k0 = blockIdx.y*64;
  int tid = threadIdx.x;
  __shared__ float lds[64][65];
  #pragma unroll
  for (int i=0;i<16;i++){
    int e = tid + i*256;
    int kl = e >> 6, c = e & 63;
    int np = n0 + c;
    int ns;
    if (split){
      if (np < split) ns = np;
      else if (np >= splitPad && np < splitPad + (N - split)) ns = np - (splitPad - split);
      else ns = -1;
    } else ns = (np < N) ? np : -1;
    int k = k0 + kl;
    float v = (ns >= 0 && k < K) ? W[(long)z*sW + (long)k*N + ns] : 0.f;
    lds[kl][c] = v;
  }
  __syncthreads();
  #pragma unroll
  for (int i=0;i<16;i++){
    int e = tid + i*256;
    int nl = e >> 6, kl = e & 63;
    out[(long)z*sO + (long)(n0+nl)*Kpad + k0 + kl] = __float2bfloat16(lds[kl][nl]);
  }
}

// ---------------- attention split-K: partial (m,l,o) over 256-key chunks
__global__ __launch_bounds__(256) void attn_split_kernel(
    const float* __restrict__ qp, const float* __restrict__ kp,
    const float* __restrict__ vp,
    float* __restrict__ po, float* __restrict__ pm, float* __restrict__ pl)
{
  int bh = blockIdx.y; int bb = bh >> 3; int h = bh & 7;
  int kc = blockIdx.z;
  int qi = blockIdx.x*256 + threadIdx.x;
  const float scale = 0.17677669529663687f;
  float qreg[32];
  const float* qptr = qp + (((bb<<10)+qi)<<8) + (h<<5);
  #pragma unroll
  for (int d=0;d<32;d++) qreg[d] = qptr[d];
  float m = -INFINITY, l = 0.f;
  float oacc[32];
  #pragma unroll
  for (int d=0;d<32;d++) oacc[d] = 0.f;

  __shared__ float Ks[64][32];
  __shared__ float Vs[64][32];
  int jbase = kc*256;
  for (int j0=jbase; j0<jbase+256; j0+=64){
    __syncthreads();
    #pragma unroll
    for (int i=0;i<8;i++){
      int e = threadIdx.x + i*256;
      int j = e >> 5, d = e & 31;
      int base = (((bb<<10)+j0+j)<<8) + (h<<5) + d;
      Ks[j][d] = kp[base];
      Vs[j][d] = vp[base];
    }
    __syncthreads();
    for (int j=0;j<64;j++){
      float s = 0.f;
      #pragma unroll
      for (int d=0;d<32;d++) s += qreg[d]*Ks[j][d];
      s *= scale;
      if (s > m){
        float corr = expf(m - s);
        l = l*corr + 1.f;
        #pragma unroll
        for (int d=0;d<32;d++) oacc[d] = oacc[d]*corr + Vs[j][d];
        m = s;
      } else {
        float p = expf(s - m);
        l += p;
        #pragma unroll
        for (int d=0;d<32;d++) oacc[d] += p*Vs[j][d];
      }
    }
  }
  int r = (bh<<10) + qi;
  pm[kc*32768 + r] = m;
  pl[kc*32768 + r] = l;
  float* pop = po + ((long)kc*32768 + r)*32;
  #pragma unroll
  for (int d=0;d<32;d++) pop[d] = oacc[d];
}

__global__ __launch_bounds__(256) void attn_merge_kernel(
    const float* __restrict__ po, const float* __restrict__ pm,
    const float* __restrict__ pl, float* __restrict__ out)
{
  int r = blockIdx.x*256 + threadIdx.x;  // 0..32767
  float mz[4], wz[4];
  float M = -INFINITY;
  #pragma unroll
  for (int zc=0;zc<4;zc++){ mz[zc] = pm[zc*32768 + r]; M = fmaxf(M, mz[zc]); }
  float L = 0.f;
  #pragma unroll
  for (int zc=0;zc<4;zc++){ wz[zc] = expf(mz[zc] - M); L += pl[zc*32768 + r]*wz[zc]; }
  float inv = 1.f / L;
  int bh = r >> 10, qi = r & 1023;
  int bb = bh >> 3, h = bh & 7;
  float* op = out + (((bb<<10)+qi)<<8) + (h<<5);
  for (int d=0; d<32; d++){
    float s = 0.f;
    #pragma unroll
    for (int zc=0;zc<4;zc++) s += wz[zc]*po[((long)zc*32768 + r)*32 + d];
    op[d] = s*inv;
  }
}

// ---------------- concat queries into x[:, 256:512]
__global__ __launch_bounds__(256) void concat_kernel(
    const float* __restrict__ queries, float* __restrict__ x)
{
  int idx = blockIdx.x*256 + threadIdx.x;
  int d = idx & 255; int r = idx >> 8;
  x[(r<<9) + 256 + d] = queries[idx];
}

// ---------------- rmsnorm (fp32 out)
__global__ __launch_bounds__(256) void rmsnorm_kernel(
    const float* __restrict__ x, const float* __restrict__ g, float* __restrict__ y)
{
  int r = blockIdx.x; int tid = threadIdx.x;
  float v0 = x[(r<<9) + tid];
  float v1 = x[(r<<9) + 256 + tid];
  float ss = v0*v0 + v1*v1;
  #pragma unroll
  for (int off=32; off>0; off>>=1) ss += __shfl_down(ss, off, 64);
  __shared__ float wsum[4];
  if ((tid & 63) == 0) wsum[tid>>6] = ss;
  __syncthreads();
  float tot = wsum[0]+wsum[1]+wsum[2]+wsum[3];
  float scale = 22.62741699796952f / fmaxf(sqrtf(tot), 1e-12f);
  y[(r<<9) + tid]       = v0*scale*g[tid];
  y[(r<<9) + 256 + tid] = v1*scale*g[256+tid];
}

// ---------------- rmsnorm (bf16 out)
__global__ __launch_bounds__(256) void rmsnorm_bf_kernel(
    const float* __restrict__ x, const float* __restrict__ g, __hip_bfloat16* __restrict__ y)
{
  int r = blockIdx.x; int tid = threadIdx.x;
  float v0 = x[(r<<9) + tid];
  float v1 = x[(r<<9) + 256 + tid];
  float ss = v0*v0 + v1*v1;
  #pragma unroll
  for (int off=32; off>0; off>>=1) ss += __shfl_down(ss, off, 64);
  __shared__ float wsum[4];
  if ((tid & 63) == 0) wsum[tid>>6] = ss;
  __syncthreads();
  float tot = wsum[0]+wsum[1]+wsum[2]+wsum[3];
  float scale = 22.62741699796952f / fmaxf(sqrtf(tot), 1e-12f);
  y[(r<<9) + tid]       = __float2bfloat16(v0*scale*g[tid]);
  y[(r<<9) + 256 + tid] = __float2bfloat16(v1*scale*g[256+tid]);
}

// ---------------- geglu glu (fp32, ffb path)
__global__ __launch_bounds__(256) void glu_kernel(
    const float* __restrict__ h, const float* __restrict__ mult, float* __restrict__ t)
{
  int idx = blockIdx.x*256 + threadIdx.x;
  int r = idx / 1365; int j = idx - r*1365;
  float a = h[(long)r*2730 + j];
  float gt = h[(long)r*2730 + 1365 + j];
  t[idx] = gelu_f(gt) * a * mult[j];
}

// ---------------- geglu glu (bf16 in/out, padded layout, ffa path)
__global__ __launch_bounds__(256) void glu_bf_kernel(
    const __hip_bfloat16* __restrict__ h, const float* __restrict__ mult,
    __hip_bfloat16* __restrict__ t)
{
  int idx = blockIdx.x*256 + threadIdx.x;   // 4096*1408
  int r = idx >> 11; int j = idx & 2047;    // 1408 not pow2 -> use div
  r = idx / 1408; j = idx - r*1408;
  float v = 0.f;
  if (j < 1365){
    float a  = __bfloat162float(h[(long)r*2816 + j]);
    float gt = __bfloat162float(h[(long)r*2816 + 1408 + j]);
    v = gelu_f(gt) * a * mult[j];
  }
  t[idx] = __float2bfloat16(v);
}

// ---------------- MoE init
__global__ __launch_bounds__(256) void moe_init_kernel(
    int* ts1, int* ts2, int* slot_token, float* sum_raw, float* z_sum)
{
  int i = blockIdx.x*256 + threadIdx.x;
  if (i < 4096){ ts1[i] = -1; ts2[i] = -1; }
  if (i < 8192) slot_token[i] = -1;
  if (i < 64)  sum_raw[i] = 0.f;
  if (i == 0)  *z_sum = 0.f;
}

// ---------------- gating
__global__ __launch_bounds__(256) void gating_kernel(
    const float* __restrict__ xn, const float* __restrict__ gate_w,
    int* __restrict__ idx1, int* __restrict__ idx2, int* __restrict__ route,
    float* __restrict__ gg1, float* __restrict__ gg2,
    float* __restrict__ sum_raw, float* __restrict__ z_sum)
{
  int t = blockIdx.x; int tid = threadIdx.x;
  __shared__ float xrow[512];
  xrow[tid]     = xn[(t<<9)+tid];
  xrow[256+tid] = xn[(t<<9)+256+tid];
  __syncthreads();
  int e = tid >> 4, l16 = tid & 15;
  float p = 0.f;
  for (int d=l16; d<512; d+=16) p += xrow[d]*gate_w[(e<<9)+d];
  __shared__ float part[16][17];
  part[e][l16] = p;
  __syncthreads();
  __shared__ float raw[16];
  if (tid < 16){
    float s = 0.f;
    #pragma unroll
    for (int i=0;i<16;i++) s += part[tid][i];
    raw[tid] = s;
  }
  __syncthreads();
  if (tid == 0){
    float mx = -1e30f;
    #pragma unroll
    for (int i=0;i<16;i++) mx = fmaxf(mx, raw[i]);
    float r[16]; float sum = 0.f;
    #pragma unroll
    for (int i=0;i<16;i++){ r[i] = expf(raw[i]-mx); sum += r[i]; }
    float lse = mx + logf(sum);
    atomicAdd(z_sum, lse*lse);
    float inv = 1.f/sum;
    #pragma unroll
    for (int i=0;i<16;i++){ r[i] *= inv; raw[i] = r[i]; }
    int i1 = -1; float b1 = -1.f;
    #pragma unroll
    for (int i=0;i<16;i++) if (r[i] > b1){ b1 = r[i]; i1 = i; }
    int i2 = -1; float b2 = -1.f;
    #pragma unroll
    for (int i=0;i<16;i++) if (i != i1 && r[i] > b2){ b2 = r[i]; i2 = i; }
    float s2 = fmaxf(b1 + b2, 1e-9f);
    float g1n = b1/s2, g2n = b2/s2;
    idx1[t] = i1; idx2[t] = i2;
    route[t] = (g2n > 0.2f) ? 1 : 0;
    gg1[t] = g1n; gg2[t] = g2n;
  }
  __syncthreads();
  int bb = t >> 10;
  if (tid < 16) atomicAdd(&sum_raw[(bb<<4)+tid], raw[tid]);
}

// ---------------- capacity scan
__global__ void scan_kernel(
    const int* __restrict__ idx1, const int* __restrict__ idx2, const int* __restrict__ route,
    int* __restrict__ ts1, int* __restrict__ ts2, int* __restrict__ slot_token,
    int* __restrict__ count1)
{
  int bb = blockIdx.x; int e = threadIdx.x;
  if (e >= 16) return;
  int cnt = 0;
  for (int n=0;n<1024;n++){
    int t = (bb<<10)+n;
    if (idx1[t] == e){
      if (cnt < CAPN){ int slot = ((e<<2)+bb)*CAPN + cnt; ts1[t] = slot; slot_token[slot] = t; }
      else ts1[t] = -1;
      cnt++;
    }
  }
  count1[(bb<<4)+e] = cnt;
  int c2 = cnt;
  for (int n=0;n<1024;n++){
    int t = (bb<<10)+n;
    if (idx2[t] == e && route[t]){
      if (c2 < CAPN){ int slot = ((e<<2)+bb)*CAPN + c2; ts2[t] = slot; slot_token[slot] = t; }
      c2++;
    }
  }
}

// ---------------- gather + layernorm -> xin bf16
__global__ __launch_bounds__(256) void gather_ln_kernel(
    const float* __restrict__ xn, const int* __restrict__ slot_token,
    const float* __restrict__ ln_g, const float* __restrict__ ln_b,
    __hip_bfloat16* __restrict__ xin)
{
  int s = blockIdx.x; int tid = threadIdx.x;
  int t = slot_token[s];
  int e = s >> 9;
  if (t < 0){
    xin[(s<<9)+tid] = __float2bfloat16(0.f);
    xin[(s<<9)+256+tid] = __float2bfloat16(0.f);
    return;
  }
  float v0 = xn[(t<<9)+tid];
  float v1 = xn[(t<<9)+256+tid];
  float sm = v0+v1, sq = v0*v0+v1*v1;
  #pragma unroll
  for (int off=32; off>0; off>>=1){
    sm += __shfl_down(sm, off, 64);
    sq += __shfl_down(sq, off, 64);
  }
  __shared__ float s1[4], s2buf[4];
  if ((tid & 63) == 0){ s1[tid>>6] = sm; s2buf[tid>>6] = sq; }
  __syncthreads();
  float tsm = s1[0]+s1[1]+s1[2]+s1[3];
  float tsq = s2buf[0]+s2buf[1]+s2buf[2]+s2buf[3];
  float mean = tsm * (1.f/512.f);
  float var = tsq * (1.f/512.f) - mean*mean;
  float rstd = rsqrtf(var + 1e-5f);
  xin[(s<<9)+tid]     = __float2bfloat16((v0-mean)*rstd*ln_g[(e<<9)+tid]     + ln_b[(e<<9)+tid]);
  xin[(s<<9)+256+tid] = __float2bfloat16((v1-mean)*rstd*ln_g[(e<<9)+256+tid] + ln_b[(e<<9)+256+tid]);
}

// ---------------- combine (in-place: x += g1*h2[s1] + g2*h2[s2])
__global__ __launch_bounds__(256) void combine_kernel(
    float* __restrict__ x, const float* __restrict__ h2,
    const int* __restrict__ ts1, const int* __restrict__ ts2,
    const float* __restrict__ gg1, const float* __restrict__ gg2)
{
  int idx = blockIdx.x*256 + threadIdx.x;
  int t = idx >> 9; int d = idx & 511;
  float v = x[idx];
  int s1 = ts1[t]; if (s1 >= 0) v += gg1[t]*h2[(s1<<9)+d];
  int s2 = ts2[t]; if (s2 >= 0) v += gg2[t]*h2[(s2<<9)+d];
  x[idx] = v;
}

// ---------------- aux losses
__global__ void aux_kernel(
    const float* __restrict__ sum_raw, const int* __restrict__ count1,
    const float* __restrict__ z_sum, float* __restrict__ out)
{
  int tid = threadIdx.x;
  float v = (sum_raw[tid] * (1.f/1024.f)) * ((float)count1[tid] * (1.f/1024.f));
  #pragma unroll
  for (int off=32; off>0; off>>=1) v += __shfl_down(v, off, 64);
  if (tid == 0){
    float bal = v * (1.f/64.f) * 256.f * 0.01f;
    float zl = (*z_sum) * (1.f/4096.f) * 0.001f;
    out[0] = bal + zl;
    out[1] = bal;
    out[2] = zl;
  }
}

// ---------------- host helpers
static void launch_gemm(hipStream_t st,
    const float* A, int lda, long sA,
    const float* W, int ldw, long sW,
    const float* bias, long sB,
    const float* R, int ldr, long sR,
    float* C, int ldc, long sC,
    int M, int N, int K, int act, int Z)
{
  dim3 g((N+63)/64, (M+63)/64, Z);
  gemm_kernel<<<g, 256, 0, st>>>(A,lda,sA, W,ldw,sW, bias,sB, R,ldr,sR, C,ldc,sC, M,N,K,act);
}

static void launch_bgemm(hipStream_t st,
    const __hip_bfloat16* A, int lda, long sA,
    const __hip_bfloat16* WT, int ldw, long sW,
    const float* bias, int nbias, int bsplit, int bsplitPad, long sB,
    const float* R, int ldr, long sR,
    void* C, int ldc, long sC, int cbf,
    int M, int N, int K, int act, int Z)
{
  dim3 g(N/128, M/128, Z);
  bgemm_kernel<<<g, 256, 0, st>>>(A,lda,sA, WT,ldw,sW, bias,nbias,bsplit,bsplitPad,sB,
                                  R,ldr,sR, C,ldc,sC,cbf, K,act);
}

extern "C" void kernel_launch(void* const* d_in, const int* in_sizes, int n_in,
                              void* d_out, int out_size, void* d_ws, size_t ws_size,
                              hipStream_t stream)
{
  const float* K_in   = (const float*)d_in[0];
  const float* V_in   = (const float*)d_in[1];
  const float* Q_in   = (const float*)d_in[2];
  const float* w_topo = (const float*)d_in[3];
  const float* b_topo = (const float*)d_in[4];
  const float* w_val  = (const float*)d_in[5];
  const float* b_val  = (const float*)d_in[6];
  const float* wq     = (const float*)d_in[7];
  const float* bq     = (const float*)d_in[8];
  const float* wk     = (const float*)d_in[9];
  const float* bk     = (const float*)d_in[10];
  const float* wv     = (const float*)d_in[11];
  const float* bv     = (const float*)d_in[12];
  const float* wo     = (const float*)d_in[13];
  const float* bo     = (const float*)d_in[14];
  const float* ffb_g  = (const float*)d_in[15];
  const float* ffb_w1 = (const float*)d_in[16];
  const float* ffb_b1 = (const float*)d_in[17];
  const float* ffb_mult=(const float*)d_in[18];
  const float* ffb_w2 = (const float*)d_in[19];
  const float* ffb_b2 = (const float*)d_in[20];
  const float* prenorm_g=(const float*)d_in[21];
  const float* gate_w = (const float*)d_in[22];
  const float* exp_ln_g=(const float*)d_in[23];
  const float* exp_ln_b=(const float*)d_in[24];
  const float* exp_w1 = (const float*)d_in[25];
  const float* exp_b1 = (const float*)d_in[26];
  const float* exp_w2 = (const float*)d_in[27];
  const float* exp_b2 = (const float*)d_in[28];
  const float* ffa_g  = (const float*)d_in[29];
  const float* ffa_w1 = (const float*)d_in[30];
  const float* ffa_b1 = (const float*)d_in[31];
  const float* ffa_mult=(const float*)d_in[32];
  const float* ffa_w2 = (const float*)d_in[33];
  const float* ffa_b2 = (const float*)d_in[34];
  const float* w_out  = (const float*)d_in[35];
  const float* b_out  = (const float*)d_in[36];
  float* dout = (float*)d_out;

  float* wsf = (float*)d_ws;
  int*   wsi = (int*)d_ws;

  // ---- workspace layout (float-element offsets) ----
  const size_t F_Q  = 0;
  const size_t F_K  = 1048576;
  const size_t F_V  = 2097152;
  const size_t F_QP = 3145728;
  const size_t F_KP = 4194304;
  const size_t F_VP = 5242880;
  const size_t F_AO = 6291456;
  const size_t PO   = 7340032;    // attn partials: 4*32768*32 fl
  const size_t PM   = 11534336;   // 131072
  const size_t PL   = 11665408;   // 131072
  const size_t F_H  = 0;          // ffb h fp32 (4096*2730)
  const size_t F_T  = 11182080;   // ffb t fp32 (4096*1365)
  const size_t F_XA = 16773120;   // 2097152
  const size_t F_XB = 18870272;   // 2097152
  const size_t F_Y  = 20967424;   // 2097152
  const size_t I_M  = 23064576;
  // MoE phase (reuses 0..16.77M):
  const size_t XIN  = 0;          // bf16 8192*512  = 2097152 fl
  const size_t WTE  = 2097152;    // bf16 16*1408*512 = 5767168 fl
  const size_t H1   = 7864320;    // bf16 16*512*1408 = 5767168 fl
  const size_t H2   = 13631488;   // fp32 8192*512 = 4194304 fl (spills into dead F_XA)
  // ffa phase:
  const size_t YBF  = 0;          // bf16 4096*512 = 1048576 fl
  const size_t WF1  = 1048576;    // bf16 2816*512 = 720896 fl
  const size_t HBF  = 1769472;    // bf16 4096*2816 = 5767168 fl
  const size_t TBF  = 7536640;    // bf16 4096*1408 = 2883584 fl
  const size_t WF2  = 10420224;   // bf16 512*1408 = 360448 fl

  int* idx1 = wsi + I_M + 0;
  int* idx2 = wsi + I_M + 4096;
  int* route= wsi + I_M + 8192;
  int* ts1  = wsi + I_M + 12288;
  int* ts2  = wsi + I_M + 16384;
  int* slot_token = wsi + I_M + 20480;
  int* count1     = wsi + I_M + 28672;
  float* sum_raw  = wsf + I_M + 28736;
  float* z_sum    = wsf + I_M + 28800;
  float* gg1      = wsf + I_M + 28864;
  float* gg2      = wsf + I_M + 32960;

  // 1. topo / values
  topo_kernel<<<8192, 256, 0, stream>>>(K_in, Q_in, w_topo, b_topo, wsf+F_K, wsf+F_Q);
  values_kernel<<<4096, 256, 0, stream>>>(V_in, w_val, b_val, wsf+F_V);

  // 2. QKV projections (fp32)
  launch_gemm(stream, wsf+F_Q,256,0, wq,256,0, bq,0, nullptr,0,0, wsf+F_QP,256,0, 4096,256,256, 0, 1);
  launch_gemm(stream, wsf+F_K,256,0, wk,256,0, bk,0, nullptr,0,0, wsf+F_KP,256,0, 4096,256,256, 0, 1);
  launch_gemm(stream, wsf+F_V,256,0, wv,256,0, bv,0, nullptr,0,0, wsf+F_VP,256,0, 4096,256,256, 0, 1);

  // 3. attention: split-K over 4 key chunks + merge
  attn_split_kernel<<<dim3(4,32,4), 256, 0, stream>>>(wsf+F_QP, wsf+F_KP, wsf+F_VP,
                                                      wsf+PO, wsf+PM, wsf+PL);
  attn_merge_kernel<<<128, 256, 0, stream>>>(wsf+PO, wsf+PM, wsf+PL, wsf+F_AO);

  // 4. o-proj + concat
  launch_gemm(stream, wsf+F_AO,256,0, wo,256,0, bo,0, nullptr,0,0, wsf+F_XA,512,0, 4096,256,256, 0, 1);
  concat_kernel<<<4096, 256, 0, stream>>>(wsf+F_Q, wsf+F_XA);

  // 5. ffb geglu (fp32, upstream of MoE gate -> keep full precision)
  rmsnorm_kernel<<<4096, 256, 0, stream>>>(wsf+F_XA, ffb_g, wsf+F_Y);
  launch_gemm(stream, wsf+F_Y,512,0, ffb_w1,2730,0, ffb_b1,0, nullptr,0,0, wsf+F_H,2730,0, 4096,2730,512, 0, 1);
  glu_kernel<<<21840, 256, 0, stream>>>(wsf+F_H, ffb_mult, wsf+F_T);
  launch_gemm(stream, wsf+F_T,1365,0, ffb_w2,512,0, ffb_b2,0, wsf+F_XA,512,0, wsf+F_XB,512,0, 4096,512,1365, 0, 1);

  // 6. MoE (gating fp32; expert GEMMs bf16 MFMA)
  rmsnorm_kernel<<<4096, 256, 0, stream>>>(wsf+F_XB, prenorm_g, wsf+F_Y);
  moe_init_kernel<<<32, 256, 0, stream>>>(ts1, ts2, slot_token, sum_raw, z_sum);
  gating_kernel<<<4096, 256, 0, stream>>>(wsf+F_Y, gate_w, idx1, idx2, route, gg1, gg2, sum_raw, z_sum);
  scan_kernel<<<4, 64, 0, stream>>>(idx1, idx2, route, ts1, ts2, slot_token, count1);

  __hip_bfloat16* xin_bf = (__hip_bfloat16*)(wsf + XIN);
  __hip_bfloat16* wte    = (__hip_bfloat16*)(wsf + WTE);
  __hip_bfloat16* h1_bf  = (__hip_bfloat16*)(wsf + H1);

  gather_ln_kernel<<<8192, 256, 0, stream>>>(wsf+F_Y, slot_token, exp_ln_g, exp_ln_b, xin_bf);
  // exp_w1 [16][512][1365] -> WT [16][1408][512]
  convT_kernel<<<dim3(22, 8, 16), 256, 0, stream>>>(exp_w1, 1365, 512, (long)512*1365,
                                                    wte, 1408, 512, (long)1408*512, 0, 0);
  launch_bgemm(stream, xin_bf,512,(long)512*512, wte,512,(long)1408*512,
               exp_b1,1365,0,0,1365, nullptr,0,0,
               h1_bf,1408,(long)512*1408, 1, 512,1408,512, 2, 16);
  // exp_w2 [16][1365][512] -> WT [16][512][1408]  (reuse wte; w1T dead)
  convT_kernel<<<dim3(8, 22, 16), 256, 0, stream>>>(exp_w2, 512, 1365, (long)1365*512,
                                                    wte, 512, 1408, (long)512*1408, 0, 0);
  launch_bgemm(stream, h1_bf,1408,(long)512*1408, wte,1408,(long)512*1408,
               exp_b2,512,0,0,512, nullptr,0,0,
               wsf+H2,512,(long)512*512, 0, 512,512,1408, 0, 16);
  combine_kernel<<<8192, 256, 0, stream>>>(wsf+F_XB, wsf+H2, ts1, ts2, gg1, gg2);
  aux_kernel<<<1, 64, 0, stream>>>(sum_raw, count1, z_sum, dout + 4096*256);

  // 7. ffa geglu (bf16 MFMA, downstream of gate)
  __hip_bfloat16* y_bf = (__hip_bfloat16*)(wsf + YBF);
  __hip_bfloat16* wf1  = (__hip_bfloat16*)(wsf + WF1);
  __hip_bfloat16* h_bf = (__hip_bfloat16*)(wsf + HBF);
  __hip_bfloat16* t_bf = (__hip_bfloat16*)(wsf + TBF);
  __hip_bfloat16* wf2  = (__hip_bfloat16*)(wsf + WF2);

  rmsnorm_bf_kernel<<<4096, 256, 0, stream>>>(wsf+F_XB, ffa_g, y_bf);
  // ffa_w1 [512][2730] -> WT [2816][512] with split remap (1365 -> pad 1408)
  convT_kernel<<<dim3(44, 8, 1), 256, 0, stream>>>(ffa_w1, 2730, 512, 0,
                                                   wf1, 2816, 512, 0, 1365, 1408);
  launch_bgemm(stream, y_bf,512,0, wf1,512,0,
               ffa_b1,2730,1365,1408,0, nullptr,0,0,
               h_bf,2816,0, 1, 4096,2816,512, 0, 1);
  glu_bf_kernel<<<22528, 256, 0, stream>>>(h_bf, ffa_mult, t_bf);
  // ffa_w2 [1365][512] -> WT [512][1408]
  convT_kernel<<<dim3(8, 22, 1), 256, 0, stream>>>(ffa_w2, 512, 1365, 0,
                                                   wf2, 512, 1408, 0, 0, 0);
  launch_bgemm(stream, t_bf,1408,0, wf2,1408,0,
               ffa_b2,512,0,0,0, wsf+F_XB,512,0,
               wsf+F_XA,512,0, 0, 4096,512,1408, 0, 1);

  // 8. out = gelu(x @ w_out + b_out)  (fp32)
  launch_gemm(stream, wsf+F_XA,512,0, w_out,256,0, b_out,0, nullptr,0,0, dout,256,0, 4096,256,512, 1, 1);
}

// Round 4
// 1229.905 us; speedup vs baseline: 2.4660x; 1.4945x over previous
//
#include <hip/hip_runtime.h>
#include <hip/hip_bf16.h>
#include <math.h>

// B=4 S=1024 DM=256 H=8 HD=32 CIN=23 E=16 D2=512 HE=1365 2HE=2730 CAP=128
#define CAPN 128

typedef short short8 __attribute__((ext_vector_type(8)));
typedef float f32x4 __attribute__((ext_vector_type(4)));

__device__ __forceinline__ float gelu_f(float x){
  return 0.5f*x*(1.0f+erff(x*0.7071067811865476f));
}
__device__ __forceinline__ void split2(float v, __hip_bfloat16& h, __hip_bfloat16& l){
  h = __float2bfloat16(v);
  l = __float2bfloat16(v - __bfloat162float(h));
}

// ---------------- topo: gelu(cat([K,Q]) @ w + b) -> keys (hi/lo), queries (hi/lo + fp32)
__global__ __launch_bounds__(256) void topo_kernel(
    const float* __restrict__ K, const float* __restrict__ Q,
    const float* __restrict__ w, const float* __restrict__ b,
    __hip_bfloat16* __restrict__ khi, __hip_bfloat16* __restrict__ klo,
    __hip_bfloat16* __restrict__ qhi, __hip_bfloat16* __restrict__ qlo,
    float* __restrict__ qf32)
{
  int idx = blockIdx.x*256 + threadIdx.x;   // 2M
  int d = idx & 255;
  int r = idx >> 8;
  int bb = r >> 11;
  int n  = r & 2047;
  const float* src = (n < 1024) ? (K + ((bb<<10) + n)*3)
                                : (Q + ((bb<<10) + (n-1024))*3);
  float v = b[d] + src[0]*w[d] + src[1]*w[256+d] + src[2]*w[512+d];
  v = gelu_f(v);
  int off = (((bb<<10) + (n & 1023))<<8) + d;
  __hip_bfloat16 h, l; split2(v, h, l);
  if (n < 1024){ khi[off] = h; klo[off] = l; }
  else         { qhi[off] = h; qlo[off] = l; qf32[off] = v; }
}

// ---------------- values: gelu(V @ w_val + b_val) -> hi/lo
__global__ __launch_bounds__(256) void values_kernel(
    const float* __restrict__ V, const float* __restrict__ w,
    const float* __restrict__ b,
    __hip_bfloat16* __restrict__ vhi, __hip_bfloat16* __restrict__ vlo)
{
  int idx = blockIdx.x*256 + threadIdx.x;
  int d = idx & 255; int r = idx >> 8;
  const float* src = V + r*23;
  float acc = b[d];
  #pragma unroll
  for (int c=0;c<23;c++) acc += src[c]*w[c*256+d];
  acc = gelu_f(acc);
  __hip_bfloat16 h, l; split2(acc, h, l);
  vhi[idx] = h; vlo[idx] = l;
}

// ---------------- split-bf16 "fp32" MFMA GEMM: C = act(A@W + bias) (+R)
// acc = Ah*Wh + Ah*Wl + Al*Wh  (rel err ~1e-5). 128x128 tile, BK=32.
#define SLP 40
__global__ __launch_bounds__(256) void sgemm_kernel(
    const __hip_bfloat16* __restrict__ Ah_, const __hip_bfloat16* __restrict__ Al_,
    int lda, long sA,
    const __hip_bfloat16* __restrict__ Wh_, const __hip_bfloat16* __restrict__ Wl_,
    int ldw, long sW,
    const float* __restrict__ bias, int nbias, int bsplit, int bsplitPad, long sB,
    const float* __restrict__ R, int ldr,
    float* __restrict__ C, int ldc, long sC,
    int K, int act)
{
  int z = blockIdx.z;
  const short* Ah = (const short*)Ah_ + (long)z*sA;
  const short* Al = (const short*)Al_ + (long)z*sA;
  const short* Wh = (const short*)Wh_ + (long)z*sW;
  const short* Wl = (const short*)Wl_ + (long)z*sW;
  int bm = blockIdx.y*128, bn = blockIdx.x*128;
  int tid = threadIdx.x, lane = tid & 63, wave = tid >> 6;
  int wm = (wave & 1)*64, wn = (wave >> 1)*64;

  __shared__ short AsH[128*SLP], AsL[128*SLP], BsH[128*SLP], BsL[128*SLP];

  f32x4 acc[4][4];
  f32x4 zero4 = {0.f,0.f,0.f,0.f};
  #pragma unroll
  for (int i=0;i<4;i++)
    #pragma unroll
    for (int j=0;j<4;j++) acc[i][j] = zero4;

  int srow = tid >> 1, scol = (tid & 1)*16;
  int ml = lane & 15, q = lane >> 4;

  for (int k0 = 0; k0 < K; k0 += 32){
    long abase = (long)(bm+srow)*lda + k0 + scol;
    long bbase = (long)(bn+srow)*ldw + k0 + scol;
    short8 ah0 = *(const short8*)&Ah[abase];
    short8 ah1 = *(const short8*)&Ah[abase + 8];
    short8 al0 = *(const short8*)&Al[abase];
    short8 al1 = *(const short8*)&Al[abase + 8];
    short8 bh0 = *(const short8*)&Wh[bbase];
    short8 bh1 = *(const short8*)&Wh[bbase + 8];
    short8 bl0 = *(const short8*)&Wl[bbase];
    short8 bl1 = *(const short8*)&Wl[bbase + 8];
    __syncthreads();
    *(short8*)&AsH[srow*SLP + scol]     = ah0;
    *(short8*)&AsH[srow*SLP + scol + 8] = ah1;
    *(short8*)&AsL[srow*SLP + scol]     = al0;
    *(short8*)&AsL[srow*SLP + scol + 8] = al1;
    *(short8*)&BsH[srow*SLP + scol]     = bh0;
    *(short8*)&BsH[srow*SLP + scol + 8] = bh1;
    *(short8*)&BsL[srow*SLP + scol]     = bl0;
    *(short8*)&BsL[srow*SLP + scol + 8] = bl1;
    __syncthreads();
    short8 afh[4], afl[4], bfh[4], bfl[4];
    #pragma unroll
    for (int i=0;i<4;i++){
      afh[i] = *(const short8*)&AsH[(wm + 16*i + ml)*SLP + q*8];
      afl[i] = *(const short8*)&AsL[(wm + 16*i + ml)*SLP + q*8];
    }
    #pragma unroll
    for (int j=0;j<4;j++){
      bfh[j] = *(const short8*)&BsH[(wn + 16*j + ml)*SLP + q*8];
      bfl[j] = *(const short8*)&BsL[(wn + 16*j + ml)*SLP + q*8];
    }
    #pragma unroll
    for (int i=0;i<4;i++)
      #pragma unroll
      for (int j=0;j<4;j++){
        acc[i][j] = __builtin_amdgcn_mfma_f32_16x16x32_bf16(afh[i], bfh[j], acc[i][j], 0,0,0);
        acc[i][j] = __builtin_amdgcn_mfma_f32_16x16x32_bf16(afh[i], bfl[j], acc[i][j], 0,0,0);
        acc[i][j] = __builtin_amdgcn_mfma_f32_16x16x32_bf16(afl[i], bfh[j], acc[i][j], 0,0,0);
      }
  }

  const float* biasz = bias ? bias + (long)z*sB : nullptr;
  long coff = (long)z*sC;
  #pragma unroll
  for (int i=0;i<4;i++){
    #pragma unroll
    for (int r=0;r<4;r++){
      int gm = bm + wm + 16*i + q*4 + r;
      #pragma unroll
      for (int j=0;j<4;j++){
        int gn = bn + wn + 16*j + ml;
        float v = acc[i][j][r];
        if (biasz){
          int bi;
          if (bsplit){
            if (gn < bsplit) bi = gn;
            else if (gn >= bsplitPad && gn < bsplitPad + (nbias - bsplit)) bi = gn - (bsplitPad - bsplit);
            else bi = -1;
          } else bi = (gn < nbias) ? gn : -1;
          if (bi >= 0) v += biasz[bi];
        }
        if (act == 1) v = gelu_f(v);
        if (R) v += R[(long)gm*ldr + gn];
        C[coff + (long)gm*ldc + gn] = v;
      }
    }
  }
}

// ---------------- pure-bf16 MFMA GEMM (experts / ffa)
#define LP 56
__global__ __launch_bounds__(256) void bgemm_kernel(
    const __hip_bfloat16* __restrict__ A, int lda, long sA,
    const __hip_bfloat16* __restrict__ WT, int ldw, long sW,
    const float* __restrict__ bias, int nbias, int bsplit, int bsplitPad, long sB,
    const float* __restrict__ R, int ldr, long sR,
    void* __restrict__ C, int ldc, long sC, int cIsBf16,
    int K, int act)
{
  int z = blockIdx.z;
  const short* Ab = (const short*)A + (long)z*sA;
  const short* Bb = (const short*)WT + (long)z*sW;
  int bm = blockIdx.y*128, bn = blockIdx.x*128;
  int tid = threadIdx.x, lane = tid & 63, wave = tid >> 6;
  int wm = (wave & 1)*64, wn = (wave >> 1)*64;

  __shared__ short As[128*LP];
  __shared__ short Bs[128*LP];

  f32x4 acc[4][4];
  f32x4 zero4 = {0.f,0.f,0.f,0.f};
  #pragma unroll
  for (int i=0;i<4;i++)
    #pragma unroll
    for (int j=0;j<4;j++) acc[i][j] = zero4;

  int g0 = tid, g1 = tid + 256;
  int r0 = g0 >> 2, c0 = (g0 & 3) * 8;
  int r1 = g1 >> 2, c1 = (g1 & 3) * 8;
  int ml = lane & 15, q = lane >> 4;

  for (int k0 = 0; k0 < K; k0 += 32){
    short8 av0 = *(const short8*)&Ab[(long)(bm+r0)*lda + k0 + c0];
    short8 av1 = *(const short8*)&Ab[(long)(bm+r1)*lda + k0 + c1];
    short8 bv0 = *(const short8*)&Bb[(long)(bn+r0)*ldw + k0 + c0];
    short8 bv1 = *(const short8*)&Bb[(long)(bn+r1)*ldw + k0 + c1];
    __syncthreads();
    *(short8*)&As[r0*LP + c0] = av0;
    *(short8*)&As[r1*LP + c1] = av1;
    *(short8*)&Bs[r0*LP + c0] = bv0;
    *(short8*)&Bs[r1*LP + c1] = bv1;
    __syncthreads();
    short8 af[4], bfv[4];
    #pragma unroll
    for (int i=0;i<4;i++) af[i]  = *(const short8*)&As[(wm + 16*i + ml)*LP + q*8];
    #pragma unroll
    for (int j=0;j<4;j++) bfv[j] = *(const short8*)&Bs[(wn + 16*j + ml)*LP + q*8];
    #pragma unroll
    for (int i=0;i<4;i++)
      #pragma unroll
      for (int j=0;j<4;j++)
        acc[i][j] = __builtin_amdgcn_mfma_f32_16x16x32_bf16(af[i], bfv[j], acc[i][j], 0,0,0);
  }

  const float* biasz = bias ? bias + (long)z*sB : nullptr;
  const float* Rz = R ? R + (long)z*sR : nullptr;
  long coff = (long)z*sC;
  #pragma unroll
  for (int i=0;i<4;i++){
    #pragma unroll
    for (int r=0;r<4;r++){
      int gm = bm + wm + 16*i + q*4 + r;
      #pragma unroll
      for (int j=0;j<4;j++){
        int gn = bn + wn + 16*j + ml;
        float v = acc[i][j][r];
        if (biasz){
          int bi;
          if (bsplit){
            if (gn < bsplit) bi = gn;
            else if (gn >= bsplitPad && gn < bsplitPad + (nbias - bsplit)) bi = gn - (bsplitPad - bsplit);
            else bi = -1;
          } else bi = (gn < nbias) ? gn : -1;
          if (bi >= 0) v += biasz[bi];
        }
        if (act == 2) v = (v > 0.f) ? v : 0.01f*v;
        if (Rz) v += Rz[(long)gm*ldr + gn];
        if (cIsBf16) ((__hip_bfloat16*)C)[coff + (long)gm*ldc + gn] = __float2bfloat16(v);
        else         ((float*)C)[coff + (long)gm*ldc + gn] = v;
      }
    }
  }
}

// ---------------- weight transpose+convert (single bf16 out, z-batched)
__global__ __launch_bounds__(256) void convT_kernel(
    const float* __restrict__ W, int N, int K, long sW,
    __hip_bfloat16* __restrict__ out, int Npad, int Kpad, long sO,
    int split, int splitPad)
{
  int z = blockIdx.z;
  int n0 = blockIdx.x*64, k0 = blockIdx.y*64;
  int tid = threadIdx.x;
  __shared__ float lds[64][65];
  #pragma unroll
  for (int i=0;i<16;i++){
    int e = tid + i*256;
    int kl = e >> 6, c = e & 63;
    int np = n0 + c;
    int ns;
    if (split){
      if (np < split) ns = np;
      else if (np >= splitPad && np < splitPad + (N - split)) ns = np - (splitPad - split);
      else ns = -1;
    } else ns = (np < N) ? np : -1;
    int k = k0 + kl;
    float v = (ns >= 0 && k < K) ? W[(long)z*sW + (long)k*N + ns] : 0.f;
    lds[kl][c] = v;
  }
  __syncthreads();
  #pragma unroll
  for (int i=0;i<16;i++){
    int e = tid + i*256;
    int nl = e >> 6, kl = e & 63;
    out[(long)z*sO + (long)(n0+nl)*Kpad + k0 + kl] = __float2bfloat16(lds[kl][nl]);
  }
}

// ---------------- weight transpose+convert with hi/lo split
__global__ __launch_bounds__(256) void convT2_kernel(
    const float* __restrict__ W, int N, int K,
    __hip_bfloat16* __restrict__ outh, __hip_bfloat16* __restrict__ outl,
    int Npad, int Kpad, int split, int splitPad)
{
  int n0 = blockIdx.x*64, k0 = blockIdx.y*64;
  int tid = threadIdx.x;
  __shared__ float lds[64][65];
  #pragma unroll
  for (int i=0;i<16;i++){
    int e = tid + i*256;
    int kl = e >> 6, c = e & 63;
    int np = n0 + c;
    int ns;
    if (split){
      if (np < split) ns = np;
      else if (np >= splitPad && np < splitPad + (N - split)) ns = np - (splitPad - split);
      else ns = -1;
    } else ns = (np < N) ? np : -1;
    int k = k0 + kl;
    float v = (ns >= 0 && k < K) ? W[(long)k*N + ns] : 0.f;
    lds[kl][c] = v;
  }
  __syncthreads();
  #pragma unroll
  for (int i=0;i<16;i++){
    int e = tid + i*256;
    int nl = e >> 6, kl = e & 63;
    float v = lds[kl][nl];
    __hip_bfloat16 h, l; split2(v, h, l);
    long o = (long)(n0+nl)*Kpad + k0 + kl;
    outh[o] = h; outl[o] = l;
  }
}

// ---------------- bias pack for z-batched QKV
__global__ void pack_bias_kernel(const float* bq, const float* bk, const float* bv, float* out){
  int i = blockIdx.x*256 + threadIdx.x;
  if (i < 256) out[i] = bq[i];
  else if (i < 512) out[i] = bk[i-256];
  else if (i < 768) out[i] = bv[i-512];
}

// ---------------- attention split-K
__global__ __launch_bounds__(256) void attn_split_kernel(
    const float* __restrict__ qp, const float* __restrict__ kp,
    const float* __restrict__ vp,
    float* __restrict__ po, float* __restrict__ pm, float* __restrict__ pl)
{
  int bh = blockIdx.y; int bb = bh >> 3; int h = bh & 7;
  int kc = blockIdx.z;
  int qi = blockIdx.x*256 + threadIdx.x;
  const float scale = 0.17677669529663687f;
  float qreg[32];
  const float* qptr = qp + (((bb<<10)+qi)<<8) + (h<<5);
  #pragma unroll
  for (int d=0;d<32;d++) qreg[d] = qptr[d];
  float m = -INFINITY, l = 0.f;
  float oacc[32];
  #pragma unroll
  for (int d=0;d<32;d++) oacc[d] = 0.f;

  __shared__ float Ks[64][32];
  __shared__ float Vs[64][32];
  int jbase = kc*256;
  for (int j0=jbase; j0<jbase+256; j0+=64){
    __syncthreads();
    #pragma unroll
    for (int i=0;i<8;i++){
      int e = threadIdx.x + i*256;
      int j = e >> 5, d = e & 31;
      int base = (((bb<<10)+j0+j)<<8) + (h<<5) + d;
      Ks[j][d] = kp[base];
      Vs[j][d] = vp[base];
    }
    __syncthreads();
    for (int j=0;j<64;j++){
      float s = 0.f;
      #pragma unroll
      for (int d=0;d<32;d++) s += qreg[d]*Ks[j][d];
      s *= scale;
      if (s > m){
        float corr = expf(m - s);
        l = l*corr + 1.f;
        #pragma unroll
        for (int d=0;d<32;d++) oacc[d] = oacc[d]*corr + Vs[j][d];
        m = s;
      } else {
        float p = expf(s - m);
        l += p;
        #pragma unroll
        for (int d=0;d<32;d++) oacc[d] += p*Vs[j][d];
      }
    }
  }
  int r = (bh<<10) + qi;
  pm[kc*32768 + r] = m;
  pl[kc*32768 + r] = l;
  float* pop = po + ((long)kc*32768 + r)*32;
  #pragma unroll
  for (int d=0;d<32;d++) pop[d] = oacc[d];
}

__global__ __launch_bounds__(256) void attn_merge_kernel(
    const float* __restrict__ po, const float* __restrict__ pm,
    const float* __restrict__ pl,
    __hip_bfloat16* __restrict__ aohi, __hip_bfloat16* __restrict__ aolo)
{
  int r = blockIdx.x*256 + threadIdx.x;
  float mz[4], wz[4];
  float M = -INFINITY;
  #pragma unroll
  for (int zc=0;zc<4;zc++){ mz[zc] = pm[zc*32768 + r]; M = fmaxf(M, mz[zc]); }
  float L = 0.f;
  #pragma unroll
  for (int zc=0;zc<4;zc++){ wz[zc] = expf(mz[zc] - M); L += pl[zc*32768 + r]*wz[zc]; }
  float inv = 1.f / L;
  int bh = r >> 10, qi = r & 1023;
  int bb = bh >> 3, h = bh & 7;
  int base = (((bb<<10)+qi)<<8) + (h<<5);
  for (int d=0; d<32; d++){
    float s = 0.f;
    #pragma unroll
    for (int zc=0;zc<4;zc++) s += wz[zc]*po[((long)zc*32768 + r)*32 + d];
    float val = s*inv;
    __hip_bfloat16 hh, ll; split2(val, hh, ll);
    aohi[base+d] = hh; aolo[base+d] = ll;
  }
}

// ---------------- concat queries into x[:, 256:512]
__global__ __launch_bounds__(256) void concat_kernel(
    const float* __restrict__ queries, float* __restrict__ x)
{
  int idx = blockIdx.x*256 + threadIdx.x;
  int d = idx & 255; int r = idx >> 8;
  x[(r<<9) + 256 + d] = queries[idx];
}

// ---------------- rmsnorm fp32 out
__global__ __launch_bounds__(256) void rmsnorm_kernel(
    const float* __restrict__ x, const float* __restrict__ g, float* __restrict__ y)
{
  int r = blockIdx.x; int tid = threadIdx.x;
  float v0 = x[(r<<9) + tid];
  float v1 = x[(r<<9) + 256 + tid];
  float ss = v0*v0 + v1*v1;
  #pragma unroll
  for (int off=32; off>0; off>>=1) ss += __shfl_down(ss, off, 64);
  __shared__ float wsum[4];
  if ((tid & 63) == 0) wsum[tid>>6] = ss;
  __syncthreads();
  float tot = wsum[0]+wsum[1]+wsum[2]+wsum[3];
  float scale = 22.62741699796952f / fmaxf(sqrtf(tot), 1e-12f);
  y[(r<<9) + tid]       = v0*scale*g[tid];
  y[(r<<9) + 256 + tid] = v1*scale*g[256+tid];
}

// ---------------- rmsnorm hi/lo out
__global__ __launch_bounds__(256) void rmsnorm_split_kernel(
    const float* __restrict__ x, const float* __restrict__ g,
    __hip_bfloat16* __restrict__ yh, __hip_bfloat16* __restrict__ yl)
{
  int r = blockIdx.x; int tid = threadIdx.x;
  float v0 = x[(r<<9) + tid];
  float v1 = x[(r<<9) + 256 + tid];
  float ss = v0*v0 + v1*v1;
  #pragma unroll
  for (int off=32; off>0; off>>=1) ss += __shfl_down(ss, off, 64);
  __shared__ float wsum[4];
  if ((tid & 63) == 0) wsum[tid>>6] = ss;
  __syncthreads();
  float tot = wsum[0]+wsum[1]+wsum[2]+wsum[3];
  float scale = 22.62741699796952f / fmaxf(sqrtf(tot), 1e-12f);
  float a = v0*scale*g[tid];
  float b = v1*scale*g[256+tid];
  __hip_bfloat16 h, l;
  split2(a, h, l); yh[(r<<9)+tid] = h;     yl[(r<<9)+tid] = l;
  split2(b, h, l); yh[(r<<9)+256+tid] = h; yl[(r<<9)+256+tid] = l;
}

// ---------------- rmsnorm bf16 out (ffa path)
__global__ __launch_bounds__(256) void rmsnorm_bf_kernel(
    const float* __restrict__ x, const float* __restrict__ g, __hip_bfloat16* __restrict__ y)
{
  int r = blockIdx.x; int tid = threadIdx.x;
  float v0 = x[(r<<9) + tid];
  float v1 = x[(r<<9) + 256 + tid];
  float ss = v0*v0 + v1*v1;
  #pragma unroll
  for (int off=32; off>0; off>>=1) ss += __shfl_down(ss, off, 64);
  __shared__ float wsum[4];
  if ((tid & 63) == 0) wsum[tid>>6] = ss;
  __syncthreads();
  float tot = wsum[0]+wsum[1]+wsum[2]+wsum[3];
  float scale = 22.62741699796952f / fmaxf(sqrtf(tot), 1e-12f);
  y[(r<<9) + tid]       = __float2bfloat16(v0*scale*g[tid]);
  y[(r<<9) + 256 + tid] = __float2bfloat16(v1*scale*g[256+tid]);
}

// ---------------- geglu glu: H fp32 padded [4096][2816] -> T hi/lo [4096][1408]
__global__ __launch_bounds__(256) void glu_split_kernel(
    const float* __restrict__ h, const float* __restrict__ mult,
    __hip_bfloat16* __restrict__ th, __hip_bfloat16* __restrict__ tl)
{
  int idx = blockIdx.x*256 + threadIdx.x;   // 4096*1408
  int r = idx / 1408; int j = idx - r*1408;
  float v = 0.f;
  if (j < 1365){
    float a  = h[(long)r*2816 + j];
    float gt = h[(long)r*2816 + 1408 + j];
    v = gelu_f(gt) * a * mult[j];
  }
  __hip_bfloat16 hh, ll; split2(v, hh, ll);
  th[idx] = hh; tl[idx] = ll;
}

// ---------------- geglu glu bf16 (ffa path)
__global__ __launch_bounds__(256) void glu_bf_kernel(
    const __hip_bfloat16* __restrict__ h, const float* __restrict__ mult,
    __hip_bfloat16* __restrict__ t)
{
  int idx = blockIdx.x*256 + threadIdx.x;   // 4096*1408
  int r = idx / 1408; int j = idx - r*1408;
  float v = 0.f;
  if (j < 1365){
    float a  = __bfloat162float(h[(long)r*2816 + j]);
    float gt = __bfloat162float(h[(long)r*2816 + 1408 + j]);
    v = gelu_f(gt) * a * mult[j];
  }
  t[idx] = __float2bfloat16(v);
}

// ---------------- split fp32 -> hi/lo
__global__ __launch_bounds__(256) void split32_kernel(
    const float* __restrict__ x, __hip_bfloat16* __restrict__ h, __hip_bfloat16* __restrict__ l)
{
  int idx = blockIdx.x*256 + threadIdx.x;
  float v = x[idx];
  __hip_bfloat16 hh, ll; split2(v, hh, ll);
  h[idx] = hh; l[idx] = ll;
}

// ---------------- MoE init
__global__ __launch_bounds__(256) void moe_init_kernel(
    int* ts1, int* ts2, int* slot_token, float* sum_raw, float* z_sum)
{
  int i = blockIdx.x*256 + threadIdx.x;
  if (i < 4096){ ts1[i] = -1; ts2[i] = -1; }
  if (i < 8192) slot_token[i] = -1;
  if (i < 64)  sum_raw[i] = 0.f;
  if (i == 0)  *z_sum = 0.f;
}

// ---------------- gating
__global__ __launch_bounds__(256) void gating_kernel(
    const float* __restrict__ xn, const float* __restrict__ gate_w,
    int* __restrict__ idx1, int* __restrict__ idx2, int* __restrict__ route,
    float* __restrict__ gg1, float* __restrict__ gg2,
    float* __restrict__ sum_raw, float* __restrict__ z_sum)
{
  int t = blockIdx.x; int tid = threadIdx.x;
  __shared__ float xrow[512];
  xrow[tid]     = xn[(t<<9)+tid];
  xrow[256+tid] = xn[(t<<9)+256+tid];
  __syncthreads();
  int e = tid >> 4, l16 = tid & 15;
  float p = 0.f;
  for (int d=l16; d<512; d+=16) p += xrow[d]*gate_w[(e<<9)+d];
  __shared__ float part[16][17];
  part[e][l16] = p;
  __syncthreads();
  __shared__ float raw[16];
  if (tid < 16){
    float s = 0.f;
    #pragma unroll
    for (int i=0;i<16;i++) s += part[tid][i];
    raw[tid] = s;
  }
  __syncthreads();
  if (tid == 0){
    float mx = -1e30f;
    #pragma unroll
    for (int i=0;i<16;i++) mx = fmaxf(mx, raw[i]);
    float r[16]; float sum = 0.f;
    #pragma unroll
    for (int i=0;i<16;i++){ r[i] = expf(raw[i]-mx); sum += r[i]; }
    float lse = mx + logf(sum);
    atomicAdd(z_sum, lse*lse);
    float inv = 1.f/sum;
    #pragma unroll
    for (int i=0;i<16;i++){ r[i] *= inv; raw[i] = r[i]; }
    int i1 = -1; float b1 = -1.f;
    #pragma unroll
    for (int i=0;i<16;i++) if (r[i] > b1){ b1 = r[i]; i1 = i; }
    int i2 = -1; float b2 = -1.f;
    #pragma unroll
    for (int i=0;i<16;i++) if (i != i1 && r[i] > b2){ b2 = r[i]; i2 = i; }
    float s2 = fmaxf(b1 + b2, 1e-9f);
    float g1n = b1/s2, g2n = b2/s2;
    idx1[t] = i1; idx2[t] = i2;
    route[t] = (g2n > 0.2f) ? 1 : 0;
    gg1[t] = g1n; gg2[t] = g2n;
  }
  __syncthreads();
  int bb = t >> 10;
  if (tid < 16) atomicAdd(&sum_raw[(bb<<4)+tid], raw[tid]);
}

// ---------------- capacity scan (LDS-staged)
__global__ __launch_bounds__(256) void scan_kernel(
    const int* __restrict__ idx1, const int* __restrict__ idx2, const int* __restrict__ route,
    int* __restrict__ ts1, int* __restrict__ ts2, int* __restrict__ slot_token,
    int* __restrict__ count1)
{
  int bb = blockIdx.x;
  __shared__ int li1[1024], li2[1024], lr[1024];
  for (int i=threadIdx.x; i<1024; i+=256){
    int t = (bb<<10)+i;
    li1[i] = idx1[t]; li2[i] = idx2[t]; lr[i] = route[t];
  }
  __syncthreads();
  int e = threadIdx.x;
  if (e >= 16) return;
  int cnt = 0;
  for (int n=0;n<1024;n++){
    if (li1[n] == e){
      int t = (bb<<10)+n;
      if (cnt < CAPN){ int slot = ((e<<2)+bb)*CAPN + cnt; ts1[t] = slot; slot_token[slot] = t; }
      else ts1[t] = -1;
      cnt++;
    }
  }
  count1[(bb<<4)+e] = cnt;
  int c2 = cnt;
  for (int n=0;n<1024;n++){
    if (li2[n] == e && lr[n]){
      int t = (bb<<10)+n;
      if (c2 < CAPN){ int slot = ((e<<2)+bb)*CAPN + c2; ts2[t] = slot; slot_token[slot] = t; }
      c2++;
    }
  }
}

// ---------------- gather + layernorm -> xin bf16
__global__ __launch_bounds__(256) void gather_ln_kernel(
    const float* __restrict__ xn, const int* __restrict__ slot_token,
    const float* __restrict__ ln_g, const float* __restrict__ ln_b,
    __hip_bfloat16* __restrict__ xin)
{
  int s = blockIdx.x; int tid = threadIdx.x;
  int t = slot_token[s];
  int e = s >> 9;
  if (t < 0){
    xin[(s<<9)+tid] = __float2bfloat16(0.f);
    xin[(s<<9)+256+tid] = __float2bfloat16(0.f);
    return;
  }
  float v0 = xn[(t<<9)+tid];
  float v1 = xn[(t<<9)+256+tid];
  float sm = v0+v1, sq = v0*v0+v1*v1;
  #pragma unroll
  for (int off=32; off>0; off>>=1){
    sm += __shfl_down(sm, off, 64);
    sq += __shfl_down(sq, off, 64);
  }
  __shared__ float s1[4], s2buf[4];
  if ((tid & 63) == 0){ s1[tid>>6] = sm; s2buf[tid>>6] = sq; }
  __syncthreads();
  float tsm = s1[0]+s1[1]+s1[2]+s1[3];
  float tsq = s2buf[0]+s2buf[1]+s2buf[2]+s2buf[3];
  float mean = tsm * (1.f/512.f);
  float var = tsq * (1.f/512.f) - mean*mean;
  float rstd = rsqrtf(var + 1e-5f);
  xin[(s<<9)+tid]     = __float2bfloat16((v0-mean)*rstd*ln_g[(e<<9)+tid]     + ln_b[(e<<9)+tid]);
  xin[(s<<9)+256+tid] = __float2bfloat16((v1-mean)*rstd*ln_g[(e<<9)+256+tid] + ln_b[(e<<9)+256+tid]);
}

// ---------------- combine (in-place)
__global__ __launch_bounds__(256) void combine_kernel(
    float* __restrict__ x, const float* __restrict__ h2,
    const int* __restrict__ ts1, const int* __restrict__ ts2,
    const float* __restrict__ gg1, const float* __restrict__ gg2)
{
  int idx = blockIdx.x*256 + threadIdx.x;
  int t = idx >> 9; int d = idx & 511;
  float v = x[idx];
  int s1 = ts1[t]; if (s1 >= 0) v += gg1[t]*h2[(s1<<9)+d];
  int s2 = ts2[t]; if (s2 >= 0) v += gg2[t]*h2[(s2<<9)+d];
  x[idx] = v;
}

// ---------------- aux losses
__global__ void aux_kernel(
    const float* __restrict__ sum_raw, const int* __restrict__ count1,
    const float* __restrict__ z_sum, float* __restrict__ out)
{
  int tid = threadIdx.x;
  float v = (sum_raw[tid] * (1.f/1024.f)) * ((float)count1[tid] * (1.f/1024.f));
  #pragma unroll
  for (int off=32; off>0; off>>=1) v += __shfl_down(v, off, 64);
  if (tid == 0){
    float bal = v * (1.f/64.f) * 256.f * 0.01f;
    float zl = (*z_sum) * (1.f/4096.f) * 0.001f;
    out[0] = bal + zl;
    out[1] = bal;
    out[2] = zl;
  }
}

extern "C" void kernel_launch(void* const* d_in, const int* in_sizes, int n_in,
                              void* d_out, int out_size, void* d_ws, size_t ws_size,
                              hipStream_t stream)
{
  const float* K_in   = (const float*)d_in[0];
  const float* V_in   = (const float*)d_in[1];
  const float* Q_in   = (const float*)d_in[2];
  const float* w_topo = (const float*)d_in[3];
  const float* b_topo = (const float*)d_in[4];
  const float* w_val  = (const float*)d_in[5];
  const float* b_val  = (const float*)d_in[6];
  const float* wq     = (const float*)d_in[7];
  const float* bq     = (const float*)d_in[8];
  const float* wk     = (const float*)d_in[9];
  const float* bk     = (const float*)d_in[10];
  const float* wv     = (const float*)d_in[11];
  const float* bv     = (const float*)d_in[12];
  const float* wo     = (const float*)d_in[13];
  const float* bo     = (const float*)d_in[14];
  const float* ffb_g  = (const float*)d_in[15];
  const float* ffb_w1 = (const float*)d_in[16];
  const float* ffb_b1 = (const float*)d_in[17];
  const float* ffb_mult=(const float*)d_in[18];
  const float* ffb_w2 = (const float*)d_in[19];
  const float* ffb_b2 = (const float*)d_in[20];
  const float* prenorm_g=(const float*)d_in[21];
  const float* gate_w = (const float*)d_in[22];
  const float* exp_ln_g=(const float*)d_in[23];
  const float* exp_ln_b=(const float*)d_in[24];
  const float* exp_w1 = (const float*)d_in[25];
  const float* exp_b1 = (const float*)d_in[26];
  const float* exp_w2 = (const float*)d_in[27];
  const float* exp_b2 = (const float*)d_in[28];
  const float* ffa_g  = (const float*)d_in[29];
  const float* ffa_w1 = (const float*)d_in[30];
  const float* ffa_b1 = (const float*)d_in[31];
  const float* ffa_mult=(const float*)d_in[32];
  const float* ffa_w2 = (const float*)d_in[33];
  const float* ffa_b2 = (const float*)d_in[34];
  const float* w_out  = (const float*)d_in[35];
  const float* b_out  = (const float*)d_in[36];
  float* dout = (float*)d_out;

  float* wsf = (float*)d_ws;
  int*   wsi = (int*)d_ws;

  // ---- layout (float offsets) ----
  const size_t A0 = 0;              // region A: 11,534,336 fl
  const size_t B0 = 11534336;       // region B:  5,767,168 fl (ends at OXA)
  const size_t OXA = 17301504;      // 2,097,152
  const size_t OXB = 19398656;      // 2,097,152
  const size_t OWP = 21495808;      // persistent split weights (393,216 fl)
  const size_t OMI = 21889024;      // misc

  // region A (early phases)
  __hip_bfloat16* qhi = (__hip_bfloat16*)(wsf + A0);
  __hip_bfloat16* khi = (__hip_bfloat16*)(wsf + A0 + 524288);
  __hip_bfloat16* vhi = (__hip_bfloat16*)(wsf + A0 + 1048576);
  __hip_bfloat16* qlo = (__hip_bfloat16*)(wsf + A0 + 1572864);
  __hip_bfloat16* klo = (__hip_bfloat16*)(wsf + A0 + 2097152);
  __hip_bfloat16* vlo = (__hip_bfloat16*)(wsf + A0 + 2621440);
  float* QP = wsf + A0 + 3145728;                         // 3x 1048576
  __hip_bfloat16* aohi = (__hip_bfloat16*)(wsf + A0 + 6291456);
  __hip_bfloat16* aolo = (__hip_bfloat16*)(wsf + A0 + 6815744);
  float* PO = wsf + A0 + 7340032;                         // 4194304 fl, ends 11534336
  // region B (early phases)
  float* PM = wsf + B0;                                   // 131072
  float* PL = wsf + B0 + 131072;                          // 131072
  float* QF = wsf + B0 + 262144;                          // 1048576, ends B0+1310720
  // phase 5 (ffb): region A holds Hb; region B sequenced in two waves
  float* Hb = wsf + A0;                                   // fp32 [4096][2816] = 11534336 fl
  __hip_bfloat16* yh   = (__hip_bfloat16*)(wsf + B0);                 // 1048576 fl
  __hip_bfloat16* yl   = (__hip_bfloat16*)(wsf + B0 + 1048576);       // 1048576 fl
  __hip_bfloat16* fw1h = (__hip_bfloat16*)(wsf + B0 + 2097152);       // 720896 fl
  __hip_bfloat16* fw1l = fw1h + 1441792;                              // 720896 fl, ends B0+3538944
  __hip_bfloat16* th   = (__hip_bfloat16*)(wsf + B0);                 // 2883584 fl (after GEMM1)
  __hip_bfloat16* tl   = (__hip_bfloat16*)(wsf + B0 + 2883584);       // 2883584 fl, ends B0+5767168
  __hip_bfloat16* fw2h = (__hip_bfloat16*)(wsf + A0);                 // 360448 fl (after glu; Hb dead)
  __hip_bfloat16* fw2l = fw2h + 720896;                               // ends A0+720896
  // phase 6 (MoE)
  __hip_bfloat16* wte   = (__hip_bfloat16*)(wsf + A0);                // 5767168 fl
  __hip_bfloat16* xin_bf= (__hip_bfloat16*)(wsf + A0 + 5767168);      // 2097152 fl
  __hip_bfloat16* h1_bf = (__hip_bfloat16*)(wsf + A0 + 7864320);      // 5767168 fl, ends 13631488 (over YM tail, ordered OK)
  float* H2 = wsf + 13631488;        // 4194304 fl, ends 17825792 (spills into dead OXA head)
  float* YM = wsf + B0;              // 2097152 fl (dead before h1_bf written)
  // phase 7 (ffa)
  __hip_bfloat16* y_bf = (__hip_bfloat16*)(wsf + A0);
  __hip_bfloat16* wf1  = (__hip_bfloat16*)(wsf + A0 + 1048576);
  __hip_bfloat16* h_bf = (__hip_bfloat16*)(wsf + A0 + 1769472);
  __hip_bfloat16* t_bf = (__hip_bfloat16*)(wsf + A0 + 7536640);
  __hip_bfloat16* wf2  = (__hip_bfloat16*)(wsf + A0 + 10420224);
  // phase 8
  __hip_bfloat16* xah = (__hip_bfloat16*)(wsf + A0);                  // 1048576 fl
  __hip_bfloat16* xal = (__hip_bfloat16*)(wsf + A0 + 1048576);        // 1048576 fl
  // persistent weights (bf16 element offsets from wp)
  __hip_bfloat16* wp = (__hip_bfloat16*)(wsf + OWP);
  __hip_bfloat16* wqh = wp;            __hip_bfloat16* wkh = wp + 65536;
  __hip_bfloat16* wvh = wp + 131072;   __hip_bfloat16* wql = wp + 196608;
  __hip_bfloat16* wkl = wp + 262144;   __hip_bfloat16* wvl = wp + 327680;
  __hip_bfloat16* woh = wp + 393216;   __hip_bfloat16* wol = wp + 458752;
  __hip_bfloat16* wouth = wp + 524288; __hip_bfloat16* woutl = wp + 655360;

  int* idx1 = wsi + OMI + 0;
  int* idx2 = wsi + OMI + 4096;
  int* route= wsi + OMI + 8192;
  int* ts1  = wsi + OMI + 12288;
  int* ts2  = wsi + OMI + 16384;
  int* slot_token = wsi + OMI + 20480;
  int* count1     = wsi + OMI + 28672;
  float* sum_raw  = wsf + OMI + 28736;
  float* z_sum    = wsf + OMI + 28800;
  float* gg1      = wsf + OMI + 28864;
  float* gg2      = wsf + OMI + 32960;
  float* bias_qkv = wsf + OMI + 37056;   // 768

  // ---- phase 0: static weight conversions ----
  convT2_kernel<<<dim3(4,4),  256, 0, stream>>>(wq, 256, 256, wqh, wql, 256, 256, 0, 0);
  convT2_kernel<<<dim3(4,4),  256, 0, stream>>>(wk, 256, 256, wkh, wkl, 256, 256, 0, 0);
  convT2_kernel<<<dim3(4,4),  256, 0, stream>>>(wv, 256, 256, wvh, wvl, 256, 256, 0, 0);
  convT2_kernel<<<dim3(4,4),  256, 0, stream>>>(wo, 256, 256, woh, wol, 256, 256, 0, 0);
  convT2_kernel<<<dim3(4,8),  256, 0, stream>>>(w_out, 256, 512, wouth, woutl, 256, 512, 0, 0);
  convT2_kernel<<<dim3(44,8), 256, 0, stream>>>(ffb_w1, 2730, 512, fw1h, fw1l, 2816, 512, 1365, 1408);
  pack_bias_kernel<<<3, 256, 0, stream>>>(bq, bk, bv, bias_qkv);

  // ---- phase 1: topo / values ----
  topo_kernel<<<8192, 256, 0, stream>>>(K_in, Q_in, w_topo, b_topo, khi, klo, qhi, qlo, QF);
  values_kernel<<<4096, 256, 0, stream>>>(V_in, w_val, b_val, vhi, vlo);

  // ---- phase 2: QKV projections (split MFMA, z-batched) ----
  sgemm_kernel<<<dim3(2,32,3), 256, 0, stream>>>(
      qhi, qlo, 256, 1048576, wqh, wql, 256, 65536,
      bias_qkv, 256, 0, 0, 256, nullptr, 0, QP, 256, 1048576, 256, 0);

  // ---- phase 3: attention ----
  attn_split_kernel<<<dim3(4,32,4), 256, 0, stream>>>(QP, QP+1048576, QP+2097152, PO, PM, PL);
  attn_merge_kernel<<<128, 256, 0, stream>>>(PO, PM, PL, aohi, aolo);

  // ---- phase 4: o-proj into XA[:, :256] + concat queries ----
  sgemm_kernel<<<dim3(2,32,1), 256, 0, stream>>>(
      aohi, aolo, 256, 0, woh, wol, 256, 0,
      bo, 256, 0, 0, 0, nullptr, 0, wsf+OXA, 512, 0, 256, 0);
  concat_kernel<<<4096, 256, 0, stream>>>(QF, wsf+OXA);

  // ---- phase 5: ffb geglu (split MFMA) ----
  rmsnorm_split_kernel<<<4096, 256, 0, stream>>>(wsf+OXA, ffb_g, yh, yl);
  sgemm_kernel<<<dim3(22,32,1), 256, 0, stream>>>(
      yh, yl, 512, 0, fw1h, fw1l, 512, 0,
      ffb_b1, 2730, 1365, 1408, 0, nullptr, 0, Hb, 2816, 0, 512, 0);
  glu_split_kernel<<<22528, 256, 0, stream>>>(Hb, ffb_mult, th, tl);
  convT2_kernel<<<dim3(8,22), 256, 0, stream>>>(ffb_w2, 512, 1365, fw2h, fw2l, 512, 1408, 0, 0);
  sgemm_kernel<<<dim3(4,32,1), 256, 0, stream>>>(
      th, tl, 1408, 0, fw2h, fw2l, 1408, 0,
      ffb_b2, 512, 0, 0, 0, wsf+OXA, 512, wsf+OXB, 512, 0, 1408, 0);

  // ---- phase 6: MoE ----
  rmsnorm_kernel<<<4096, 256, 0, stream>>>(wsf+OXB, prenorm_g, YM);
  moe_init_kernel<<<32, 256, 0, stream>>>(ts1, ts2, slot_token, sum_raw, z_sum);
  gating_kernel<<<4096, 256, 0, stream>>>(YM, gate_w, idx1, idx2, route, gg1, gg2, sum_raw, z_sum);
  scan_kernel<<<4, 256, 0, stream>>>(idx1, idx2, route, ts1, ts2, slot_token, count1);
  gather_ln_kernel<<<8192, 256, 0, stream>>>(YM, slot_token, exp_ln_g, exp_ln_b, xin_bf);
  convT_kernel<<<dim3(22, 8, 16), 256, 0, stream>>>(exp_w1, 1365, 512, (long)512*1365,
                                                    wte, 1408, 512, (long)1408*512, 0, 0);
  bgemm_kernel<<<dim3(11,4,16), 256, 0, stream>>>(
      xin_bf, 512, (long)512*512, wte, 512, (long)1408*512,
      exp_b1, 1365, 0, 0, 1365, nullptr, 0, 0,
      h1_bf, 1408, (long)512*1408, 1, 512, 2);
  convT_kernel<<<dim3(8, 22, 16), 256, 0, stream>>>(exp_w2, 512, 1365, (long)1365*512,
                                                    wte, 512, 1408, (long)512*1408, 0, 0);
  bgemm_kernel<<<dim3(4,4,16), 256, 0, stream>>>(
      h1_bf, 1408, (long)512*1408, wte, 1408, (long)512*1408,
      exp_b2, 512, 0, 0, 512, nullptr, 0, 0,
      H2, 512, (long)512*512, 0, 1408, 0);
  combine_kernel<<<8192, 256, 0, stream>>>(wsf+OXB, H2, ts1, ts2, gg1, gg2);
  aux_kernel<<<1, 64, 0, stream>>>(sum_raw, count1, z_sum, dout + 4096*256);

  // ---- phase 7: ffa geglu (bf16 MFMA) ----
  rmsnorm_bf_kernel<<<4096, 256, 0, stream>>>(wsf+OXB, ffa_g, y_bf);
  convT_kernel<<<dim3(44, 8, 1), 256, 0, stream>>>(ffa_w1, 2730, 512, 0,
                                                   wf1, 2816, 512, 0, 1365, 1408);
  bgemm_kernel<<<dim3(22,32,1), 256, 0, stream>>>(
      y_bf, 512, 0, wf1, 512, 0,
      ffa_b1, 2730, 1365, 1408, 0, nullptr, 0, 0,
      h_bf, 2816, 0, 1, 512, 0);
  glu_bf_kernel<<<22528, 256, 0, stream>>>(h_bf, ffa_mult, t_bf);
  convT_kernel<<<dim3(8, 22, 1), 256, 0, stream>>>(ffa_w2, 512, 1365, 0,
                                                   wf2, 512, 1408, 0, 0, 0);
  bgemm_kernel<<<dim3(4,32,1), 256, 0, stream>>>(
      t_bf, 1408, 0, wf2, 1408, 0,
      ffa_b2, 512, 0, 0, 0, wsf+OXB, 512, 0,
      wsf+OXA, 512, 0, 0, 1408, 0);

  // ---- phase 8: out = gelu(XA @ w_out + b_out) ----
  split32_kernel<<<8192, 256, 0, stream>>>(wsf+OXA, xah, xal);
  sgemm_kernel<<<dim3(2,32,1), 256, 0, stream>>>(
      xah, xal, 512, 0, wouth, woutl, 512, 0,
      b_out, 256, 0, 0, 0, nullptr, 0, dout, 256, 0, 512, 1);
}

// Round 5
// 1020.970 us; speedup vs baseline: 2.9707x; 1.2046x over previous
//
#include <hip/hip_runtime.h>
#include <hip/hip_bf16.h>
#include <math.h>

// B=4 S=1024 DM=256 H=8 HD=32 CIN=23 E=16 D2=512 HE=1365 2HE=2730 CAP=128
#define CAPN 128

typedef short short8 __attribute__((ext_vector_type(8)));
typedef float f32x4 __attribute__((ext_vector_type(4)));

__device__ __forceinline__ float gelu_f(float x){
  return 0.5f*x*(1.0f+erff(x*0.7071067811865476f));
}
__device__ __forceinline__ void split2(float v, __hip_bfloat16& h, __hip_bfloat16& l){
  h = __float2bfloat16(v);
  l = __float2bfloat16(v - __bfloat162float(h));
}

// ---------------- topo: gelu(cat([K,Q]) @ w + b) -> keys (hi/lo), queries (hi/lo + fp32)
__global__ __launch_bounds__(256) void topo_kernel(
    const float* __restrict__ K, const float* __restrict__ Q,
    const float* __restrict__ w, const float* __restrict__ b,
    __hip_bfloat16* __restrict__ khi, __hip_bfloat16* __restrict__ klo,
    __hip_bfloat16* __restrict__ qhi, __hip_bfloat16* __restrict__ qlo,
    float* __restrict__ qf32)
{
  int idx = blockIdx.x*256 + threadIdx.x;   // 2M
  int d = idx & 255;
  int r = idx >> 8;
  int bb = r >> 11;
  int n  = r & 2047;
  const float* src = (n < 1024) ? (K + ((bb<<10) + n)*3)
                                : (Q + ((bb<<10) + (n-1024))*3);
  float v = b[d] + src[0]*w[d] + src[1]*w[256+d] + src[2]*w[512+d];
  v = gelu_f(v);
  int off = (((bb<<10) + (n & 1023))<<8) + d;
  __hip_bfloat16 h, l; split2(v, h, l);
  if (n < 1024){ khi[off] = h; klo[off] = l; }
  else         { qhi[off] = h; qlo[off] = l; qf32[off] = v; }
}

// ---------------- values: gelu(V @ w_val + b_val) -> hi/lo
__global__ __launch_bounds__(256) void values_kernel(
    const float* __restrict__ V, const float* __restrict__ w,
    const float* __restrict__ b,
    __hip_bfloat16* __restrict__ vhi, __hip_bfloat16* __restrict__ vlo)
{
  int idx = blockIdx.x*256 + threadIdx.x;
  int d = idx & 255; int r = idx >> 8;
  const float* src = V + r*23;
  float acc = b[d];
  #pragma unroll
  for (int c=0;c<23;c++) acc += src[c]*w[c*256+d];
  acc = gelu_f(acc);
  __hip_bfloat16 h, l; split2(acc, h, l);
  vhi[idx] = h; vlo[idx] = l;
}

// ---------------- split-bf16 "fp32" MFMA GEMM: C = act(A@W + bias) (+R)
// acc = Ah*Wh + Ah*Wl + Al*Wh  (rel err ~1e-5). 128x128 tile, BK=32.
#define SLP 40
__global__ __launch_bounds__(256) void sgemm_kernel(
    const __hip_bfloat16* __restrict__ Ah_, const __hip_bfloat16* __restrict__ Al_,
    int lda, long sA,
    const __hip_bfloat16* __restrict__ Wh_, const __hip_bfloat16* __restrict__ Wl_,
    int ldw, long sW,
    const float* __restrict__ bias, int nbias, int bsplit, int bsplitPad, long sB,
    const float* __restrict__ R, int ldr,
    float* __restrict__ C, int ldc, long sC,
    int K, int act)
{
  int z = blockIdx.z;
  const short* Ah = (const short*)Ah_ + (long)z*sA;
  const short* Al = (const short*)Al_ + (long)z*sA;
  const short* Wh = (const short*)Wh_ + (long)z*sW;
  const short* Wl = (const short*)Wl_ + (long)z*sW;
  int bm = blockIdx.y*128, bn = blockIdx.x*128;
  int tid = threadIdx.x, lane = tid & 63, wave = tid >> 6;
  int wm = (wave & 1)*64, wn = (wave >> 1)*64;

  __shared__ short AsH[128*SLP], AsL[128*SLP], BsH[128*SLP], BsL[128*SLP];

  f32x4 acc[4][4];
  f32x4 zero4 = {0.f,0.f,0.f,0.f};
  #pragma unroll
  for (int i=0;i<4;i++)
    #pragma unroll
    for (int j=0;j<4;j++) acc[i][j] = zero4;

  int srow = tid >> 1, scol = (tid & 1)*16;
  int ml = lane & 15, q = lane >> 4;

  for (int k0 = 0; k0 < K; k0 += 32){
    long abase = (long)(bm+srow)*lda + k0 + scol;
    long bbase = (long)(bn+srow)*ldw + k0 + scol;
    short8 ah0 = *(const short8*)&Ah[abase];
    short8 ah1 = *(const short8*)&Ah[abase + 8];
    short8 al0 = *(const short8*)&Al[abase];
    short8 al1 = *(const short8*)&Al[abase + 8];
    short8 bh0 = *(const short8*)&Wh[bbase];
    short8 bh1 = *(const short8*)&Wh[bbase + 8];
    short8 bl0 = *(const short8*)&Wl[bbase];
    short8 bl1 = *(const short8*)&Wl[bbase + 8];
    __syncthreads();
    *(short8*)&AsH[srow*SLP + scol]     = ah0;
    *(short8*)&AsH[srow*SLP + scol + 8] = ah1;
    *(short8*)&AsL[srow*SLP + scol]     = al0;
    *(short8*)&AsL[srow*SLP + scol + 8] = al1;
    *(short8*)&BsH[srow*SLP + scol]     = bh0;
    *(short8*)&BsH[srow*SLP + scol + 8] = bh1;
    *(short8*)&BsL[srow*SLP + scol]     = bl0;
    *(short8*)&BsL[srow*SLP + scol + 8] = bl1;
    __syncthreads();
    short8 afh[4], afl[4], bfh[4], bfl[4];
    #pragma unroll
    for (int i=0;i<4;i++){
      afh[i] = *(const short8*)&AsH[(wm + 16*i + ml)*SLP + q*8];
      afl[i] = *(const short8*)&AsL[(wm + 16*i + ml)*SLP + q*8];
    }
    #pragma unroll
    for (int j=0;j<4;j++){
      bfh[j] = *(const short8*)&BsH[(wn + 16*j + ml)*SLP + q*8];
      bfl[j] = *(const short8*)&BsL[(wn + 16*j + ml)*SLP + q*8];
    }
    #pragma unroll
    for (int i=0;i<4;i++)
      #pragma unroll
      for (int j=0;j<4;j++){
        acc[i][j] = __builtin_amdgcn_mfma_f32_16x16x32_bf16(afh[i], bfh[j], acc[i][j], 0,0,0);
        acc[i][j] = __builtin_amdgcn_mfma_f32_16x16x32_bf16(afh[i], bfl[j], acc[i][j], 0,0,0);
        acc[i][j] = __builtin_amdgcn_mfma_f32_16x16x32_bf16(afl[i], bfh[j], acc[i][j], 0,0,0);
      }
  }

  const float* biasz = bias ? bias + (long)z*sB : nullptr;
  long coff = (long)z*sC;
  #pragma unroll
  for (int i=0;i<4;i++){
    #pragma unroll
    for (int r=0;r<4;r++){
      int gm = bm + wm + 16*i + q*4 + r;
      #pragma unroll
      for (int j=0;j<4;j++){
        int gn = bn + wn + 16*j + ml;
        float v = acc[i][j][r];
        if (biasz){
          int bi;
          if (bsplit){
            if (gn < bsplit) bi = gn;
            else if (gn >= bsplitPad && gn < bsplitPad + (nbias - bsplit)) bi = gn - (bsplitPad - bsplit);
            else bi = -1;
          } else bi = (gn < nbias) ? gn : -1;
          if (bi >= 0) v += biasz[bi];
        }
        if (act == 1) v = gelu_f(v);
        if (R) v += R[(long)gm*ldr + gn];
        C[coff + (long)gm*ldc + gn] = v;
      }
    }
  }
}

// ---------------- pure-bf16 MFMA GEMM (experts / ffa)
#define LP 56
__global__ __launch_bounds__(256) void bgemm_kernel(
    const __hip_bfloat16* __restrict__ A, int lda, long sA,
    const __hip_bfloat16* __restrict__ WT, int ldw, long sW,
    const float* __restrict__ bias, int nbias, int bsplit, int bsplitPad, long sB,
    const float* __restrict__ R, int ldr, long sR,
    void* __restrict__ C, int ldc, long sC, int cIsBf16,
    int K, int act)
{
  int z = blockIdx.z;
  const short* Ab = (const short*)A + (long)z*sA;
  const short* Bb = (const short*)WT + (long)z*sW;
  int bm = blockIdx.y*128, bn = blockIdx.x*128;
  int tid = threadIdx.x, lane = tid & 63, wave = tid >> 6;
  int wm = (wave & 1)*64, wn = (wave >> 1)*64;

  __shared__ short As[128*LP];
  __shared__ short Bs[128*LP];

  f32x4 acc[4][4];
  f32x4 zero4 = {0.f,0.f,0.f,0.f};
  #pragma unroll
  for (int i=0;i<4;i++)
    #pragma unroll
    for (int j=0;j<4;j++) acc[i][j] = zero4;

  int g0 = tid, g1 = tid + 256;
  int r0 = g0 >> 2, c0 = (g0 & 3) * 8;
  int r1 = g1 >> 2, c1 = (g1 & 3) * 8;
  int ml = lane & 15, q = lane >> 4;

  for (int k0 = 0; k0 < K; k0 += 32){
    short8 av0 = *(const short8*)&Ab[(long)(bm+r0)*lda + k0 + c0];
    short8 av1 = *(const short8*)&Ab[(long)(bm+r1)*lda + k0 + c1];
    short8 bv0 = *(const short8*)&Bb[(long)(bn+r0)*ldw + k0 + c0];
    short8 bv1 = *(const short8*)&Bb[(long)(bn+r1)*ldw + k0 + c1];
    __syncthreads();
    *(short8*)&As[r0*LP + c0] = av0;
    *(short8*)&As[r1*LP + c1] = av1;
    *(short8*)&Bs[r0*LP + c0] = bv0;
    *(short8*)&Bs[r1*LP + c1] = bv1;
    __syncthreads();
    short8 af[4], bfv[4];
    #pragma unroll
    for (int i=0;i<4;i++) af[i]  = *(const short8*)&As[(wm + 16*i + ml)*LP + q*8];
    #pragma unroll
    for (int j=0;j<4;j++) bfv[j] = *(const short8*)&Bs[(wn + 16*j + ml)*LP + q*8];
    #pragma unroll
    for (int i=0;i<4;i++)
      #pragma unroll
      for (int j=0;j<4;j++)
        acc[i][j] = __builtin_amdgcn_mfma_f32_16x16x32_bf16(af[i], bfv[j], acc[i][j], 0,0,0);
  }

  const float* biasz = bias ? bias + (long)z*sB : nullptr;
  const float* Rz = R ? R + (long)z*sR : nullptr;
  long coff = (long)z*sC;
  #pragma unroll
  for (int i=0;i<4;i++){
    #pragma unroll
    for (int r=0;r<4;r++){
      int gm = bm + wm + 16*i + q*4 + r;
      #pragma unroll
      for (int j=0;j<4;j++){
        int gn = bn + wn + 16*j + ml;
        float v = acc[i][j][r];
        if (biasz){
          int bi;
          if (bsplit){
            if (gn < bsplit) bi = gn;
            else if (gn >= bsplitPad && gn < bsplitPad + (nbias - bsplit)) bi = gn - (bsplitPad - bsplit);
            else bi = -1;
          } else bi = (gn < nbias) ? gn : -1;
          if (bi >= 0) v += biasz[bi];
        }
        if (act == 2) v = (v > 0.f) ? v : 0.01f*v;
        if (Rz) v += Rz[(long)gm*ldr + gn];
        if (cIsBf16) ((__hip_bfloat16*)C)[coff + (long)gm*ldc + gn] = __float2bfloat16(v);
        else         ((float*)C)[coff + (long)gm*ldc + gn] = v;
      }
    }
  }
}

// ---------------- weight transpose+convert (single bf16 out, z-batched)
__global__ __launch_bounds__(256) void convT_kernel(
    const float* __restrict__ W, int N, int K, long sW,
    __hip_bfloat16* __restrict__ out, int Npad, int Kpad, long sO,
    int split, int splitPad)
{
  int z = blockIdx.z;
  int n0 = blockIdx.x*64, k0 = blockIdx.y*64;
  int tid = threadIdx.x;
  __shared__ float lds[64][65];
  #pragma unroll
  for (int i=0;i<16;i++){
    int e = tid + i*256;
    int kl = e >> 6, c = e & 63;
    int np = n0 + c;
    int ns;
    if (split){
      if (np < split) ns = np;
      else if (np >= splitPad && np < splitPad + (N - split)) ns = np - (splitPad - split);
      else ns = -1;
    } else ns = (np < N) ? np : -1;
    int k = k0 + kl;
    float v = (ns >= 0 && k < K) ? W[(long)z*sW + (long)k*N + ns] : 0.f;
    lds[kl][c] = v;
  }
  __syncthreads();
  #pragma unroll
  for (int i=0;i<16;i++){
    int e = tid + i*256;
    int nl = e >> 6, kl = e & 63;
    out[(long)z*sO + (long)(n0+nl)*Kpad + k0 + kl] = __float2bfloat16(lds[kl][nl]);
  }
}

// ---------------- weight transpose+convert with hi/lo split
__global__ __launch_bounds__(256) void convT2_kernel(
    const float* __restrict__ W, int N, int K,
    __hip_bfloat16* __restrict__ outh, __hip_bfloat16* __restrict__ outl,
    int Npad, int Kpad, int split, int splitPad)
{
  int n0 = blockIdx.x*64, k0 = blockIdx.y*64;
  int tid = threadIdx.x;
  __shared__ float lds[64][65];
  #pragma unroll
  for (int i=0;i<16;i++){
    int e = tid + i*256;
    int kl = e >> 6, c = e & 63;
    int np = n0 + c;
    int ns;
    if (split){
      if (np < split) ns = np;
      else if (np >= splitPad && np < splitPad + (N - split)) ns = np - (splitPad - split);
      else ns = -1;
    } else ns = (np < N) ? np : -1;
    int k = k0 + kl;
    float v = (ns >= 0 && k < K) ? W[(long)k*N + ns] : 0.f;
    lds[kl][c] = v;
  }
  __syncthreads();
  #pragma unroll
  for (int i=0;i<16;i++){
    int e = tid + i*256;
    int nl = e >> 6, kl = e & 63;
    float v = lds[kl][nl];
    __hip_bfloat16 h, l; split2(v, h, l);
    long o = (long)(n0+nl)*Kpad + k0 + kl;
    outh[o] = h; outl[o] = l;
  }
}

// ---------------- bias pack for z-batched QKV
__global__ void pack_bias_kernel(const float* bq, const float* bk, const float* bv, float* out){
  int i = blockIdx.x*256 + threadIdx.x;
  if (i < 256) out[i] = bq[i];
  else if (i < 512) out[i] = bk[i-256];
  else if (i < 768) out[i] = bv[i-512];
}

// ---------------- attention split-K
__global__ __launch_bounds__(256) void attn_split_kernel(
    const float* __restrict__ qp, const float* __restrict__ kp,
    const float* __restrict__ vp,
    float* __restrict__ po, float* __restrict__ pm, float* __restrict__ pl)
{
  int bh = blockIdx.y; int bb = bh >> 3; int h = bh & 7;
  int kc = blockIdx.z;
  int qi = blockIdx.x*256 + threadIdx.x;
  const float scale = 0.17677669529663687f;
  float qreg[32];
  const float* qptr = qp + (((bb<<10)+qi)<<8) + (h<<5);
  #pragma unroll
  for (int d=0;d<32;d++) qreg[d] = qptr[d];
  float m = -INFINITY, l = 0.f;
  float oacc[32];
  #pragma unroll
  for (int d=0;d<32;d++) oacc[d] = 0.f;

  __shared__ float Ks[64][32];
  __shared__ float Vs[64][32];
  int jbase = kc*256;
  for (int j0=jbase; j0<jbase+256; j0+=64){
    __syncthreads();
    #pragma unroll
    for (int i=0;i<8;i++){
      int e = threadIdx.x + i*256;
      int j = e >> 5, d = e & 31;
      int base = (((bb<<10)+j0+j)<<8) + (h<<5) + d;
      Ks[j][d] = kp[base];
      Vs[j][d] = vp[base];
    }
    __syncthreads();
    for (int j=0;j<64;j++){
      float s = 0.f;
      #pragma unroll
      for (int d=0;d<32;d++) s += qreg[d]*Ks[j][d];
      s *= scale;
      if (s > m){
        float corr = expf(m - s);
        l = l*corr + 1.f;
        #pragma unroll
        for (int d=0;d<32;d++) oacc[d] = oacc[d]*corr + Vs[j][d];
        m = s;
      } else {
        float p = expf(s - m);
        l += p;
        #pragma unroll
        for (int d=0;d<32;d++) oacc[d] += p*Vs[j][d];
      }
    }
  }
  int r = (bh<<10) + qi;
  pm[kc*32768 + r] = m;
  pl[kc*32768 + r] = l;
  float* pop = po + ((long)kc*32768 + r)*32;
  #pragma unroll
  for (int d=0;d<32;d++) pop[d] = oacc[d];
}

__global__ __launch_bounds__(256) void attn_merge_kernel(
    const float* __restrict__ po, const float* __restrict__ pm,
    const float* __restrict__ pl,
    __hip_bfloat16* __restrict__ aohi, __hip_bfloat16* __restrict__ aolo)
{
  int r = blockIdx.x*256 + threadIdx.x;
  float mz[4], wz[4];
  float M = -INFINITY;
  #pragma unroll
  for (int zc=0;zc<4;zc++){ mz[zc] = pm[zc*32768 + r]; M = fmaxf(M, mz[zc]); }
  float L = 0.f;
  #pragma unroll
  for (int zc=0;zc<4;zc++){ wz[zc] = expf(mz[zc] - M); L += pl[zc*32768 + r]*wz[zc]; }
  float inv = 1.f / L;
  int bh = r >> 10, qi = r & 1023;
  int bb = bh >> 3, h = bh & 7;
  int base = (((bb<<10)+qi)<<8) + (h<<5);
  for (int d=0; d<32; d++){
    float s = 0.f;
    #pragma unroll
    for (int zc=0;zc<4;zc++) s += wz[zc]*po[((long)zc*32768 + r)*32 + d];
    float val = s*inv;
    __hip_bfloat16 hh, ll; split2(val, hh, ll);
    aohi[base+d] = hh; aolo[base+d] = ll;
  }
}

// ---------------- concat queries into x[:, 256:512]
__global__ __launch_bounds__(256) void concat_kernel(
    const float* __restrict__ queries, float* __restrict__ x)
{
  int idx = blockIdx.x*256 + threadIdx.x;
  int d = idx & 255; int r = idx >> 8;
  x[(r<<9) + 256 + d] = queries[idx];
}

// ---------------- rmsnorm fp32 out
__global__ __launch_bounds__(256) void rmsnorm_kernel(
    const float* __restrict__ x, const float* __restrict__ g, float* __restrict__ y)
{
  int r = blockIdx.x; int tid = threadIdx.x;
  float v0 = x[(r<<9) + tid];
  float v1 = x[(r<<9) + 256 + tid];
  float ss = v0*v0 + v1*v1;
  #pragma unroll
  for (int off=32; off>0; off>>=1) ss += __shfl_down(ss, off, 64);
  __shared__ float wsum[4];
  if ((tid & 63) == 0) wsum[tid>>6] = ss;
  __syncthreads();
  float tot = wsum[0]+wsum[1]+wsum[2]+wsum[3];
  float scale = 22.62741699796952f / fmaxf(sqrtf(tot), 1e-12f);
  y[(r<<9) + tid]       = v0*scale*g[tid];
  y[(r<<9) + 256 + tid] = v1*scale*g[256+tid];
}

// ---------------- rmsnorm hi/lo out
__global__ __launch_bounds__(256) void rmsnorm_split_kernel(
    const float* __restrict__ x, const float* __restrict__ g,
    __hip_bfloat16* __restrict__ yh, __hip_bfloat16* __restrict__ yl)
{
  int r = blockIdx.x; int tid = threadIdx.x;
  float v0 = x[(r<<9) + tid];
  float v1 = x[(r<<9) + 256 + tid];
  float ss = v0*v0 + v1*v1;
  #pragma unroll
  for (int off=32; off>0; off>>=1) ss += __shfl_down(ss, off, 64);
  __shared__ float wsum[4];
  if ((tid & 63) == 0) wsum[tid>>6] = ss;
  __syncthreads();
  float tot = wsum[0]+wsum[1]+wsum[2]+wsum[3];
  float scale = 22.62741699796952f / fmaxf(sqrtf(tot), 1e-12f);
  float a = v0*scale*g[tid];
  float b = v1*scale*g[256+tid];
  __hip_bfloat16 h, l;
  split2(a, h, l); yh[(r<<9)+tid] = h;     yl[(r<<9)+tid] = l;
  split2(b, h, l); yh[(r<<9)+256+tid] = h; yl[(r<<9)+256+tid] = l;
}

// ---------------- rmsnorm bf16 out (ffa path)
__global__ __launch_bounds__(256) void rmsnorm_bf_kernel(
    const float* __restrict__ x, const float* __restrict__ g, __hip_bfloat16* __restrict__ y)
{
  int r = blockIdx.x; int tid = threadIdx.x;
  float v0 = x[(r<<9) + tid];
  float v1 = x[(r<<9) + 256 + tid];
  float ss = v0*v0 + v1*v1;
  #pragma unroll
  for (int off=32; off>0; off>>=1) ss += __shfl_down(ss, off, 64);
  __shared__ float wsum[4];
  if ((tid & 63) == 0) wsum[tid>>6] = ss;
  __syncthreads();
  float tot = wsum[0]+wsum[1]+wsum[2]+wsum[3];
  float scale = 22.62741699796952f / fmaxf(sqrtf(tot), 1e-12f);
  y[(r<<9) + tid]       = __float2bfloat16(v0*scale*g[tid]);
  y[(r<<9) + 256 + tid] = __float2bfloat16(v1*scale*g[256+tid]);
}

// ---------------- geglu glu: H fp32 padded [4096][2816] -> T hi/lo [4096][1408]
__global__ __launch_bounds__(256) void glu_split_kernel(
    const float* __restrict__ h, const float* __restrict__ mult,
    __hip_bfloat16* __restrict__ th, __hip_bfloat16* __restrict__ tl)
{
  int idx = blockIdx.x*256 + threadIdx.x;   // 4096*1408
  int r = idx / 1408; int j = idx - r*1408;
  float v = 0.f;
  if (j < 1365){
    float a  = h[(long)r*2816 + j];
    float gt = h[(long)r*2816 + 1408 + j];
    v = gelu_f(gt) * a * mult[j];
  }
  __hip_bfloat16 hh, ll; split2(v, hh, ll);
  th[idx] = hh; tl[idx] = ll;
}

// ---------------- geglu glu bf16 (ffa path)
__global__ __launch_bounds__(256) void glu_bf_kernel(
    const __hip_bfloat16* __restrict__ h, const float* __restrict__ mult,
    __hip_bfloat16* __restrict__ t)
{
  int idx = blockIdx.x*256 + threadIdx.x;   // 4096*1408
  int r = idx / 1408; int j = idx - r*1408;
  float v = 0.f;
  if (j < 1365){
    float a  = __bfloat162float(h[(long)r*2816 + j]);
    float gt = __bfloat162float(h[(long)r*2816 + 1408 + j]);
    v = gelu_f(gt) * a * mult[j];
  }
  t[idx] = __float2bfloat16(v);
}

// ---------------- split fp32 -> hi/lo
__global__ __launch_bounds__(256) void split32_kernel(
    const float* __restrict__ x, __hip_bfloat16* __restrict__ h, __hip_bfloat16* __restrict__ l)
{
  int idx = blockIdx.x*256 + threadIdx.x;
  float v = x[idx];
  __hip_bfloat16 hh, ll; split2(v, hh, ll);
  h[idx] = hh; l[idx] = ll;
}

// ---------------- MoE init (sum_raw/z_sum only; scan writes everything else)
__global__ void moe_init_kernel(float* sum_raw, float* z_sum)
{
  int i = threadIdx.x;
  if (i < 64) sum_raw[i] = 0.f;
  if (i == 0) *z_sum = 0.f;
}

// ---------------- gating
__global__ __launch_bounds__(256) void gating_kernel(
    const float* __restrict__ xn, const float* __restrict__ gate_w,
    int* __restrict__ idx1, int* __restrict__ idx2, int* __restrict__ route,
    float* __restrict__ gg1, float* __restrict__ gg2,
    float* __restrict__ sum_raw, float* __restrict__ z_sum)
{
  int t = blockIdx.x; int tid = threadIdx.x;
  __shared__ float xrow[512];
  xrow[tid]     = xn[(t<<9)+tid];
  xrow[256+tid] = xn[(t<<9)+256+tid];
  __syncthreads();
  int e = tid >> 4, l16 = tid & 15;
  float p = 0.f;
  for (int d=l16; d<512; d+=16) p += xrow[d]*gate_w[(e<<9)+d];
  __shared__ float part[16][17];
  part[e][l16] = p;
  __syncthreads();
  __shared__ float raw[16];
  if (tid < 16){
    float s = 0.f;
    #pragma unroll
    for (int i=0;i<16;i++) s += part[tid][i];
    raw[tid] = s;
  }
  __syncthreads();
  if (tid == 0){
    float mx = -1e30f;
    #pragma unroll
    for (int i=0;i<16;i++) mx = fmaxf(mx, raw[i]);
    float r[16]; float sum = 0.f;
    #pragma unroll
    for (int i=0;i<16;i++){ r[i] = expf(raw[i]-mx); sum += r[i]; }
    float lse = mx + logf(sum);
    atomicAdd(z_sum, lse*lse);
    float inv = 1.f/sum;
    #pragma unroll
    for (int i=0;i<16;i++){ r[i] *= inv; raw[i] = r[i]; }
    int i1 = -1; float b1 = -1.f;
    #pragma unroll
    for (int i=0;i<16;i++) if (r[i] > b1){ b1 = r[i]; i1 = i; }
    int i2 = -1; float b2 = -1.f;
    #pragma unroll
    for (int i=0;i<16;i++) if (i != i1 && r[i] > b2){ b2 = r[i]; i2 = i; }
    float s2 = fmaxf(b1 + b2, 1e-9f);
    float g1n = b1/s2, g2n = b2/s2;
    idx1[t] = i1; idx2[t] = i2;
    route[t] = (g2n > 0.2f) ? 1 : 0;
    gg1[t] = g1n; gg2[t] = g2n;
  }
  __syncthreads();
  int bb = t >> 10;
  if (tid < 16) atomicAdd(&sum_raw[(bb<<4)+tid], raw[tid]);
}

// ---------------- capacity assignment: parallel segmented prefix scan
// one block per (batch, expert); 256 threads x 4 tokens each (int4 loads).
// Matches reference cumsum semantics exactly: choice-1 rank = exclusive count,
// choice-2 rank = exclusive routed count + UNCAPPED choice-1 total.
__global__ __launch_bounds__(256) void scan_kernel(
    const int* __restrict__ idx1, const int* __restrict__ idx2, const int* __restrict__ route,
    int* __restrict__ ts1, int* __restrict__ ts2, int* __restrict__ slot_token,
    int* __restrict__ count1)
{
  int bb = blockIdx.x >> 4;
  int e  = blockIdx.x & 15;
  int tid = threadIdx.x;
  int tbase = (bb<<10) + tid*4;
  int4 i1 = *(const int4*)&idx1[tbase];
  int4 i2 = *(const int4*)&idx2[tbase];
  int4 rt = *(const int4*)&route[tbase];
  int m1[4] = { i1.x==e, i1.y==e, i1.z==e, i1.w==e };
  int m2[4] = { i2.x==e, i2.y==e, i2.z==e, i2.w==e };
  int r4[4] = { rt.x, rt.y, rt.z, rt.w };
  int c1 = m1[0]+m1[1]+m1[2]+m1[3];
  int c2 = (m2[0]&&r4[0]) + (m2[1]&&r4[1]) + (m2[2]&&r4[2]) + (m2[3]&&r4[3]);
  __shared__ int s1[256], s2v[256];
  s1[tid] = c1; s2v[tid] = c2;
  __syncthreads();
  for (int off=1; off<256; off<<=1){
    int v1 = (tid>=off) ? s1[tid-off] : 0;
    int v2 = (tid>=off) ? s2v[tid-off] : 0;
    __syncthreads();
    s1[tid] += v1; s2v[tid] += v2;
    __syncthreads();
  }
  int tot1 = s1[255], tot2 = s2v[255];
  int p1 = s1[tid] - c1;    // exclusive prefix
  int p2 = s2v[tid] - c2;
  if (tid == 0) count1[(bb<<4)+e] = tot1;
  int base = ((e<<2)+bb)*CAPN;
  #pragma unroll
  for (int i=0;i<4;i++){
    int t = tbase + i;
    if (m1[i]){
      if (p1 < CAPN){ ts1[t] = base+p1; slot_token[base+p1] = t; }
      else ts1[t] = -1;
      p1++;
    }
    if (m2[i]){
      if (r4[i]){
        int pos = tot1 + p2;
        if (pos < CAPN){ ts2[t] = base+pos; slot_token[base+pos] = t; }
        else ts2[t] = -1;
        p2++;
      } else ts2[t] = -1;
    }
  }
  // -1-init unfilled slots (fill is contiguous: [0,tot1) then [tot1, tot1+tot2) capped)
  int filled = min(CAPN, tot1 + tot2);
  if (tid < CAPN && tid >= filled) slot_token[base+tid] = -1;
}

// ---------------- gather + layernorm -> xin bf16
__global__ __launch_bounds__(256) void gather_ln_kernel(
    const float* __restrict__ xn, const int* __restrict__ slot_token,
    const float* __restrict__ ln_g, const float* __restrict__ ln_b,
    __hip_bfloat16* __restrict__ xin)
{
  int s = blockIdx.x; int tid = threadIdx.x;
  int t = slot_token[s];
  int e = s >> 9;
  if (t < 0){
    xin[(s<<9)+tid] = __float2bfloat16(0.f);
    xin[(s<<9)+256+tid] = __float2bfloat16(0.f);
    return;
  }
  float v0 = xn[(t<<9)+tid];
  float v1 = xn[(t<<9)+256+tid];
  float sm = v0+v1, sq = v0*v0+v1*v1;
  #pragma unroll
  for (int off=32; off>0; off>>=1){
    sm += __shfl_down(sm, off, 64);
    sq += __shfl_down(sq, off, 64);
  }
  __shared__ float s1[4], s2buf[4];
  if ((tid & 63) == 0){ s1[tid>>6] = sm; s2buf[tid>>6] = sq; }
  __syncthreads();
  float tsm = s1[0]+s1[1]+s1[2]+s1[3];
  float tsq = s2buf[0]+s2buf[1]+s2buf[2]+s2buf[3];
  float mean = tsm * (1.f/512.f);
  float var = tsq * (1.f/512.f) - mean*mean;
  float rstd = rsqrtf(var + 1e-5f);
  xin[(s<<9)+tid]     = __float2bfloat16((v0-mean)*rstd*ln_g[(e<<9)+tid]     + ln_b[(e<<9)+tid]);
  xin[(s<<9)+256+tid] = __float2bfloat16((v1-mean)*rstd*ln_g[(e<<9)+256+tid] + ln_b[(e<<9)+256+tid]);
}

// ---------------- combine (in-place)
__global__ __launch_bounds__(256) void combine_kernel(
    float* __restrict__ x, const float* __restrict__ h2,
    const int* __restrict__ ts1, const int* __restrict__ ts2,
    const float* __restrict__ gg1, const float* __restrict__ gg2)
{
  int idx = blockIdx.x*256 + threadIdx.x;
  int t = idx >> 9; int d = idx & 511;
  float v = x[idx];
  int s1 = ts1[t]; if (s1 >= 0) v += gg1[t]*h2[(s1<<9)+d];
  int s2 = ts2[t]; if (s2 >= 0) v += gg2[t]*h2[(s2<<9)+d];
  x[idx] = v;
}

// ---------------- aux losses
__global__ void aux_kernel(
    const float* __restrict__ sum_raw, const int* __restrict__ count1,
    const float* __restrict__ z_sum, float* __restrict__ out)
{
  int tid = threadIdx.x;
  float v = (sum_raw[tid] * (1.f/1024.f)) * ((float)count1[tid] * (1.f/1024.f));
  #pragma unroll
  for (int off=32; off>0; off>>=1) v += __shfl_down(v, off, 64);
  if (tid == 0){
    float bal = v * (1.f/64.f) * 256.f * 0.01f;
    float zl = (*z_sum) * (1.f/4096.f) * 0.001f;
    out[0] = bal + zl;
    out[1] = bal;
    out[2] = zl;
  }
}

extern "C" void kernel_launch(void* const* d_in, const int* in_sizes, int n_in,
                              void* d_out, int out_size, void* d_ws, size_t ws_size,
                              hipStream_t stream)
{
  const float* K_in   = (const float*)d_in[0];
  const float* V_in   = (const float*)d_in[1];
  const float* Q_in   = (const float*)d_in[2];
  const float* w_topo = (const float*)d_in[3];
  const float* b_topo = (const float*)d_in[4];
  const float* w_val  = (const float*)d_in[5];
  const float* b_val  = (const float*)d_in[6];
  const float* wq     = (const float*)d_in[7];
  const float* bq     = (const float*)d_in[8];
  const float* wk     = (const float*)d_in[9];
  const float* bk     = (const float*)d_in[10];
  const float* wv     = (const float*)d_in[11];
  const float* bv     = (const float*)d_in[12];
  const float* wo     = (const float*)d_in[13];
  const float* bo     = (const float*)d_in[14];
  const float* ffb_g  = (const float*)d_in[15];
  const float* ffb_w1 = (const float*)d_in[16];
  const float* ffb_b1 = (const float*)d_in[17];
  const float* ffb_mult=(const float*)d_in[18];
  const float* ffb_w2 = (const float*)d_in[19];
  const float* ffb_b2 = (const float*)d_in[20];
  const float* prenorm_g=(const float*)d_in[21];
  const float* gate_w = (const float*)d_in[22];
  const float* exp_ln_g=(const float*)d_in[23];
  const float* exp_ln_b=(const float*)d_in[24];
  const float* exp_w1 = (const float*)d_in[25];
  const float* exp_b1 = (const float*)d_in[26];
  const float* exp_w2 = (const float*)d_in[27];
  const float* exp_b2 = (const float*)d_in[28];
  const float* ffa_g  = (const float*)d_in[29];
  const float* ffa_w1 = (const float*)d_in[30];
  const float* ffa_b1 = (const float*)d_in[31];
  const float* ffa_mult=(const float*)d_in[32];
  const float* ffa_w2 = (const float*)d_in[33];
  const float* ffa_b2 = (const float*)d_in[34];
  const float* w_out  = (const float*)d_in[35];
  const float* b_out  = (const float*)d_in[36];
  float* dout = (float*)d_out;

  float* wsf = (float*)d_ws;
  int*   wsi = (int*)d_ws;

  // ---- layout (float offsets) ----
  const size_t A0 = 0;              // region A: 11,534,336 fl
  const size_t B0 = 11534336;       // region B:  5,767,168 fl (ends at OXA)
  const size_t OXA = 17301504;      // 2,097,152
  const size_t OXB = 19398656;      // 2,097,152
  const size_t OWP = 21495808;      // persistent split weights (393,216 fl)
  const size_t OMI = 21889024;      // misc

  // region A (early phases)
  __hip_bfloat16* qhi = (__hip_bfloat16*)(wsf + A0);
  __hip_bfloat16* khi = (__hip_bfloat16*)(wsf + A0 + 524288);
  __hip_bfloat16* vhi = (__hip_bfloat16*)(wsf + A0 + 1048576);
  __hip_bfloat16* qlo = (__hip_bfloat16*)(wsf + A0 + 1572864);
  __hip_bfloat16* klo = (__hip_bfloat16*)(wsf + A0 + 2097152);
  __hip_bfloat16* vlo = (__hip_bfloat16*)(wsf + A0 + 2621440);
  float* QP = wsf + A0 + 3145728;                         // 3x 1048576
  __hip_bfloat16* aohi = (__hip_bfloat16*)(wsf + A0 + 6291456);
  __hip_bfloat16* aolo = (__hip_bfloat16*)(wsf + A0 + 6815744);
  float* PO = wsf + A0 + 7340032;                         // 4194304 fl, ends 11534336
  // region B (early phases)
  float* PM = wsf + B0;                                   // 131072
  float* PL = wsf + B0 + 131072;                          // 131072
  float* QF = wsf + B0 + 262144;                          // 1048576, ends B0+1310720
  // phase 5 (ffb): region A holds Hb; region B sequenced in two waves
  float* Hb = wsf + A0;                                   // fp32 [4096][2816] = 11534336 fl
  __hip_bfloat16* yh   = (__hip_bfloat16*)(wsf + B0);                 // 1048576 fl
  __hip_bfloat16* yl   = (__hip_bfloat16*)(wsf + B0 + 1048576);       // 1048576 fl
  __hip_bfloat16* fw1h = (__hip_bfloat16*)(wsf + B0 + 2097152);       // 720896 fl
  __hip_bfloat16* fw1l = fw1h + 1441792;                              // 720896 fl, ends B0+3538944
  __hip_bfloat16* th   = (__hip_bfloat16*)(wsf + B0);                 // 2883584 fl (after GEMM1)
  __hip_bfloat16* tl   = (__hip_bfloat16*)(wsf + B0 + 2883584);       // 2883584 fl, ends B0+5767168
  __hip_bfloat16* fw2h = (__hip_bfloat16*)(wsf + A0);                 // 360448 fl (after glu; Hb dead)
  __hip_bfloat16* fw2l = fw2h + 720896;                               // ends A0+720896
  // phase 6 (MoE)
  __hip_bfloat16* wte   = (__hip_bfloat16*)(wsf + A0);                // 5767168 fl
  __hip_bfloat16* xin_bf= (__hip_bfloat16*)(wsf + A0 + 5767168);      // 2097152 fl
  __hip_bfloat16* h1_bf = (__hip_bfloat16*)(wsf + A0 + 7864320);      // 5767168 fl
  float* H2 = wsf + 13631488;        // 4194304 fl, ends 17825792 (spills into dead OXA head)
  float* YM = wsf + B0;              // 2097152 fl (dead before h1_bf written)
  // phase 7 (ffa)
  __hip_bfloat16* y_bf = (__hip_bfloat16*)(wsf + A0);
  __hip_bfloat16* wf1  = (__hip_bfloat16*)(wsf + A0 + 1048576);
  __hip_bfloat16* h_bf = (__hip_bfloat16*)(wsf + A0 + 1769472);
  __hip_bfloat16* t_bf = (__hip_bfloat16*)(wsf + A0 + 7536640);
  __hip_bfloat16* wf2  = (__hip_bfloat16*)(wsf + A0 + 10420224);
  // phase 8
  __hip_bfloat16* xah = (__hip_bfloat16*)(wsf + A0);                  // 1048576 fl
  __hip_bfloat16* xal = (__hip_bfloat16*)(wsf + A0 + 1048576);        // 1048576 fl
  // persistent weights (bf16 element offsets from wp)
  __hip_bfloat16* wp = (__hip_bfloat16*)(wsf + OWP);
  __hip_bfloat16* wqh = wp;            __hip_bfloat16* wkh = wp + 65536;
  __hip_bfloat16* wvh = wp + 131072;   __hip_bfloat16* wql = wp + 196608;
  __hip_bfloat16* wkl = wp + 262144;   __hip_bfloat16* wvl = wp + 327680;
  __hip_bfloat16* woh = wp + 393216;   __hip_bfloat16* wol = wp + 458752;
  __hip_bfloat16* wouth = wp + 524288; __hip_bfloat16* woutl = wp + 655360;

  int* idx1 = wsi + OMI + 0;
  int* idx2 = wsi + OMI + 4096;
  int* route= wsi + OMI + 8192;
  int* ts1  = wsi + OMI + 12288;
  int* ts2  = wsi + OMI + 16384;
  int* slot_token = wsi + OMI + 20480;
  int* count1     = wsi + OMI + 28672;
  float* sum_raw  = wsf + OMI + 28736;
  float* z_sum    = wsf + OMI + 28800;
  float* gg1      = wsf + OMI + 28864;
  float* gg2      = wsf + OMI + 32960;
  float* bias_qkv = wsf + OMI + 37056;   // 768

  // ---- phase 0: static weight conversions ----
  convT2_kernel<<<dim3(4,4),  256, 0, stream>>>(wq, 256, 256, wqh, wql, 256, 256, 0, 0);
  convT2_kernel<<<dim3(4,4),  256, 0, stream>>>(wk, 256, 256, wkh, wkl, 256, 256, 0, 0);
  convT2_kernel<<<dim3(4,4),  256, 0, stream>>>(wv, 256, 256, wvh, wvl, 256, 256, 0, 0);
  convT2_kernel<<<dim3(4,4),  256, 0, stream>>>(wo, 256, 256, woh, wol, 256, 256, 0, 0);
  convT2_kernel<<<dim3(4,8),  256, 0, stream>>>(w_out, 256, 512, wouth, woutl, 256, 512, 0, 0);
  convT2_kernel<<<dim3(44,8), 256, 0, stream>>>(ffb_w1, 2730, 512, fw1h, fw1l, 2816, 512, 1365, 1408);
  pack_bias_kernel<<<3, 256, 0, stream>>>(bq, bk, bv, bias_qkv);

  // ---- phase 1: topo / values ----
  topo_kernel<<<8192, 256, 0, stream>>>(K_in, Q_in, w_topo, b_topo, khi, klo, qhi, qlo, QF);
  values_kernel<<<4096, 256, 0, stream>>>(V_in, w_val, b_val, vhi, vlo);

  // ---- phase 2: QKV projections (split MFMA, z-batched) ----
  sgemm_kernel<<<dim3(2,32,3), 256, 0, stream>>>(
      qhi, qlo, 256, 1048576, wqh, wql, 256, 65536,
      bias_qkv, 256, 0, 0, 256, nullptr, 0, QP, 256, 1048576, 256, 0);

  // ---- phase 3: attention ----
  attn_split_kernel<<<dim3(4,32,4), 256, 0, stream>>>(QP, QP+1048576, QP+2097152, PO, PM, PL);
  attn_merge_kernel<<<128, 256, 0, stream>>>(PO, PM, PL, aohi, aolo);

  // ---- phase 4: o-proj into XA[:, :256] + concat queries ----
  sgemm_kernel<<<dim3(2,32,1), 256, 0, stream>>>(
      aohi, aolo, 256, 0, woh, wol, 256, 0,
      bo, 256, 0, 0, 0, nullptr, 0, wsf+OXA, 512, 0, 256, 0);
  concat_kernel<<<4096, 256, 0, stream>>>(QF, wsf+OXA);

  // ---- phase 5: ffb geglu (split MFMA) ----
  rmsnorm_split_kernel<<<4096, 256, 0, stream>>>(wsf+OXA, ffb_g, yh, yl);
  sgemm_kernel<<<dim3(22,32,1), 256, 0, stream>>>(
      yh, yl, 512, 0, fw1h, fw1l, 512, 0,
      ffb_b1, 2730, 1365, 1408, 0, nullptr, 0, Hb, 2816, 0, 512, 0);
  glu_split_kernel<<<22528, 256, 0, stream>>>(Hb, ffb_mult, th, tl);
  convT2_kernel<<<dim3(8,22), 256, 0, stream>>>(ffb_w2, 512, 1365, fw2h, fw2l, 512, 1408, 0, 0);
  sgemm_kernel<<<dim3(4,32,1), 256, 0, stream>>>(
      th, tl, 1408, 0, fw2h, fw2l, 1408, 0,
      ffb_b2, 512, 0, 0, 0, wsf+OXA, 512, wsf+OXB, 512, 0, 1408, 0);

  // ---- phase 6: MoE ----
  rmsnorm_kernel<<<4096, 256, 0, stream>>>(wsf+OXB, prenorm_g, YM);
  moe_init_kernel<<<1, 64, 0, stream>>>(sum_raw, z_sum);
  gating_kernel<<<4096, 256, 0, stream>>>(YM, gate_w, idx1, idx2, route, gg1, gg2, sum_raw, z_sum);
  scan_kernel<<<64, 256, 0, stream>>>(idx1, idx2, route, ts1, ts2, slot_token, count1);
  gather_ln_kernel<<<8192, 256, 0, stream>>>(YM, slot_token, exp_ln_g, exp_ln_b, xin_bf);
  convT_kernel<<<dim3(22, 8, 16), 256, 0, stream>>>(exp_w1, 1365, 512, (long)512*1365,
                                                    wte, 1408, 512, (long)1408*512, 0, 0);
  bgemm_kernel<<<dim3(11,4,16), 256, 0, stream>>>(
      xin_bf, 512, (long)512*512, wte, 512, (long)1408*512,
      exp_b1, 1365, 0, 0, 1365, nullptr, 0, 0,
      h1_bf, 1408, (long)512*1408, 1, 512, 2);
  convT_kernel<<<dim3(8, 22, 16), 256, 0, stream>>>(exp_w2, 512, 1365, (long)1365*512,
                                                    wte, 512, 1408, (long)512*1408, 0, 0);
  bgemm_kernel<<<dim3(4,4,16), 256, 0, stream>>>(
      h1_bf, 1408, (long)512*1408, wte, 1408, (long)512*1408,
      exp_b2, 512, 0, 0, 512, nullptr, 0, 0,
      H2, 512, (long)512*512, 0, 1408, 0);
  combine_kernel<<<8192, 256, 0, stream>>>(wsf+OXB, H2, ts1, ts2, gg1, gg2);
  aux_kernel<<<1, 64, 0, stream>>>(sum_raw, count1, z_sum, dout + 4096*256);

  // ---- phase 7: ffa geglu (bf16 MFMA) ----
  rmsnorm_bf_kernel<<<4096, 256, 0, stream>>>(wsf+OXB, ffa_g, y_bf);
  convT_kernel<<<dim3(44, 8, 1), 256, 0, stream>>>(ffa_w1, 2730, 512, 0,
                                                   wf1, 2816, 512, 0, 1365, 1408);
  bgemm_kernel<<<dim3(22,32,1), 256, 0, stream>>>(
      y_bf, 512, 0, wf1, 512, 0,
      ffa_b1, 2730, 1365, 1408, 0, nullptr, 0, 0,
      h_bf, 2816, 0, 1, 512, 0);
  glu_bf_kernel<<<22528, 256, 0, stream>>>(h_bf, ffa_mult, t_bf);
  convT_kernel<<<dim3(8, 22, 1), 256, 0, stream>>>(ffa_w2, 512, 1365, 0,
                                                   wf2, 512, 1408, 0, 0, 0);
  bgemm_kernel<<<dim3(4,32,1), 256, 0, stream>>>(
      t_bf, 1408, 0, wf2, 1408, 0,
      ffa_b2, 512, 0, 0, 0, wsf+OXB, 512, 0,
      wsf+OXA, 512, 0, 0, 1408, 0);

  // ---- phase 8: out = gelu(XA @ w_out + b_out) ----
  split32_kernel<<<8192, 256, 0, stream>>>(wsf+OXA, xah, xal);
  sgemm_kernel<<<dim3(2,32,1), 256, 0, stream>>>(
      xah, xal, 512, 0, wouth, woutl, 512, 0,
      b_out, 256, 0, 0, 0, nullptr, 0, dout, 256, 0, 512, 1);
}

// Round 6
// 971.847 us; speedup vs baseline: 3.1208x; 1.0505x over previous
//
#include <hip/hip_runtime.h>
#include <hip/hip_bf16.h>
#include <math.h>

// B=4 S=1024 DM=256 H=8 HD=32 CIN=23 E=16 D2=512 HE=1365 2HE=2730 CAP=128
#define CAPN 128

typedef short short8 __attribute__((ext_vector_type(8)));
typedef short short4v __attribute__((ext_vector_type(4)));
typedef float f32x4 __attribute__((ext_vector_type(4)));

__device__ __forceinline__ float gelu_f(float x){
  return 0.5f*x*(1.0f+erff(x*0.7071067811865476f));
}
__device__ __forceinline__ void split2(float v, __hip_bfloat16& h, __hip_bfloat16& l){
  h = __float2bfloat16(v);
  l = __float2bfloat16(v - __bfloat162float(h));
}
__device__ __forceinline__ void split2s(float v, short& h, short& l){
  __hip_bfloat16 hh = __float2bfloat16(v);
  __hip_bfloat16 ll = __float2bfloat16(v - __bfloat162float(hh));
  h = *(short*)&hh; l = *(short*)&ll;
}

// ---------------- topo: gelu(cat([K,Q]) @ w + b) -> keys (hi/lo), queries (hi/lo + fp32)
__global__ __launch_bounds__(256) void topo_kernel(
    const float* __restrict__ K, const float* __restrict__ Q,
    const float* __restrict__ w, const float* __restrict__ b,
    __hip_bfloat16* __restrict__ khi, __hip_bfloat16* __restrict__ klo,
    __hip_bfloat16* __restrict__ qhi, __hip_bfloat16* __restrict__ qlo,
    float* __restrict__ qf32)
{
  int idx = blockIdx.x*256 + threadIdx.x;   // 2M
  int d = idx & 255;
  int r = idx >> 8;
  int bb = r >> 11;
  int n  = r & 2047;
  const float* src = (n < 1024) ? (K + ((bb<<10) + n)*3)
                                : (Q + ((bb<<10) + (n-1024))*3);
  float v = b[d] + src[0]*w[d] + src[1]*w[256+d] + src[2]*w[512+d];
  v = gelu_f(v);
  int off = (((bb<<10) + (n & 1023))<<8) + d;
  __hip_bfloat16 h, l; split2(v, h, l);
  if (n < 1024){ khi[off] = h; klo[off] = l; }
  else         { qhi[off] = h; qlo[off] = l; qf32[off] = v; }
}

// ---------------- values: gelu(V @ w_val + b_val) -> hi/lo
__global__ __launch_bounds__(256) void values_kernel(
    const float* __restrict__ V, const float* __restrict__ w,
    const float* __restrict__ b,
    __hip_bfloat16* __restrict__ vhi, __hip_bfloat16* __restrict__ vlo)
{
  int idx = blockIdx.x*256 + threadIdx.x;
  int d = idx & 255; int r = idx >> 8;
  const float* src = V + r*23;
  float acc = b[d];
  #pragma unroll
  for (int c=0;c<23;c++) acc += src[c]*w[c*256+d];
  acc = gelu_f(acc);
  __hip_bfloat16 h, l; split2(acc, h, l);
  vhi[idx] = h; vlo[idx] = l;
}

// ---------------- split-bf16 "fp32" MFMA GEMM: C = act(A@W + bias) (+R)
// acc = Ah*Wh + Ah*Wl + Al*Wh  (rel err ~1e-5). 128x128 tile, BK=32.
#define SLP 40
__global__ __launch_bounds__(256) void sgemm_kernel(
    const __hip_bfloat16* __restrict__ Ah_, const __hip_bfloat16* __restrict__ Al_,
    int lda, long sA,
    const __hip_bfloat16* __restrict__ Wh_, const __hip_bfloat16* __restrict__ Wl_,
    int ldw, long sW,
    const float* __restrict__ bias, int nbias, int bsplit, int bsplitPad, long sB,
    const float* __restrict__ R, int ldr,
    float* __restrict__ C, int ldc, long sC,
    int K, int act)
{
  int z = blockIdx.z;
  const short* Ah = (const short*)Ah_ + (long)z*sA;
  const short* Al = (const short*)Al_ + (long)z*sA;
  const short* Wh = (const short*)Wh_ + (long)z*sW;
  const short* Wl = (const short*)Wl_ + (long)z*sW;
  int bm = blockIdx.y*128, bn = blockIdx.x*128;
  int tid = threadIdx.x, lane = tid & 63, wave = tid >> 6;
  int wm = (wave & 1)*64, wn = (wave >> 1)*64;

  __shared__ short AsH[128*SLP], AsL[128*SLP], BsH[128*SLP], BsL[128*SLP];

  f32x4 acc[4][4];
  f32x4 zero4 = {0.f,0.f,0.f,0.f};
  #pragma unroll
  for (int i=0;i<4;i++)
    #pragma unroll
    for (int j=0;j<4;j++) acc[i][j] = zero4;

  int srow = tid >> 1, scol = (tid & 1)*16;
  int ml = lane & 15, q = lane >> 4;

  for (int k0 = 0; k0 < K; k0 += 32){
    long abase = (long)(bm+srow)*lda + k0 + scol;
    long bbase = (long)(bn+srow)*ldw + k0 + scol;
    short8 ah0 = *(const short8*)&Ah[abase];
    short8 ah1 = *(const short8*)&Ah[abase + 8];
    short8 al0 = *(const short8*)&Al[abase];
    short8 al1 = *(const short8*)&Al[abase + 8];
    short8 bh0 = *(const short8*)&Wh[bbase];
    short8 bh1 = *(const short8*)&Wh[bbase + 8];
    short8 bl0 = *(const short8*)&Wl[bbase];
    short8 bl1 = *(const short8*)&Wl[bbase + 8];
    __syncthreads();
    *(short8*)&AsH[srow*SLP + scol]     = ah0;
    *(short8*)&AsH[srow*SLP + scol + 8] = ah1;
    *(short8*)&AsL[srow*SLP + scol]     = al0;
    *(short8*)&AsL[srow*SLP + scol + 8] = al1;
    *(short8*)&BsH[srow*SLP + scol]     = bh0;
    *(short8*)&BsH[srow*SLP + scol + 8] = bh1;
    *(short8*)&BsL[srow*SLP + scol]     = bl0;
    *(short8*)&BsL[srow*SLP + scol + 8] = bl1;
    __syncthreads();
    short8 afh[4], afl[4], bfh[4], bfl[4];
    #pragma unroll
    for (int i=0;i<4;i++){
      afh[i] = *(const short8*)&AsH[(wm + 16*i + ml)*SLP + q*8];
      afl[i] = *(const short8*)&AsL[(wm + 16*i + ml)*SLP + q*8];
    }
    #pragma unroll
    for (int j=0;j<4;j++){
      bfh[j] = *(const short8*)&BsH[(wn + 16*j + ml)*SLP + q*8];
      bfl[j] = *(const short8*)&BsL[(wn + 16*j + ml)*SLP + q*8];
    }
    #pragma unroll
    for (int i=0;i<4;i++)
      #pragma unroll
      for (int j=0;j<4;j++){
        acc[i][j] = __builtin_amdgcn_mfma_f32_16x16x32_bf16(afh[i], bfh[j], acc[i][j], 0,0,0);
        acc[i][j] = __builtin_amdgcn_mfma_f32_16x16x32_bf16(afh[i], bfl[j], acc[i][j], 0,0,0);
        acc[i][j] = __builtin_amdgcn_mfma_f32_16x16x32_bf16(afl[i], bfh[j], acc[i][j], 0,0,0);
      }
  }

  const float* biasz = bias ? bias + (long)z*sB : nullptr;
  long coff = (long)z*sC;
  #pragma unroll
  for (int i=0;i<4;i++){
    #pragma unroll
    for (int r=0;r<4;r++){
      int gm = bm + wm + 16*i + q*4 + r;
      #pragma unroll
      for (int j=0;j<4;j++){
        int gn = bn + wn + 16*j + ml;
        float v = acc[i][j][r];
        if (biasz){
          int bi;
          if (bsplit){
            if (gn < bsplit) bi = gn;
            else if (gn >= bsplitPad && gn < bsplitPad + (nbias - bsplit)) bi = gn - (bsplitPad - bsplit);
            else bi = -1;
          } else bi = (gn < nbias) ? gn : -1;
          if (bi >= 0) v += biasz[bi];
        }
        if (act == 1) v = gelu_f(v);
        if (R) v += R[(long)gm*ldr + gn];
        C[coff + (long)gm*ldc + gn] = v;
      }
    }
  }
}

// ---------------- pure-bf16 MFMA GEMM (experts / ffa)
#define LP 56
__global__ __launch_bounds__(256) void bgemm_kernel(
    const __hip_bfloat16* __restrict__ A, int lda, long sA,
    const __hip_bfloat16* __restrict__ WT, int ldw, long sW,
    const float* __restrict__ bias, int nbias, int bsplit, int bsplitPad, long sB,
    const float* __restrict__ R, int ldr, long sR,
    void* __restrict__ C, int ldc, long sC, int cIsBf16,
    int K, int act)
{
  int z = blockIdx.z;
  const short* Ab = (const short*)A + (long)z*sA;
  const short* Bb = (const short*)WT + (long)z*sW;
  int bm = blockIdx.y*128, bn = blockIdx.x*128;
  int tid = threadIdx.x, lane = tid & 63, wave = tid >> 6;
  int wm = (wave & 1)*64, wn = (wave >> 1)*64;

  __shared__ short As[128*LP];
  __shared__ short Bs[128*LP];

  f32x4 acc[4][4];
  f32x4 zero4 = {0.f,0.f,0.f,0.f};
  #pragma unroll
  for (int i=0;i<4;i++)
    #pragma unroll
    for (int j=0;j<4;j++) acc[i][j] = zero4;

  int g0 = tid, g1 = tid + 256;
  int r0 = g0 >> 2, c0 = (g0 & 3) * 8;
  int r1 = g1 >> 2, c1 = (g1 & 3) * 8;
  int ml = lane & 15, q = lane >> 4;

  for (int k0 = 0; k0 < K; k0 += 32){
    short8 av0 = *(const short8*)&Ab[(long)(bm+r0)*lda + k0 + c0];
    short8 av1 = *(const short8*)&Ab[(long)(bm+r1)*lda + k0 + c1];
    short8 bv0 = *(const short8*)&Bb[(long)(bn+r0)*ldw + k0 + c0];
    short8 bv1 = *(const short8*)&Bb[(long)(bn+r1)*ldw + k0 + c1];
    __syncthreads();
    *(short8*)&As[r0*LP + c0] = av0;
    *(short8*)&As[r1*LP + c1] = av1;
    *(short8*)&Bs[r0*LP + c0] = bv0;
    *(short8*)&Bs[r1*LP + c1] = bv1;
    __syncthreads();
    short8 af[4], bfv[4];
    #pragma unroll
    for (int i=0;i<4;i++) af[i]  = *(const short8*)&As[(wm + 16*i + ml)*LP + q*8];
    #pragma unroll
    for (int j=0;j<4;j++) bfv[j] = *(const short8*)&Bs[(wn + 16*j + ml)*LP + q*8];
    #pragma unroll
    for (int i=0;i<4;i++)
      #pragma unroll
      for (int j=0;j<4;j++)
        acc[i][j] = __builtin_amdgcn_mfma_f32_16x16x32_bf16(af[i], bfv[j], acc[i][j], 0,0,0);
  }

  const float* biasz = bias ? bias + (long)z*sB : nullptr;
  const float* Rz = R ? R + (long)z*sR : nullptr;
  long coff = (long)z*sC;
  #pragma unroll
  for (int i=0;i<4;i++){
    #pragma unroll
    for (int r=0;r<4;r++){
      int gm = bm + wm + 16*i + q*4 + r;
      #pragma unroll
      for (int j=0;j<4;j++){
        int gn = bn + wn + 16*j + ml;
        float v = acc[i][j][r];
        if (biasz){
          int bi;
          if (bsplit){
            if (gn < bsplit) bi = gn;
            else if (gn >= bsplitPad && gn < bsplitPad + (nbias - bsplit)) bi = gn - (bsplitPad - bsplit);
            else bi = -1;
          } else bi = (gn < nbias) ? gn : -1;
          if (bi >= 0) v += biasz[bi];
        }
        if (act == 2) v = (v > 0.f) ? v : 0.01f*v;
        if (Rz) v += Rz[(long)gm*ldr + gn];
        if (cIsBf16) ((__hip_bfloat16*)C)[coff + (long)gm*ldc + gn] = __float2bfloat16(v);
        else         ((float*)C)[coff + (long)gm*ldc + gn] = v;
      }
    }
  }
}

// ---------------- weight transpose+convert (single bf16 out, z-batched)
__global__ __launch_bounds__(256) void convT_kernel(
    const float* __restrict__ W, int N, int K, long sW,
    __hip_bfloat16* __restrict__ out, int Npad, int Kpad, long sO,
    int split, int splitPad)
{
  int z = blockIdx.z;
  int n0 = blockIdx.x*64, k0 = blockIdx.y*64;
  int tid = threadIdx.x;
  __shared__ float lds[64][65];
  #pragma unroll
  for (int i=0;i<16;i++){
    int e = tid + i*256;
    int kl = e >> 6, c = e & 63;
    int np = n0 + c;
    int ns;
    if (split){
      if (np < split) ns = np;
      else if (np >= splitPad && np < splitPad + (N - split)) ns = np - (splitPad - split);
      else ns = -1;
    } else ns = (np < N) ? np : -1;
    int k = k0 + kl;
    float v = (ns >= 0 && k < K) ? W[(long)z*sW + (long)k*N + ns] : 0.f;
    lds[kl][c] = v;
  }
  __syncthreads();
  #pragma unroll
  for (int i=0;i<16;i++){
    int e = tid + i*256;
    int nl = e >> 6, kl = e & 63;
    out[(long)z*sO + (long)(n0+nl)*Kpad + k0 + kl] = __float2bfloat16(lds[kl][nl]);
  }
}

// ---------------- weight transpose+convert with hi/lo split
__global__ __launch_bounds__(256) void convT2_kernel(
    const float* __restrict__ W, int N, int K,
    __hip_bfloat16* __restrict__ outh, __hip_bfloat16* __restrict__ outl,
    int Npad, int Kpad, int split, int splitPad)
{
  int n0 = blockIdx.x*64, k0 = blockIdx.y*64;
  int tid = threadIdx.x;
  __shared__ float lds[64][65];
  #pragma unroll
  for (int i=0;i<16;i++){
    int e = tid + i*256;
    int kl = e >> 6, c = e & 63;
    int np = n0 + c;
    int ns;
    if (split){
      if (np < split) ns = np;
      else if (np >= splitPad && np < splitPad + (N - split)) ns = np - (splitPad - split);
      else ns = -1;
    } else ns = (np < N) ? np : -1;
    int k = k0 + kl;
    float v = (ns >= 0 && k < K) ? W[(long)k*N + ns] : 0.f;
    lds[kl][c] = v;
  }
  __syncthreads();
  #pragma unroll
  for (int i=0;i<16;i++){
    int e = tid + i*256;
    int nl = e >> 6, kl = e & 63;
    float v = lds[kl][nl];
    __hip_bfloat16 h, l; split2(v, h, l);
    long o = (long)(n0+nl)*Kpad + k0 + kl;
    outh[o] = h; outl[o] = l;
  }
}

// ---------------- bias pack for z-batched QKV
__global__ void pack_bias_kernel(const float* bq, const float* bk, const float* bv, float* out){
  int i = blockIdx.x*256 + threadIdx.x;
  if (i < 256) out[i] = bq[i];
  else if (i < 512) out[i] = bk[i-256];
  else if (i < 768) out[i] = bv[i-512];
}

// ---------------- attention prep: Q (scaled) and K fp32 -> hi/lo bf16
__global__ __launch_bounds__(256) void qksplit_kernel(
    const float* __restrict__ QP,
    __hip_bfloat16* __restrict__ qsh, __hip_bfloat16* __restrict__ qsl,
    __hip_bfloat16* __restrict__ ksh, __hip_bfloat16* __restrict__ ksl)
{
  int idx = blockIdx.x*256 + threadIdx.x;   // 1048576
  float qv = QP[idx] * 0.17677669529663687f;   // fold 1/sqrt(32)
  __hip_bfloat16 h, l;
  split2(qv, h, l); qsh[idx] = h; qsl[idx] = l;
  float kv = QP[1048576 + idx];
  split2(kv, h, l); ksh[idx] = h; ksl[idx] = l;
}

// ---------------- attention prep: V fp32 [s][256] -> V^T hi/lo [bh][32 d][1024 s]
__global__ __launch_bounds__(256) void vtrans_kernel(
    const float* __restrict__ VP,
    __hip_bfloat16* __restrict__ vth, __hip_bfloat16* __restrict__ vtl)
{
  int bh = blockIdx.y, bb = bh >> 3, h = bh & 7;
  int s0 = blockIdx.x*64;
  int tid = threadIdx.x;
  __shared__ float t[64][33];
  #pragma unroll
  for (int p=0;p<8;p++){
    int sl = (tid>>5) + p*8;
    int d = tid & 31;
    t[sl][d] = VP[((bb<<10)+s0+sl)*256 + h*32 + d];
  }
  __syncthreads();
  #pragma unroll
  for (int p=0;p<8;p++){
    int dl = (tid>>6) + p*4;
    int s = tid & 63;
    float v = t[s][dl];
    __hip_bfloat16 hh, ll; split2(v, hh, ll);
    vth[(bh*32+dl)*1024 + s0 + s] = hh;
    vtl[(bh*32+dl)*1024 + s0 + s] = ll;
  }
}

// ---------------- MFMA flash attention (split-bf16, online softmax)
// grid (16 q-blocks, 32 bh), 256 thr. Wave = 16 q rows; k-tiles of 32.
#define KSP 40
__global__ __launch_bounds__(256) void attn_mfma_kernel(
    const __hip_bfloat16* __restrict__ qsh_, const __hip_bfloat16* __restrict__ qsl_,
    const __hip_bfloat16* __restrict__ ksh_, const __hip_bfloat16* __restrict__ ksl_,
    const __hip_bfloat16* __restrict__ vth_, const __hip_bfloat16* __restrict__ vtl_,
    __hip_bfloat16* __restrict__ aoh, __hip_bfloat16* __restrict__ aol)
{
  const short* qsh = (const short*)qsh_; const short* qsl = (const short*)qsl_;
  const short* ksh = (const short*)ksh_; const short* ksl = (const short*)ksl_;
  const short* vth = (const short*)vth_; const short* vtl = (const short*)vtl_;
  int bh = blockIdx.y, bb = bh >> 3, h = bh & 7;
  int tid = threadIdx.x, lane = tid & 63, wave = tid >> 6;
  int ml = lane & 15, quad = lane >> 4;
  int q0 = blockIdx.x*64 + wave*16;

  __shared__ short KhS[32*KSP], KlS[32*KSP], VhS[32*KSP], VlS[32*KSP];
  __shared__ short PhS[4][16*KSP], PlS[4][16*KSP];
  short* Phw = PhS[wave]; short* Plw = PlS[wave];

  int qrow = (bb<<10) + q0 + ml;
  short8 qfh = *(const short8*)&qsh[qrow*256 + h*32 + quad*8];
  short8 qfl = *(const short8*)&qsl[qrow*256 + h*32 + quad*8];

  f32x4 O0 = {0.f,0.f,0.f,0.f}, O1 = {0.f,0.f,0.f,0.f};
  float m_[4], l_[4];
  #pragma unroll
  for (int r=0;r<4;r++){ m_[r] = -INFINITY; l_[r] = 0.f; }

  int sr = tid >> 3, sc = (tid & 7)*4;   // staging: 32 rows x 8 thr x 4 elems
  for (int k0 = 0; k0 < 1024; k0 += 32){
    int krow = (bb<<10) + k0 + sr;
    short4v kvh = *(const short4v*)&ksh[krow*256 + h*32 + sc];
    short4v kvl = *(const short4v*)&ksl[krow*256 + h*32 + sc];
    short4v vvh = *(const short4v*)&vth[(bh*32+sr)*1024 + k0 + sc];
    short4v vvl = *(const short4v*)&vtl[(bh*32+sr)*1024 + k0 + sc];
    __syncthreads();
    *(short4v*)&KhS[sr*KSP + sc] = kvh;
    *(short4v*)&KlS[sr*KSP + sc] = kvl;
    *(short4v*)&VhS[sr*KSP + sc] = vvh;
    *(short4v*)&VlS[sr*KSP + sc] = vvl;
    __syncthreads();
    // ---- QK^T: S[16 q][32 k] as two 16x16 C-tiles
    short8 kb0h = *(const short8*)&KhS[ml*KSP + quad*8];
    short8 kb0l = *(const short8*)&KlS[ml*KSP + quad*8];
    short8 kb1h = *(const short8*)&KhS[(16+ml)*KSP + quad*8];
    short8 kb1l = *(const short8*)&KlS[(16+ml)*KSP + quad*8];
    f32x4 S0 = {0.f,0.f,0.f,0.f}, S1 = {0.f,0.f,0.f,0.f};
    S0 = __builtin_amdgcn_mfma_f32_16x16x32_bf16(qfl, kb0h, S0, 0,0,0);
    S0 = __builtin_amdgcn_mfma_f32_16x16x32_bf16(qfh, kb0l, S0, 0,0,0);
    S0 = __builtin_amdgcn_mfma_f32_16x16x32_bf16(qfh, kb0h, S0, 0,0,0);
    S1 = __builtin_amdgcn_mfma_f32_16x16x32_bf16(qfl, kb1h, S1, 0,0,0);
    S1 = __builtin_amdgcn_mfma_f32_16x16x32_bf16(qfh, kb1l, S1, 0,0,0);
    S1 = __builtin_amdgcn_mfma_f32_16x16x32_bf16(qfh, kb1h, S1, 0,0,0);
    // ---- online softmax per q row (rows = quad*4+r, cols = ml / ml+16)
    #pragma unroll
    for (int r=0;r<4;r++){
      float tm = fmaxf(S0[r], S1[r]);
      #pragma unroll
      for (int o=1;o<16;o<<=1) tm = fmaxf(tm, __shfl_xor(tm, o, 64));
      float nm = fmaxf(m_[r], tm);
      float alpha = expf(m_[r] - nm);
      float p0 = expf(S0[r] - nm);
      float p1 = expf(S1[r] - nm);
      float ps = p0 + p1;
      #pragma unroll
      for (int o=1;o<16;o<<=1) ps += __shfl_xor(ps, o, 64);
      l_[r] = l_[r]*alpha + ps;
      m_[r] = nm;
      O0[r] *= alpha; O1[r] *= alpha;
      short sh, sl2;
      split2s(p0, sh, sl2);
      Phw[(quad*4+r)*KSP + ml] = sh;  Plw[(quad*4+r)*KSP + ml] = sl2;
      split2s(p1, sh, sl2);
      Phw[(quad*4+r)*KSP + 16 + ml] = sh;  Plw[(quad*4+r)*KSP + 16 + ml] = sl2;
    }
    // ---- P (A-layout via LDS round trip) x V^T -> O (same-wave, no barrier)
    short8 pAh = *(const short8*)&Phw[ml*KSP + quad*8];
    short8 pAl = *(const short8*)&Plw[ml*KSP + quad*8];
    short8 vb0h = *(const short8*)&VhS[ml*KSP + quad*8];
    short8 vb0l = *(const short8*)&VlS[ml*KSP + quad*8];
    short8 vb1h = *(const short8*)&VhS[(16+ml)*KSP + quad*8];
    short8 vb1l = *(const short8*)&VlS[(16+ml)*KSP + quad*8];
    O0 = __builtin_amdgcn_mfma_f32_16x16x32_bf16(pAl, vb0h, O0, 0,0,0);
    O0 = __builtin_amdgcn_mfma_f32_16x16x32_bf16(pAh, vb0l, O0, 0,0,0);
    O0 = __builtin_amdgcn_mfma_f32_16x16x32_bf16(pAh, vb0h, O0, 0,0,0);
    O1 = __builtin_amdgcn_mfma_f32_16x16x32_bf16(pAl, vb1h, O1, 0,0,0);
    O1 = __builtin_amdgcn_mfma_f32_16x16x32_bf16(pAh, vb1l, O1, 0,0,0);
    O1 = __builtin_amdgcn_mfma_f32_16x16x32_bf16(pAh, vb1h, O1, 0,0,0);
  }
  // ---- epilogue: O/l -> split bf16 attention out
  #pragma unroll
  for (int r=0;r<4;r++){
    float inv = 1.f / l_[r];
    int row = (bb<<10) + q0 + quad*4 + r;
    __hip_bfloat16 hh, ll;
    split2(O0[r]*inv, hh, ll);
    aoh[row*256 + h*32 + ml] = hh;       aol[row*256 + h*32 + ml] = ll;
    split2(O1[r]*inv, hh, ll);
    aoh[row*256 + h*32 + 16 + ml] = hh;  aol[row*256 + h*32 + 16 + ml] = ll;
  }
}

// ---------------- concat queries into x[:, 256:512]
__global__ __launch_bounds__(256) void concat_kernel(
    const float* __restrict__ queries, float* __restrict__ x)
{
  int idx = blockIdx.x*256 + threadIdx.x;
  int d = idx & 255; int r = idx >> 8;
  x[(r<<9) + 256 + d] = queries[idx];
}

// ---------------- rmsnorm fp32 out
__global__ __launch_bounds__(256) void rmsnorm_kernel(
    const float* __restrict__ x, const float* __restrict__ g, float* __restrict__ y)
{
  int r = blockIdx.x; int tid = threadIdx.x;
  float v0 = x[(r<<9) + tid];
  float v1 = x[(r<<9) + 256 + tid];
  float ss = v0*v0 + v1*v1;
  #pragma unroll
  for (int off=32; off>0; off>>=1) ss += __shfl_down(ss, off, 64);
  __shared__ float wsum[4];
  if ((tid & 63) == 0) wsum[tid>>6] = ss;
  __syncthreads();
  float tot = wsum[0]+wsum[1]+wsum[2]+wsum[3];
  float scale = 22.62741699796952f / fmaxf(sqrtf(tot), 1e-12f);
  y[(r<<9) + tid]       = v0*scale*g[tid];
  y[(r<<9) + 256 + tid] = v1*scale*g[256+tid];
}

// ---------------- rmsnorm hi/lo out
__global__ __launch_bounds__(256) void rmsnorm_split_kernel(
    const float* __restrict__ x, const float* __restrict__ g,
    __hip_bfloat16* __restrict__ yh, __hip_bfloat16* __restrict__ yl)
{
  int r = blockIdx.x; int tid = threadIdx.x;
  float v0 = x[(r<<9) + tid];
  float v1 = x[(r<<9) + 256 + tid];
  float ss = v0*v0 + v1*v1;
  #pragma unroll
  for (int off=32; off>0; off>>=1) ss += __shfl_down(ss, off, 64);
  __shared__ float wsum[4];
  if ((tid & 63) == 0) wsum[tid>>6] = ss;
  __syncthreads();
  float tot = wsum[0]+wsum[1]+wsum[2]+wsum[3];
  float scale = 22.62741699796952f / fmaxf(sqrtf(tot), 1e-12f);
  float a = v0*scale*g[tid];
  float b = v1*scale*g[256+tid];
  __hip_bfloat16 h, l;
  split2(a, h, l); yh[(r<<9)+tid] = h;     yl[(r<<9)+tid] = l;
  split2(b, h, l); yh[(r<<9)+256+tid] = h; yl[(r<<9)+256+tid] = l;
}

// ---------------- rmsnorm bf16 out (ffa path)
__global__ __launch_bounds__(256) void rmsnorm_bf_kernel(
    const float* __restrict__ x, const float* __restrict__ g, __hip_bfloat16* __restrict__ y)
{
  int r = blockIdx.x; int tid = threadIdx.x;
  float v0 = x[(r<<9) + tid];
  float v1 = x[(r<<9) + 256 + tid];
  float ss = v0*v0 + v1*v1;
  #pragma unroll
  for (int off=32; off>0; off>>=1) ss += __shfl_down(ss, off, 64);
  __shared__ float wsum[4];
  if ((tid & 63) == 0) wsum[tid>>6] = ss;
  __syncthreads();
  float tot = wsum[0]+wsum[1]+wsum[2]+wsum[3];
  float scale = 22.62741699796952f / fmaxf(sqrtf(tot), 1e-12f);
  y[(r<<9) + tid]       = __float2bfloat16(v0*scale*g[tid]);
  y[(r<<9) + 256 + tid] = __float2bfloat16(v1*scale*g[256+tid]);
}

// ---------------- geglu glu: H fp32 padded [4096][2816] -> T hi/lo [4096][1408]
__global__ __launch_bounds__(256) void glu_split_kernel(
    const float* __restrict__ h, const float* __restrict__ mult,
    __hip_bfloat16* __restrict__ th, __hip_bfloat16* __restrict__ tl)
{
  int idx = blockIdx.x*256 + threadIdx.x;   // 4096*1408
  int r = idx / 1408; int j = idx - r*1408;
  float v = 0.f;
  if (j < 1365){
    float a  = h[(long)r*2816 + j];
    float gt = h[(long)r*2816 + 1408 + j];
    v = gelu_f(gt) * a * mult[j];
  }
  __hip_bfloat16 hh, ll; split2(v, hh, ll);
  th[idx] = hh; tl[idx] = ll;
}

// ---------------- geglu glu bf16 (ffa path)
__global__ __launch_bounds__(256) void glu_bf_kernel(
    const __hip_bfloat16* __restrict__ h, const float* __restrict__ mult,
    __hip_bfloat16* __restrict__ t)
{
  int idx = blockIdx.x*256 + threadIdx.x;   // 4096*1408
  int r = idx / 1408; int j = idx - r*1408;
  float v = 0.f;
  if (j < 1365){
    float a  = __bfloat162float(h[(long)r*2816 + j]);
    float gt = __bfloat162float(h[(long)r*2816 + 1408 + j]);
    v = gelu_f(gt) * a * mult[j];
  }
  t[idx] = __float2bfloat16(v);
}

// ---------------- split fp32 -> hi/lo
__global__ __launch_bounds__(256) void split32_kernel(
    const float* __restrict__ x, __hip_bfloat16* __restrict__ h, __hip_bfloat16* __restrict__ l)
{
  int idx = blockIdx.x*256 + threadIdx.x;
  float v = x[idx];
  __hip_bfloat16 hh, ll; split2(v, hh, ll);
  h[idx] = hh; l[idx] = ll;
}

// ---------------- MoE init (sum_raw/z_sum only; scan writes everything else)
__global__ void moe_init_kernel(float* sum_raw, float* z_sum)
{
  int i = threadIdx.x;
  if (i < 64) sum_raw[i] = 0.f;
  if (i == 0) *z_sum = 0.f;
}

// ---------------- gating
__global__ __launch_bounds__(256) void gating_kernel(
    const float* __restrict__ xn, const float* __restrict__ gate_w,
    int* __restrict__ idx1, int* __restrict__ idx2, int* __restrict__ route,
    float* __restrict__ gg1, float* __restrict__ gg2,
    float* __restrict__ sum_raw, float* __restrict__ z_sum)
{
  int t = blockIdx.x; int tid = threadIdx.x;
  __shared__ float xrow[512];
  xrow[tid]     = xn[(t<<9)+tid];
  xrow[256+tid] = xn[(t<<9)+256+tid];
  __syncthreads();
  int e = tid >> 4, l16 = tid & 15;
  float p = 0.f;
  for (int d=l16; d<512; d+=16) p += xrow[d]*gate_w[(e<<9)+d];
  __shared__ float part[16][17];
  part[e][l16] = p;
  __syncthreads();
  __shared__ float raw[16];
  if (tid < 16){
    float s = 0.f;
    #pragma unroll
    for (int i=0;i<16;i++) s += part[tid][i];
    raw[tid] = s;
  }
  __syncthreads();
  if (tid == 0){
    float mx = -1e30f;
    #pragma unroll
    for (int i=0;i<16;i++) mx = fmaxf(mx, raw[i]);
    float r[16]; float sum = 0.f;
    #pragma unroll
    for (int i=0;i<16;i++){ r[i] = expf(raw[i]-mx); sum += r[i]; }
    float lse = mx + logf(sum);
    atomicAdd(z_sum, lse*lse);
    float inv = 1.f/sum;
    #pragma unroll
    for (int i=0;i<16;i++){ r[i] *= inv; raw[i] = r[i]; }
    int i1 = -1; float b1 = -1.f;
    #pragma unroll
    for (int i=0;i<16;i++) if (r[i] > b1){ b1 = r[i]; i1 = i; }
    int i2 = -1; float b2 = -1.f;
    #pragma unroll
    for (int i=0;i<16;i++) if (i != i1 && r[i] > b2){ b2 = r[i]; i2 = i; }
    float s2 = fmaxf(b1 + b2, 1e-9f);
    float g1n = b1/s2, g2n = b2/s2;
    idx1[t] = i1; idx2[t] = i2;
    route[t] = (g2n > 0.2f) ? 1 : 0;
    gg1[t] = g1n; gg2[t] = g2n;
  }
  __syncthreads();
  int bb = t >> 10;
  if (tid < 16) atomicAdd(&sum_raw[(bb<<4)+tid], raw[tid]);
}

// ---------------- capacity assignment: parallel segmented prefix scan
__global__ __launch_bounds__(256) void scan_kernel(
    const int* __restrict__ idx1, const int* __restrict__ idx2, const int* __restrict__ route,
    int* __restrict__ ts1, int* __restrict__ ts2, int* __restrict__ slot_token,
    int* __restrict__ count1)
{
  int bb = blockIdx.x >> 4;
  int e  = blockIdx.x & 15;
  int tid = threadIdx.x;
  int tbase = (bb<<10) + tid*4;
  int4 i1 = *(const int4*)&idx1[tbase];
  int4 i2 = *(const int4*)&idx2[tbase];
  int4 rt = *(const int4*)&route[tbase];
  int m1[4] = { i1.x==e, i1.y==e, i1.z==e, i1.w==e };
  int m2[4] = { i2.x==e, i2.y==e, i2.z==e, i2.w==e };
  int r4[4] = { rt.x, rt.y, rt.z, rt.w };
  int c1 = m1[0]+m1[1]+m1[2]+m1[3];
  int c2 = (m2[0]&&r4[0]) + (m2[1]&&r4[1]) + (m2[2]&&r4[2]) + (m2[3]&&r4[3]);
  __shared__ int s1[256], s2v[256];
  s1[tid] = c1; s2v[tid] = c2;
  __syncthreads();
  for (int off=1; off<256; off<<=1){
    int v1 = (tid>=off) ? s1[tid-off] : 0;
    int v2 = (tid>=off) ? s2v[tid-off] : 0;
    __syncthreads();
    s1[tid] += v1; s2v[tid] += v2;
    __syncthreads();
  }
  int tot1 = s1[255], tot2 = s2v[255];
  int p1 = s1[tid] - c1;
  int p2 = s2v[tid] - c2;
  if (tid == 0) count1[(bb<<4)+e] = tot1;
  int base = ((e<<2)+bb)*CAPN;
  #pragma unroll
  for (int i=0;i<4;i++){
    int t = tbase + i;
    if (m1[i]){
      if (p1 < CAPN){ ts1[t] = base+p1; slot_token[base+p1] = t; }
      else ts1[t] = -1;
      p1++;
    }
    if (m2[i]){
      if (r4[i]){
        int pos = tot1 + p2;
        if (pos < CAPN){ ts2[t] = base+pos; slot_token[base+pos] = t; }
        else ts2[t] = -1;
        p2++;
      } else ts2[t] = -1;
    }
  }
  int filled = min(CAPN, tot1 + tot2);
  if (tid < CAPN && tid >= filled) slot_token[base+tid] = -1;
}

// ---------------- gather + layernorm -> xin bf16
__global__ __launch_bounds__(256) void gather_ln_kernel(
    const float* __restrict__ xn, const int* __restrict__ slot_token,
    const float* __restrict__ ln_g, const float* __restrict__ ln_b,
    __hip_bfloat16* __restrict__ xin)
{
  int s = blockIdx.x; int tid = threadIdx.x;
  int t = slot_token[s];
  int e = s >> 9;
  if (t < 0){
    xin[(s<<9)+tid] = __float2bfloat16(0.f);
    xin[(s<<9)+256+tid] = __float2bfloat16(0.f);
    return;
  }
  float v0 = xn[(t<<9)+tid];
  float v1 = xn[(t<<9)+256+tid];
  float sm = v0+v1, sq = v0*v0+v1*v1;
  #pragma unroll
  for (int off=32; off>0; off>>=1){
    sm += __shfl_down(sm, off, 64);
    sq += __shfl_down(sq, off, 64);
  }
  __shared__ float s1[4], s2buf[4];
  if ((tid & 63) == 0){ s1[tid>>6] = sm; s2buf[tid>>6] = sq; }
  __syncthreads();
  float tsm = s1[0]+s1[1]+s1[2]+s1[3];
  float tsq = s2buf[0]+s2buf[1]+s2buf[2]+s2buf[3];
  float mean = tsm * (1.f/512.f);
  float var = tsq * (1.f/512.f) - mean*mean;
  float rstd = rsqrtf(var + 1e-5f);
  xin[(s<<9)+tid]     = __float2bfloat16((v0-mean)*rstd*ln_g[(e<<9)+tid]     + ln_b[(e<<9)+tid]);
  xin[(s<<9)+256+tid] = __float2bfloat16((v1-mean)*rstd*ln_g[(e<<9)+256+tid] + ln_b[(e<<9)+256+tid]);
}

// ---------------- combine (in-place)
__global__ __launch_bounds__(256) void combine_kernel(
    float* __restrict__ x, const float* __restrict__ h2,
    const int* __restrict__ ts1, const int* __restrict__ ts2,
    const float* __restrict__ gg1, const float* __restrict__ gg2)
{
  int idx = blockIdx.x*256 + threadIdx.x;
  int t = idx >> 9; int d = idx & 511;
  float v = x[idx];
  int s1 = ts1[t]; if (s1 >= 0) v += gg1[t]*h2[(s1<<9)+d];
  int s2 = ts2[t]; if (s2 >= 0) v += gg2[t]*h2[(s2<<9)+d];
  x[idx] = v;
}

// ---------------- aux losses
__global__ void aux_kernel(
    const float* __restrict__ sum_raw, const int* __restrict__ count1,
    const float* __restrict__ z_sum, float* __restrict__ out)
{
  int tid = threadIdx.x;
  float v = (sum_raw[tid] * (1.f/1024.f)) * ((float)count1[tid] * (1.f/1024.f));
  #pragma unroll
  for (int off=32; off>0; off>>=1) v += __shfl_down(v, off, 64);
  if (tid == 0){
    float bal = v * (1.f/64.f) * 256.f * 0.01f;
    float zl = (*z_sum) * (1.f/4096.f) * 0.001f;
    out[0] = bal + zl;
    out[1] = bal;
    out[2] = zl;
  }
}

extern "C" void kernel_launch(void* const* d_in, const int* in_sizes, int n_in,
                              void* d_out, int out_size, void* d_ws, size_t ws_size,
                              hipStream_t stream)
{
  const float* K_in   = (const float*)d_in[0];
  const float* V_in   = (const float*)d_in[1];
  const float* Q_in   = (const float*)d_in[2];
  const float* w_topo = (const float*)d_in[3];
  const float* b_topo = (const float*)d_in[4];
  const float* w_val  = (const float*)d_in[5];
  const float* b_val  = (const float*)d_in[6];
  const float* wq     = (const float*)d_in[7];
  const float* bq     = (const float*)d_in[8];
  const float* wk     = (const float*)d_in[9];
  const float* bk     = (const float*)d_in[10];
  const float* wv     = (const float*)d_in[11];
  const float* bv     = (const float*)d_in[12];
  const float* wo     = (const float*)d_in[13];
  const float* bo     = (const float*)d_in[14];
  const float* ffb_g  = (const float*)d_in[15];
  const float* ffb_w1 = (const float*)d_in[16];
  const float* ffb_b1 = (const float*)d_in[17];
  const float* ffb_mult=(const float*)d_in[18];
  const float* ffb_w2 = (const float*)d_in[19];
  const float* ffb_b2 = (const float*)d_in[20];
  const float* prenorm_g=(const float*)d_in[21];
  const float* gate_w = (const float*)d_in[22];
  const float* exp_ln_g=(const float*)d_in[23];
  const float* exp_ln_b=(const float*)d_in[24];
  const float* exp_w1 = (const float*)d_in[25];
  const float* exp_b1 = (const float*)d_in[26];
  const float* exp_w2 = (const float*)d_in[27];
  const float* exp_b2 = (const float*)d_in[28];
  const float* ffa_g  = (const float*)d_in[29];
  const float* ffa_w1 = (const float*)d_in[30];
  const float* ffa_b1 = (const float*)d_in[31];
  const float* ffa_mult=(const float*)d_in[32];
  const float* ffa_w2 = (const float*)d_in[33];
  const float* ffa_b2 = (const float*)d_in[34];
  const float* w_out  = (const float*)d_in[35];
  const float* b_out  = (const float*)d_in[36];
  float* dout = (float*)d_out;

  float* wsf = (float*)d_ws;
  int*   wsi = (int*)d_ws;

  // ---- layout (float offsets) ----
  const size_t A0 = 0;              // region A: 11,534,336 fl
  const size_t B0 = 11534336;       // region B:  5,767,168 fl (ends at OXA)
  const size_t OXA = 17301504;      // 2,097,152
  const size_t OXB = 19398656;      // 2,097,152
  const size_t OWP = 21495808;      // persistent split weights (393,216 fl)
  const size_t OMI = 21889024;      // misc

  // region A (early phases)
  __hip_bfloat16* qhi = (__hip_bfloat16*)(wsf + A0);
  __hip_bfloat16* khi = (__hip_bfloat16*)(wsf + A0 + 524288);
  __hip_bfloat16* vhi = (__hip_bfloat16*)(wsf + A0 + 1048576);
  __hip_bfloat16* qlo = (__hip_bfloat16*)(wsf + A0 + 1572864);
  __hip_bfloat16* klo = (__hip_bfloat16*)(wsf + A0 + 2097152);
  __hip_bfloat16* vlo = (__hip_bfloat16*)(wsf + A0 + 2621440);
  float* QP = wsf + A0 + 3145728;                         // 3x 1048576 (Q,K,V fp32)
  __hip_bfloat16* aohi = (__hip_bfloat16*)(wsf + A0 + 6291456);
  __hip_bfloat16* aolo = (__hip_bfloat16*)(wsf + A0 + 6815744);
  // attention prep (overwrites dead topo splits after QKV sgemm)
  __hip_bfloat16* qsh = (__hip_bfloat16*)(wsf + A0);
  __hip_bfloat16* qsl = (__hip_bfloat16*)(wsf + A0 + 524288);
  __hip_bfloat16* ksh = (__hip_bfloat16*)(wsf + A0 + 1048576);
  __hip_bfloat16* ksl = (__hip_bfloat16*)(wsf + A0 + 1572864);
  __hip_bfloat16* vth = (__hip_bfloat16*)(wsf + A0 + 2097152);
  __hip_bfloat16* vtl = (__hip_bfloat16*)(wsf + A0 + 2621440);
  // region B (early phases)
  float* QF = wsf + B0 + 262144;                          // 1048576
  // phase 5 (ffb)
  float* Hb = wsf + A0;                                   // fp32 [4096][2816] = 11534336 fl
  __hip_bfloat16* yh   = (__hip_bfloat16*)(wsf + B0);                 // 1048576 fl
  __hip_bfloat16* yl   = (__hip_bfloat16*)(wsf + B0 + 1048576);       // 1048576 fl
  __hip_bfloat16* fw1h = (__hip_bfloat16*)(wsf + B0 + 2097152);       // 720896 fl
  __hip_bfloat16* fw1l = fw1h + 1441792;                              // ends B0+3538944
  __hip_bfloat16* th   = (__hip_bfloat16*)(wsf + B0);                 // 2883584 fl (after GEMM1)
  __hip_bfloat16* tl   = (__hip_bfloat16*)(wsf + B0 + 2883584);       // ends B0+5767168
  __hip_bfloat16* fw2h = (__hip_bfloat16*)(wsf + A0);                 // after glu; Hb dead
  __hip_bfloat16* fw2l = fw2h + 720896;
  // phase 6 (MoE)
  __hip_bfloat16* wte   = (__hip_bfloat16*)(wsf + A0);
  __hip_bfloat16* xin_bf= (__hip_bfloat16*)(wsf + A0 + 5767168);
  __hip_bfloat16* h1_bf = (__hip_bfloat16*)(wsf + A0 + 7864320);
  float* H2 = wsf + 13631488;
  float* YM = wsf + B0;
  // phase 7 (ffa)
  __hip_bfloat16* y_bf = (__hip_bfloat16*)(wsf + A0);
  __hip_bfloat16* wf1  = (__hip_bfloat16*)(wsf + A0 + 1048576);
  __hip_bfloat16* h_bf = (__hip_bfloat16*)(wsf + A0 + 1769472);
  __hip_bfloat16* t_bf = (__hip_bfloat16*)(wsf + A0 + 7536640);
  __hip_bfloat16* wf2  = (__hip_bfloat16*)(wsf + A0 + 10420224);
  // phase 8
  __hip_bfloat16* xah = (__hip_bfloat16*)(wsf + A0);
  __hip_bfloat16* xal = (__hip_bfloat16*)(wsf + A0 + 1048576);
  // persistent weights
  __hip_bfloat16* wp = (__hip_bfloat16*)(wsf + OWP);
  __hip_bfloat16* wqh = wp;            __hip_bfloat16* wkh = wp + 65536;
  __hip_bfloat16* wvh = wp + 131072;   __hip_bfloat16* wql = wp + 196608;
  __hip_bfloat16* wkl = wp + 262144;   __hip_bfloat16* wvl = wp + 327680;
  __hip_bfloat16* woh = wp + 393216;   __hip_bfloat16* wol = wp + 458752;
  __hip_bfloat16* wouth = wp + 524288; __hip_bfloat16* woutl = wp + 655360;

  int* idx1 = wsi + OMI + 0;
  int* idx2 = wsi + OMI + 4096;
  int* route= wsi + OMI + 8192;
  int* ts1  = wsi + OMI + 12288;
  int* ts2  = wsi + OMI + 16384;
  int* slot_token = wsi + OMI + 20480;
  int* count1     = wsi + OMI + 28672;
  float* sum_raw  = wsf + OMI + 28736;
  float* z_sum    = wsf + OMI + 28800;
  float* gg1      = wsf + OMI + 28864;
  float* gg2      = wsf + OMI + 32960;
  float* bias_qkv = wsf + OMI + 37056;   // 768

  // ---- phase 0: static weight conversions ----
  convT2_kernel<<<dim3(4,4),  256, 0, stream>>>(wq, 256, 256, wqh, wql, 256, 256, 0, 0);
  convT2_kernel<<<dim3(4,4),  256, 0, stream>>>(wk, 256, 256, wkh, wkl, 256, 256, 0, 0);
  convT2_kernel<<<dim3(4,4),  256, 0, stream>>>(wv, 256, 256, wvh, wvl, 256, 256, 0, 0);
  convT2_kernel<<<dim3(4,4),  256, 0, stream>>>(wo, 256, 256, woh, wol, 256, 256, 0, 0);
  convT2_kernel<<<dim3(4,8),  256, 0, stream>>>(w_out, 256, 512, wouth, woutl, 256, 512, 0, 0);
  convT2_kernel<<<dim3(44,8), 256, 0, stream>>>(ffb_w1, 2730, 512, fw1h, fw1l, 2816, 512, 1365, 1408);
  pack_bias_kernel<<<3, 256, 0, stream>>>(bq, bk, bv, bias_qkv);

  // ---- phase 1: topo / values ----
  topo_kernel<<<8192, 256, 0, stream>>>(K_in, Q_in, w_topo, b_topo, khi, klo, qhi, qlo, QF);
  values_kernel<<<4096, 256, 0, stream>>>(V_in, w_val, b_val, vhi, vlo);

  // ---- phase 2: QKV projections (split MFMA, z-batched) ----
  sgemm_kernel<<<dim3(2,32,3), 256, 0, stream>>>(
      qhi, qlo, 256, 1048576, wqh, wql, 256, 65536,
      bias_qkv, 256, 0, 0, 256, nullptr, 0, QP, 256, 1048576, 256, 0);

  // ---- phase 3: MFMA flash attention ----
  qksplit_kernel<<<4096, 256, 0, stream>>>(QP, qsh, qsl, ksh, ksl);
  vtrans_kernel<<<dim3(16,32), 256, 0, stream>>>(QP + 2097152, vth, vtl);
  attn_mfma_kernel<<<dim3(16,32), 256, 0, stream>>>(qsh, qsl, ksh, ksl, vth, vtl, aohi, aolo);

  // ---- phase 4: o-proj into XA[:, :256] + concat queries ----
  sgemm_kernel<<<dim3(2,32,1), 256, 0, stream>>>(
      aohi, aolo, 256, 0, woh, wol, 256, 0,
      bo, 256, 0, 0, 0, nullptr, 0, wsf+OXA, 512, 0, 256, 0);
  concat_kernel<<<4096, 256, 0, stream>>>(QF, wsf+OXA);

  // ---- phase 5: ffb geglu (split MFMA) ----
  rmsnorm_split_kernel<<<4096, 256, 0, stream>>>(wsf+OXA, ffb_g, yh, yl);
  sgemm_kernel<<<dim3(22,32,1), 256, 0, stream>>>(
      yh, yl, 512, 0, fw1h, fw1l, 512, 0,
      ffb_b1, 2730, 1365, 1408, 0, nullptr, 0, Hb, 2816, 0, 512, 0);
  glu_split_kernel<<<22528, 256, 0, stream>>>(Hb, ffb_mult, th, tl);
  convT2_kernel<<<dim3(8,22), 256, 0, stream>>>(ffb_w2, 512, 1365, fw2h, fw2l, 512, 1408, 0, 0);
  sgemm_kernel<<<dim3(4,32,1), 256, 0, stream>>>(
      th, tl, 1408, 0, fw2h, fw2l, 1408, 0,
      ffb_b2, 512, 0, 0, 0, wsf+OXA, 512, wsf+OXB, 512, 0, 1408, 0);

  // ---- phase 6: MoE ----
  rmsnorm_kernel<<<4096, 256, 0, stream>>>(wsf+OXB, prenorm_g, YM);
  moe_init_kernel<<<1, 64, 0, stream>>>(sum_raw, z_sum);
  gating_kernel<<<4096, 256, 0, stream>>>(YM, gate_w, idx1, idx2, route, gg1, gg2, sum_raw, z_sum);
  scan_kernel<<<64, 256, 0, stream>>>(idx1, idx2, route, ts1, ts2, slot_token, count1);
  gather_ln_kernel<<<8192, 256, 0, stream>>>(YM, slot_token, exp_ln_g, exp_ln_b, xin_bf);
  convT_kernel<<<dim3(22, 8, 16), 256, 0, stream>>>(exp_w1, 1365, 512, (long)512*1365,
                                                    wte, 1408, 512, (long)1408*512, 0, 0);
  bgemm_kernel<<<dim3(11,4,16), 256, 0, stream>>>(
      xin_bf, 512, (long)512*512, wte, 512, (long)1408*512,
      exp_b1, 1365, 0, 0, 1365, nullptr, 0, 0,
      h1_bf, 1408, (long)512*1408, 1, 512, 2);
  convT_kernel<<<dim3(8, 22, 16), 256, 0, stream>>>(exp_w2, 512, 1365, (long)1365*512,
                                                    wte, 512, 1408, (long)512*1408, 0, 0);
  bgemm_kernel<<<dim3(4,4,16), 256, 0, stream>>>(
      h1_bf, 1408, (long)512*1408, wte, 1408, (long)512*1408,
      exp_b2, 512, 0, 0, 512, nullptr, 0, 0,
      H2, 512, (long)512*512, 0, 1408, 0);
  combine_kernel<<<8192, 256, 0, stream>>>(wsf+OXB, H2, ts1, ts2, gg1, gg2);
  aux_kernel<<<1, 64, 0, stream>>>(sum_raw, count1, z_sum, dout + 4096*256);

  // ---- phase 7: ffa geglu (bf16 MFMA) ----
  rmsnorm_bf_kernel<<<4096, 256, 0, stream>>>(wsf+OXB, ffa_g, y_bf);
  convT_kernel<<<dim3(44, 8, 1), 256, 0, stream>>>(ffa_w1, 2730, 512, 0,
                                                   wf1, 2816, 512, 0, 1365, 1408);
  bgemm_kernel<<<dim3(22,32,1), 256, 0, stream>>>(
      y_bf, 512, 0, wf1, 512, 0,
      ffa_b1, 2730, 1365, 1408, 0, nullptr, 0, 0,
      h_bf, 2816, 0, 1, 512, 0);
  glu_bf_kernel<<<22528, 256, 0, stream>>>(h_bf, ffa_mult, t_bf);
  convT_kernel<<<dim3(8, 22, 1), 256, 0, stream>>>(ffa_w2, 512, 1365, 0,
                                                   wf2, 512, 1408, 0, 0, 0);
  bgemm_kernel<<<dim3(4,32,1), 256, 0, stream>>>(
      t_bf, 1408, 0, wf2, 1408, 0,
      ffa_b2, 512, 0, 0, 0, wsf+OXB, 512, 0,
      wsf+OXA, 512, 0, 0, 1408, 0);

  // ---- phase 8: out = gelu(XA @ w_out + b_out) ----
  split32_kernel<<<8192, 256, 0, stream>>>(wsf+OXA, xah, xal);
  sgemm_kernel<<<dim3(2,32,1), 256, 0, stream>>>(
      xah, xal, 512, 0, wouth, woutl, 512, 0,
      b_out, 256, 0, 0, 0, nullptr, 0, dout, 256, 0, 512, 1);
}

// Round 7
// 926.019 us; speedup vs baseline: 3.2753x; 1.0495x over previous
//
#include <hip/hip_runtime.h>
#include <hip/hip_bf16.h>
#include <math.h>

// B=4 S=1024 DM=256 H=8 HD=32 CIN=23 E=16 D2=512 HE=1365 2HE=2730 CAP=128
#define CAPN 128

typedef short short8 __attribute__((ext_vector_type(8)));
typedef short short4v __attribute__((ext_vector_type(4)));
typedef float f32x4 __attribute__((ext_vector_type(4)));

__device__ __forceinline__ float gelu_f(float x){
  return 0.5f*x*(1.0f+erff(x*0.7071067811865476f));
}
__device__ __forceinline__ void split2(float v, __hip_bfloat16& h, __hip_bfloat16& l){
  h = __float2bfloat16(v);
  l = __float2bfloat16(v - __bfloat162float(h));
}
__device__ __forceinline__ void split2s(float v, short& h, short& l){
  __hip_bfloat16 hh = __float2bfloat16(v);
  __hip_bfloat16 ll = __float2bfloat16(v - __bfloat162float(hh));
  h = *(short*)&hh; l = *(short*)&ll;
}

// ---------------- topo
__global__ __launch_bounds__(256) void topo_kernel(
    const float* __restrict__ K, const float* __restrict__ Q,
    const float* __restrict__ w, const float* __restrict__ b,
    __hip_bfloat16* __restrict__ khi, __hip_bfloat16* __restrict__ klo,
    __hip_bfloat16* __restrict__ qhi, __hip_bfloat16* __restrict__ qlo,
    float* __restrict__ qf32)
{
  int idx = blockIdx.x*256 + threadIdx.x;   // 2M
  int d = idx & 255;
  int r = idx >> 8;
  int bb = r >> 11;
  int n  = r & 2047;
  const float* src = (n < 1024) ? (K + ((bb<<10) + n)*3)
                                : (Q + ((bb<<10) + (n-1024))*3);
  float v = b[d] + src[0]*w[d] + src[1]*w[256+d] + src[2]*w[512+d];
  v = gelu_f(v);
  int off = (((bb<<10) + (n & 1023))<<8) + d;
  __hip_bfloat16 h, l; split2(v, h, l);
  if (n < 1024){ khi[off] = h; klo[off] = l; }
  else         { qhi[off] = h; qlo[off] = l; qf32[off] = v; }
}

// ---------------- values
__global__ __launch_bounds__(256) void values_kernel(
    const float* __restrict__ V, const float* __restrict__ w,
    const float* __restrict__ b,
    __hip_bfloat16* __restrict__ vhi, __hip_bfloat16* __restrict__ vlo)
{
  int idx = blockIdx.x*256 + threadIdx.x;
  int d = idx & 255; int r = idx >> 8;
  const float* src = V + r*23;
  float acc = b[d];
  #pragma unroll
  for (int c=0;c<23;c++) acc += src[c]*w[c*256+d];
  acc = gelu_f(acc);
  __hip_bfloat16 h, l; split2(acc, h, l);
  vhi[idx] = h; vlo[idx] = l;
}

// ---------------- split-bf16 "fp32" MFMA GEMM (register-prefetch pipelined)
#define SLP 40
__global__ __launch_bounds__(256) void sgemm_kernel(
    const __hip_bfloat16* __restrict__ Ah_, const __hip_bfloat16* __restrict__ Al_,
    int lda, long sA,
    const __hip_bfloat16* __restrict__ Wh_, const __hip_bfloat16* __restrict__ Wl_,
    int ldw, long sW,
    const float* __restrict__ bias, int nbias, int bsplit, int bsplitPad, long sB,
    const float* __restrict__ R, int ldr,
    float* __restrict__ C, int ldc, long sC,
    int K, int act)
{
  int z = blockIdx.z;
  const short* Ah = (const short*)Ah_ + (long)z*sA;
  const short* Al = (const short*)Al_ + (long)z*sA;
  const short* Wh = (const short*)Wh_ + (long)z*sW;
  const short* Wl = (const short*)Wl_ + (long)z*sW;
  int bm = blockIdx.y*128, bn = blockIdx.x*128;
  int tid = threadIdx.x, lane = tid & 63, wave = tid >> 6;
  int wm = (wave & 1)*64, wn = (wave >> 1)*64;

  __shared__ short AsH[128*SLP], AsL[128*SLP], BsH[128*SLP], BsL[128*SLP];

  f32x4 acc[4][4];
  f32x4 zero4 = {0.f,0.f,0.f,0.f};
  #pragma unroll
  for (int i=0;i<4;i++)
    #pragma unroll
    for (int j=0;j<4;j++) acc[i][j] = zero4;

  int srow = tid >> 1, scol = (tid & 1)*16;
  int ml = lane & 15, q = lane >> 4;
  long abase = (long)(bm+srow)*lda + scol;
  long bbase = (long)(bn+srow)*ldw + scol;

  // preload k=0
  short8 ah0 = *(const short8*)&Ah[abase];
  short8 ah1 = *(const short8*)&Ah[abase + 8];
  short8 al0 = *(const short8*)&Al[abase];
  short8 al1 = *(const short8*)&Al[abase + 8];
  short8 bh0 = *(const short8*)&Wh[bbase];
  short8 bh1 = *(const short8*)&Wh[bbase + 8];
  short8 bl0 = *(const short8*)&Wl[bbase];
  short8 bl1 = *(const short8*)&Wl[bbase + 8];

  for (int k0 = 0; k0 < K; k0 += 32){
    __syncthreads();
    *(short8*)&AsH[srow*SLP + scol]     = ah0;
    *(short8*)&AsH[srow*SLP + scol + 8] = ah1;
    *(short8*)&AsL[srow*SLP + scol]     = al0;
    *(short8*)&AsL[srow*SLP + scol + 8] = al1;
    *(short8*)&BsH[srow*SLP + scol]     = bh0;
    *(short8*)&BsH[srow*SLP + scol + 8] = bh1;
    *(short8*)&BsL[srow*SLP + scol]     = bl0;
    *(short8*)&BsL[srow*SLP + scol + 8] = bl1;
    __syncthreads();
    // prefetch next tile (latency hidden under the MFMAs below)
    if (k0 + 32 < K){
      long ab = abase + k0 + 32;
      long bb2 = bbase + k0 + 32;
      ah0 = *(const short8*)&Ah[ab];
      ah1 = *(const short8*)&Ah[ab + 8];
      al0 = *(const short8*)&Al[ab];
      al1 = *(const short8*)&Al[ab + 8];
      bh0 = *(const short8*)&Wh[bb2];
      bh1 = *(const short8*)&Wh[bb2 + 8];
      bl0 = *(const short8*)&Wl[bb2];
      bl1 = *(const short8*)&Wl[bb2 + 8];
    }
    short8 afh[4], afl[4], bfh[4], bfl[4];
    #pragma unroll
    for (int i=0;i<4;i++){
      afh[i] = *(const short8*)&AsH[(wm + 16*i + ml)*SLP + q*8];
      afl[i] = *(const short8*)&AsL[(wm + 16*i + ml)*SLP + q*8];
    }
    #pragma unroll
    for (int j=0;j<4;j++){
      bfh[j] = *(const short8*)&BsH[(wn + 16*j + ml)*SLP + q*8];
      bfl[j] = *(const short8*)&BsL[(wn + 16*j + ml)*SLP + q*8];
    }
    #pragma unroll
    for (int i=0;i<4;i++)
      #pragma unroll
      for (int j=0;j<4;j++){
        acc[i][j] = __builtin_amdgcn_mfma_f32_16x16x32_bf16(afh[i], bfh[j], acc[i][j], 0,0,0);
        acc[i][j] = __builtin_amdgcn_mfma_f32_16x16x32_bf16(afh[i], bfl[j], acc[i][j], 0,0,0);
        acc[i][j] = __builtin_amdgcn_mfma_f32_16x16x32_bf16(afl[i], bfh[j], acc[i][j], 0,0,0);
      }
  }

  const float* biasz = bias ? bias + (long)z*sB : nullptr;
  long coff = (long)z*sC;
  #pragma unroll
  for (int i=0;i<4;i++){
    #pragma unroll
    for (int r=0;r<4;r++){
      int gm = bm + wm + 16*i + q*4 + r;
      #pragma unroll
      for (int j=0;j<4;j++){
        int gn = bn + wn + 16*j + ml;
        float v = acc[i][j][r];
        if (biasz){
          int bi;
          if (bsplit){
            if (gn < bsplit) bi = gn;
            else if (gn >= bsplitPad && gn < bsplitPad + (nbias - bsplit)) bi = gn - (bsplitPad - bsplit);
            else bi = -1;
          } else bi = (gn < nbias) ? gn : -1;
          if (bi >= 0) v += biasz[bi];
        }
        if (act == 1) v = gelu_f(v);
        if (R) v += R[(long)gm*ldr + gn];
        C[coff + (long)gm*ldc + gn] = v;
      }
    }
  }
}

// ---------------- pure-bf16 MFMA GEMM (register-prefetch pipelined)
#define LP 56
__global__ __launch_bounds__(256) void bgemm_kernel(
    const __hip_bfloat16* __restrict__ A, int lda, long sA,
    const __hip_bfloat16* __restrict__ WT, int ldw, long sW,
    const float* __restrict__ bias, int nbias, int bsplit, int bsplitPad, long sB,
    const float* __restrict__ R, int ldr, long sR,
    void* __restrict__ C, int ldc, long sC, int cIsBf16,
    int K, int act)
{
  int z = blockIdx.z;
  const short* Ab = (const short*)A + (long)z*sA;
  const short* Bb = (const short*)WT + (long)z*sW;
  int bm = blockIdx.y*128, bn = blockIdx.x*128;
  int tid = threadIdx.x, lane = tid & 63, wave = tid >> 6;
  int wm = (wave & 1)*64, wn = (wave >> 1)*64;

  __shared__ short As[128*LP];
  __shared__ short Bs[128*LP];

  f32x4 acc[4][4];
  f32x4 zero4 = {0.f,0.f,0.f,0.f};
  #pragma unroll
  for (int i=0;i<4;i++)
    #pragma unroll
    for (int j=0;j<4;j++) acc[i][j] = zero4;

  int g0 = tid, g1 = tid + 256;
  int r0 = g0 >> 2, c0 = (g0 & 3) * 8;
  int r1 = g1 >> 2, c1 = (g1 & 3) * 8;
  int ml = lane & 15, q = lane >> 4;
  long a0base = (long)(bm+r0)*lda + c0;
  long a1base = (long)(bm+r1)*lda + c1;
  long b0base = (long)(bn+r0)*ldw + c0;
  long b1base = (long)(bn+r1)*ldw + c1;

  short8 av0 = *(const short8*)&Ab[a0base];
  short8 av1 = *(const short8*)&Ab[a1base];
  short8 bv0 = *(const short8*)&Bb[b0base];
  short8 bv1 = *(const short8*)&Bb[b1base];

  for (int k0 = 0; k0 < K; k0 += 32){
    __syncthreads();
    *(short8*)&As[r0*LP + c0] = av0;
    *(short8*)&As[r1*LP + c1] = av1;
    *(short8*)&Bs[r0*LP + c0] = bv0;
    *(short8*)&Bs[r1*LP + c1] = bv1;
    __syncthreads();
    if (k0 + 32 < K){
      av0 = *(const short8*)&Ab[a0base + k0 + 32];
      av1 = *(const short8*)&Ab[a1base + k0 + 32];
      bv0 = *(const short8*)&Bb[b0base + k0 + 32];
      bv1 = *(const short8*)&Bb[b1base + k0 + 32];
    }
    short8 af[4], bfv[4];
    #pragma unroll
    for (int i=0;i<4;i++) af[i]  = *(const short8*)&As[(wm + 16*i + ml)*LP + q*8];
    #pragma unroll
    for (int j=0;j<4;j++) bfv[j] = *(const short8*)&Bs[(wn + 16*j + ml)*LP + q*8];
    #pragma unroll
    for (int i=0;i<4;i++)
      #pragma unroll
      for (int j=0;j<4;j++)
        acc[i][j] = __builtin_amdgcn_mfma_f32_16x16x32_bf16(af[i], bfv[j], acc[i][j], 0,0,0);
  }

  const float* biasz = bias ? bias + (long)z*sB : nullptr;
  const float* Rz = R ? R + (long)z*sR : nullptr;
  long coff = (long)z*sC;
  #pragma unroll
  for (int i=0;i<4;i++){
    #pragma unroll
    for (int r=0;r<4;r++){
      int gm = bm + wm + 16*i + q*4 + r;
      #pragma unroll
      for (int j=0;j<4;j++){
        int gn = bn + wn + 16*j + ml;
        float v = acc[i][j][r];
        if (biasz){
          int bi;
          if (bsplit){
            if (gn < bsplit) bi = gn;
            else if (gn >= bsplitPad && gn < bsplitPad + (nbias - bsplit)) bi = gn - (bsplitPad - bsplit);
            else bi = -1;
          } else bi = (gn < nbias) ? gn : -1;
          if (bi >= 0) v += biasz[bi];
        }
        if (act == 2) v = (v > 0.f) ? v : 0.01f*v;
        if (Rz) v += Rz[(long)gm*ldr + gn];
        if (cIsBf16) ((__hip_bfloat16*)C)[coff + (long)gm*ldc + gn] = __float2bfloat16(v);
        else         ((float*)C)[coff + (long)gm*ldc + gn] = v;
      }
    }
  }
}

// ---------------- weight transpose+convert (single bf16 out, z-batched)
__global__ __launch_bounds__(256) void convT_kernel(
    const float* __restrict__ W, int N, int K, long sW,
    __hip_bfloat16* __restrict__ out, int Npad, int Kpad, long sO,
    int split, int splitPad)
{
  int z = blockIdx.z;
  int n0 = blockIdx.x*64, k0 = blockIdx.y*64;
  int tid = threadIdx.x;
  __shared__ float lds[64][65];
  #pragma unroll
  for (int i=0;i<16;i++){
    int e = tid + i*256;
    int kl = e >> 6, c = e & 63;
    int np = n0 + c;
    int ns;
    if (split){
      if (np < split) ns = np;
      else if (np >= splitPad && np < splitPad + (N - split)) ns = np - (splitPad - split);
      else ns = -1;
    } else ns = (np < N) ? np : -1;
    int k = k0 + kl;
    float v = (ns >= 0 && k < K) ? W[(long)z*sW + (long)k*N + ns] : 0.f;
    lds[kl][c] = v;
  }
  __syncthreads();
  #pragma unroll
  for (int i=0;i<16;i++){
    int e = tid + i*256;
    int nl = e >> 6, kl = e & 63;
    out[(long)z*sO + (long)(n0+nl)*Kpad + k0 + kl] = __float2bfloat16(lds[kl][nl]);
  }
}

// ---------------- weight transpose+convert with hi/lo split
__global__ __launch_bounds__(256) void convT2_kernel(
    const float* __restrict__ W, int N, int K,
    __hip_bfloat16* __restrict__ outh, __hip_bfloat16* __restrict__ outl,
    int Npad, int Kpad, int split, int splitPad)
{
  int n0 = blockIdx.x*64, k0 = blockIdx.y*64;
  int tid = threadIdx.x;
  __shared__ float lds[64][65];
  #pragma unroll
  for (int i=0;i<16;i++){
    int e = tid + i*256;
    int kl = e >> 6, c = e & 63;
    int np = n0 + c;
    int ns;
    if (split){
      if (np < split) ns = np;
      else if (np >= splitPad && np < splitPad + (N - split)) ns = np - (splitPad - split);
      else ns = -1;
    } else ns = (np < N) ? np : -1;
    int k = k0 + kl;
    float v = (ns >= 0 && k < K) ? W[(long)k*N + ns] : 0.f;
    lds[kl][c] = v;
  }
  __syncthreads();
  #pragma unroll
  for (int i=0;i<16;i++){
    int e = tid + i*256;
    int nl = e >> 6, kl = e & 63;
    float v = lds[kl][nl];
    __hip_bfloat16 h, l; split2(v, h, l);
    long o = (long)(n0+nl)*Kpad + k0 + kl;
    outh[o] = h; outl[o] = l;
  }
}

// ---------------- bias pack for z-batched QKV
__global__ void pack_bias_kernel(const float* bq, const float* bk, const float* bv, float* out){
  int i = blockIdx.x*256 + threadIdx.x;
  if (i < 256) out[i] = bq[i];
  else if (i < 512) out[i] = bk[i-256];
  else if (i < 768) out[i] = bv[i-512];
}

// ---------------- attention prep: Q (scaled) and K fp32 -> hi/lo bf16
__global__ __launch_bounds__(256) void qksplit_kernel(
    const float* __restrict__ QP,
    __hip_bfloat16* __restrict__ qsh, __hip_bfloat16* __restrict__ qsl,
    __hip_bfloat16* __restrict__ ksh, __hip_bfloat16* __restrict__ ksl)
{
  int idx = blockIdx.x*256 + threadIdx.x;   // 1048576
  float qv = QP[idx] * 0.17677669529663687f;
  __hip_bfloat16 h, l;
  split2(qv, h, l); qsh[idx] = h; qsl[idx] = l;
  float kv = QP[1048576 + idx];
  split2(kv, h, l); ksh[idx] = h; ksl[idx] = l;
}

// ---------------- attention prep: V fp32 [s][256] -> V^T hi/lo [bh][32 d][1024 s]
__global__ __launch_bounds__(256) void vtrans_kernel(
    const float* __restrict__ VP,
    __hip_bfloat16* __restrict__ vth, __hip_bfloat16* __restrict__ vtl)
{
  int bh = blockIdx.y, bb = bh >> 3, h = bh & 7;
  int s0 = blockIdx.x*64;
  int tid = threadIdx.x;
  __shared__ float t[64][33];
  #pragma unroll
  for (int p=0;p<8;p++){
    int sl = (tid>>5) + p*8;
    int d = tid & 31;
    t[sl][d] = VP[((bb<<10)+s0+sl)*256 + h*32 + d];
  }
  __syncthreads();
  #pragma unroll
  for (int p=0;p<8;p++){
    int dl = (tid>>6) + p*4;
    int s = tid & 63;
    float v = t[s][dl];
    __hip_bfloat16 hh, ll; split2(v, hh, ll);
    vth[(bh*32+dl)*1024 + s0 + s] = hh;
    vtl[(bh*32+dl)*1024 + s0 + s] = ll;
  }
}

// ---------------- MFMA flash attention (split-bf16, online softmax)
#define KSP 40
__global__ __launch_bounds__(256) void attn_mfma_kernel(
    const __hip_bfloat16* __restrict__ qsh_, const __hip_bfloat16* __restrict__ qsl_,
    const __hip_bfloat16* __restrict__ ksh_, const __hip_bfloat16* __restrict__ ksl_,
    const __hip_bfloat16* __restrict__ vth_, const __hip_bfloat16* __restrict__ vtl_,
    __hip_bfloat16* __restrict__ aoh, __hip_bfloat16* __restrict__ aol)
{
  const short* qsh = (const short*)qsh_; const short* qsl = (const short*)qsl_;
  const short* ksh = (const short*)ksh_; const short* ksl = (const short*)ksl_;
  const short* vth = (const short*)vth_; const short* vtl = (const short*)vtl_;
  int bh = blockIdx.y, bb = bh >> 3, h = bh & 7;
  int tid = threadIdx.x, lane = tid & 63, wave = tid >> 6;
  int ml = lane & 15, quad = lane >> 4;
  int q0 = blockIdx.x*64 + wave*16;

  __shared__ short KhS[32*KSP], KlS[32*KSP], VhS[32*KSP], VlS[32*KSP];
  __shared__ short PhS[4][16*KSP], PlS[4][16*KSP];
  short* Phw = PhS[wave]; short* Plw = PlS[wave];

  int qrow = (bb<<10) + q0 + ml;
  short8 qfh = *(const short8*)&qsh[qrow*256 + h*32 + quad*8];
  short8 qfl = *(const short8*)&qsl[qrow*256 + h*32 + quad*8];

  f32x4 O0 = {0.f,0.f,0.f,0.f}, O1 = {0.f,0.f,0.f,0.f};
  float m_[4], l_[4];
  #pragma unroll
  for (int r=0;r<4;r++){ m_[r] = -INFINITY; l_[r] = 0.f; }

  int sr = tid >> 3, sc = (tid & 7)*4;
  for (int k0 = 0; k0 < 1024; k0 += 32){
    int krow = (bb<<10) + k0 + sr;
    short4v kvh = *(const short4v*)&ksh[krow*256 + h*32 + sc];
    short4v kvl = *(const short4v*)&ksl[krow*256 + h*32 + sc];
    short4v vvh = *(const short4v*)&vth[(bh*32+sr)*1024 + k0 + sc];
    short4v vvl = *(const short4v*)&vtl[(bh*32+sr)*1024 + k0 + sc];
    __syncthreads();
    *(short4v*)&KhS[sr*KSP + sc] = kvh;
    *(short4v*)&KlS[sr*KSP + sc] = kvl;
    *(short4v*)&VhS[sr*KSP + sc] = vvh;
    *(short4v*)&VlS[sr*KSP + sc] = vvl;
    __syncthreads();
    short8 kb0h = *(const short8*)&KhS[ml*KSP + quad*8];
    short8 kb0l = *(const short8*)&KlS[ml*KSP + quad*8];
    short8 kb1h = *(const short8*)&KhS[(16+ml)*KSP + quad*8];
    short8 kb1l = *(const short8*)&KlS[(16+ml)*KSP + quad*8];
    f32x4 S0 = {0.f,0.f,0.f,0.f}, S1 = {0.f,0.f,0.f,0.f};
    S0 = __builtin_amdgcn_mfma_f32_16x16x32_bf16(qfl, kb0h, S0, 0,0,0);
    S0 = __builtin_amdgcn_mfma_f32_16x16x32_bf16(qfh, kb0l, S0, 0,0,0);
    S0 = __builtin_amdgcn_mfma_f32_16x16x32_bf16(qfh, kb0h, S0, 0,0,0);
    S1 = __builtin_amdgcn_mfma_f32_16x16x32_bf16(qfl, kb1h, S1, 0,0,0);
    S1 = __builtin_amdgcn_mfma_f32_16x16x32_bf16(qfh, kb1l, S1, 0,0,0);
    S1 = __builtin_amdgcn_mfma_f32_16x16x32_bf16(qfh, kb1h, S1, 0,0,0);
    #pragma unroll
    for (int r=0;r<4;r++){
      float tm = fmaxf(S0[r], S1[r]);
      #pragma unroll
      for (int o=1;o<16;o<<=1) tm = fmaxf(tm, __shfl_xor(tm, o, 64));
      float nm = fmaxf(m_[r], tm);
      float alpha = expf(m_[r] - nm);
      float p0 = expf(S0[r] - nm);
      float p1 = expf(S1[r] - nm);
      float ps = p0 + p1;
      #pragma unroll
      for (int o=1;o<16;o<<=1) ps += __shfl_xor(ps, o, 64);
      l_[r] = l_[r]*alpha + ps;
      m_[r] = nm;
      O0[r] *= alpha; O1[r] *= alpha;
      short sh, sl2;
      split2s(p0, sh, sl2);
      Phw[(quad*4+r)*KSP + ml] = sh;  Plw[(quad*4+r)*KSP + ml] = sl2;
      split2s(p1, sh, sl2);
      Phw[(quad*4+r)*KSP + 16 + ml] = sh;  Plw[(quad*4+r)*KSP + 16 + ml] = sl2;
    }
    short8 pAh = *(const short8*)&Phw[ml*KSP + quad*8];
    short8 pAl = *(const short8*)&Plw[ml*KSP + quad*8];
    short8 vb0h = *(const short8*)&VhS[ml*KSP + quad*8];
    short8 vb0l = *(const short8*)&VlS[ml*KSP + quad*8];
    short8 vb1h = *(const short8*)&VhS[(16+ml)*KSP + quad*8];
    short8 vb1l = *(const short8*)&VlS[(16+ml)*KSP + quad*8];
    O0 = __builtin_amdgcn_mfma_f32_16x16x32_bf16(pAl, vb0h, O0, 0,0,0);
    O0 = __builtin_amdgcn_mfma_f32_16x16x32_bf16(pAh, vb0l, O0, 0,0,0);
    O0 = __builtin_amdgcn_mfma_f32_16x16x32_bf16(pAh, vb0h, O0, 0,0,0);
    O1 = __builtin_amdgcn_mfma_f32_16x16x32_bf16(pAl, vb1h, O1, 0,0,0);
    O1 = __builtin_amdgcn_mfma_f32_16x16x32_bf16(pAh, vb1l, O1, 0,0,0);
    O1 = __builtin_amdgcn_mfma_f32_16x16x32_bf16(pAh, vb1h, O1, 0,0,0);
  }
  #pragma unroll
  for (int r=0;r<4;r++){
    float inv = 1.f / l_[r];
    int row = (bb<<10) + q0 + quad*4 + r;
    __hip_bfloat16 hh, ll;
    split2(O0[r]*inv, hh, ll);
    aoh[row*256 + h*32 + ml] = hh;       aol[row*256 + h*32 + ml] = ll;
    split2(O1[r]*inv, hh, ll);
    aoh[row*256 + h*32 + 16 + ml] = hh;  aol[row*256 + h*32 + 16 + ml] = ll;
  }
}

// ---------------- concat queries into x[:, 256:512]
__global__ __launch_bounds__(256) void concat_kernel(
    const float* __restrict__ queries, float* __restrict__ x)
{
  int idx = blockIdx.x*256 + threadIdx.x;
  int d = idx & 255; int r = idx >> 8;
  x[(r<<9) + 256 + d] = queries[idx];
}

// ---------------- rmsnorm fp32 out
__global__ __launch_bounds__(256) void rmsnorm_kernel(
    const float* __restrict__ x, const float* __restrict__ g, float* __restrict__ y)
{
  int r = blockIdx.x; int tid = threadIdx.x;
  float v0 = x[(r<<9) + tid];
  float v1 = x[(r<<9) + 256 + tid];
  float ss = v0*v0 + v1*v1;
  #pragma unroll
  for (int off=32; off>0; off>>=1) ss += __shfl_down(ss, off, 64);
  __shared__ float wsum[4];
  if ((tid & 63) == 0) wsum[tid>>6] = ss;
  __syncthreads();
  float tot = wsum[0]+wsum[1]+wsum[2]+wsum[3];
  float scale = 22.62741699796952f / fmaxf(sqrtf(tot), 1e-12f);
  y[(r<<9) + tid]       = v0*scale*g[tid];
  y[(r<<9) + 256 + tid] = v1*scale*g[256+tid];
}

// ---------------- rmsnorm hi/lo out
__global__ __launch_bounds__(256) void rmsnorm_split_kernel(
    const float* __restrict__ x, const float* __restrict__ g,
    __hip_bfloat16* __restrict__ yh, __hip_bfloat16* __restrict__ yl)
{
  int r = blockIdx.x; int tid = threadIdx.x;
  float v0 = x[(r<<9) + tid];
  float v1 = x[(r<<9) + 256 + tid];
  float ss = v0*v0 + v1*v1;
  #pragma unroll
  for (int off=32; off>0; off>>=1) ss += __shfl_down(ss, off, 64);
  __shared__ float wsum[4];
  if ((tid & 63) == 0) wsum[tid>>6] = ss;
  __syncthreads();
  float tot = wsum[0]+wsum[1]+wsum[2]+wsum[3];
  float scale = 22.62741699796952f / fmaxf(sqrtf(tot), 1e-12f);
  float a = v0*scale*g[tid];
  float b = v1*scale*g[256+tid];
  __hip_bfloat16 h, l;
  split2(a, h, l); yh[(r<<9)+tid] = h;     yl[(r<<9)+tid] = l;
  split2(b, h, l); yh[(r<<9)+256+tid] = h; yl[(r<<9)+256+tid] = l;
}

// ---------------- rmsnorm bf16 out (ffa path)
__global__ __launch_bounds__(256) void rmsnorm_bf_kernel(
    const float* __restrict__ x, const float* __restrict__ g, __hip_bfloat16* __restrict__ y)
{
  int r = blockIdx.x; int tid = threadIdx.x;
  float v0 = x[(r<<9) + tid];
  float v1 = x[(r<<9) + 256 + tid];
  float ss = v0*v0 + v1*v1;
  #pragma unroll
  for (int off=32; off>0; off>>=1) ss += __shfl_down(ss, off, 64);
  __shared__ float wsum[4];
  if ((tid & 63) == 0) wsum[tid>>6] = ss;
  __syncthreads();
  float tot = wsum[0]+wsum[1]+wsum[2]+wsum[3];
  float scale = 22.62741699796952f / fmaxf(sqrtf(tot), 1e-12f);
  y[(r<<9) + tid]       = __float2bfloat16(v0*scale*g[tid]);
  y[(r<<9) + 256 + tid] = __float2bfloat16(v1*scale*g[256+tid]);
}

// ---------------- geglu glu: H fp32 padded [4096][2816] -> T hi/lo [4096][1408]
__global__ __launch_bounds__(256) void glu_split_kernel(
    const float* __restrict__ h, const float* __restrict__ mult,
    __hip_bfloat16* __restrict__ th, __hip_bfloat16* __restrict__ tl)
{
  int idx = blockIdx.x*256 + threadIdx.x;
  int r = idx / 1408; int j = idx - r*1408;
  float v = 0.f;
  if (j < 1365){
    float a  = h[(long)r*2816 + j];
    float gt = h[(long)r*2816 + 1408 + j];
    v = gelu_f(gt) * a * mult[j];
  }
  __hip_bfloat16 hh, ll; split2(v, hh, ll);
  th[idx] = hh; tl[idx] = ll;
}

// ---------------- geglu glu bf16 (ffa path)
__global__ __launch_bounds__(256) void glu_bf_kernel(
    const __hip_bfloat16* __restrict__ h, const float* __restrict__ mult,
    __hip_bfloat16* __restrict__ t)
{
  int idx = blockIdx.x*256 + threadIdx.x;
  int r = idx / 1408; int j = idx - r*1408;
  float v = 0.f;
  if (j < 1365){
    float a  = __bfloat162float(h[(long)r*2816 + j]);
    float gt = __bfloat162float(h[(long)r*2816 + 1408 + j]);
    v = gelu_f(gt) * a * mult[j];
  }
  t[idx] = __float2bfloat16(v);
}

// ---------------- split fp32 -> hi/lo
__global__ __launch_bounds__(256) void split32_kernel(
    const float* __restrict__ x, __hip_bfloat16* __restrict__ h, __hip_bfloat16* __restrict__ l)
{
  int idx = blockIdx.x*256 + threadIdx.x;
  float v = x[idx];
  __hip_bfloat16 hh, ll; split2(v, hh, ll);
  h[idx] = hh; l[idx] = ll;
}

// ---------------- MoE init
__global__ void moe_init_kernel(float* sum_raw, float* z_sum)
{
  int i = threadIdx.x;
  if (i < 64) sum_raw[i] = 0.f;
  if (i == 0) *z_sum = 0.f;
}

// ---------------- gating
__global__ __launch_bounds__(256) void gating_kernel(
    const float* __restrict__ xn, const float* __restrict__ gate_w,
    int* __restrict__ idx1, int* __restrict__ idx2, int* __restrict__ route,
    float* __restrict__ gg1, float* __restrict__ gg2,
    float* __restrict__ sum_raw, float* __restrict__ z_sum)
{
  int t = blockIdx.x; int tid = threadIdx.x;
  __shared__ float xrow[512];
  xrow[tid]     = xn[(t<<9)+tid];
  xrow[256+tid] = xn[(t<<9)+256+tid];
  __syncthreads();
  int e = tid >> 4, l16 = tid & 15;
  float p = 0.f;
  for (int d=l16; d<512; d+=16) p += xrow[d]*gate_w[(e<<9)+d];
  __shared__ float part[16][17];
  part[e][l16] = p;
  __syncthreads();
  __shared__ float raw[16];
  if (tid < 16){
    float s = 0.f;
    #pragma unroll
    for (int i=0;i<16;i++) s += part[tid][i];
    raw[tid] = s;
  }
  __syncthreads();
  if (tid == 0){
    float mx = -1e30f;
    #pragma unroll
    for (int i=0;i<16;i++) mx = fmaxf(mx, raw[i]);
    float r[16]; float sum = 0.f;
    #pragma unroll
    for (int i=0;i<16;i++){ r[i] = expf(raw[i]-mx); sum += r[i]; }
    float lse = mx + logf(sum);
    atomicAdd(z_sum, lse*lse);
    float inv = 1.f/sum;
    #pragma unroll
    for (int i=0;i<16;i++){ r[i] *= inv; raw[i] = r[i]; }
    int i1 = -1; float b1 = -1.f;
    #pragma unroll
    for (int i=0;i<16;i++) if (r[i] > b1){ b1 = r[i]; i1 = i; }
    int i2 = -1; float b2 = -1.f;
    #pragma unroll
    for (int i=0;i<16;i++) if (i != i1 && r[i] > b2){ b2 = r[i]; i2 = i; }
    float s2 = fmaxf(b1 + b2, 1e-9f);
    float g1n = b1/s2, g2n = b2/s2;
    idx1[t] = i1; idx2[t] = i2;
    route[t] = (g2n > 0.2f) ? 1 : 0;
    gg1[t] = g1n; gg2[t] = g2n;
  }
  __syncthreads();
  int bb = t >> 10;
  if (tid < 16) atomicAdd(&sum_raw[(bb<<4)+tid], raw[tid]);
}

// ---------------- capacity assignment: parallel segmented prefix scan
__global__ __launch_bounds__(256) void scan_kernel(
    const int* __restrict__ idx1, const int* __restrict__ idx2, const int* __restrict__ route,
    int* __restrict__ ts1, int* __restrict__ ts2, int* __restrict__ slot_token,
    int* __restrict__ count1)
{
  int bb = blockIdx.x >> 4;
  int e  = blockIdx.x & 15;
  int tid = threadIdx.x;
  int tbase = (bb<<10) + tid*4;
  int4 i1 = *(const int4*)&idx1[tbase];
  int4 i2 = *(const int4*)&idx2[tbase];
  int4 rt = *(const int4*)&route[tbase];
  int m1[4] = { i1.x==e, i1.y==e, i1.z==e, i1.w==e };
  int m2[4] = { i2.x==e, i2.y==e, i2.z==e, i2.w==e };
  int r4[4] = { rt.x, rt.y, rt.z, rt.w };
  int c1 = m1[0]+m1[1]+m1[2]+m1[3];
  int c2 = (m2[0]&&r4[0]) + (m2[1]&&r4[1]) + (m2[2]&&r4[2]) + (m2[3]&&r4[3]);
  __shared__ int s1[256], s2v[256];
  s1[tid] = c1; s2v[tid] = c2;
  __syncthreads();
  for (int off=1; off<256; off<<=1){
    int v1 = (tid>=off) ? s1[tid-off] : 0;
    int v2 = (tid>=off) ? s2v[tid-off] : 0;
    __syncthreads();
    s1[tid] += v1; s2v[tid] += v2;
    __syncthreads();
  }
  int tot1 = s1[255], tot2 = s2v[255];
  int p1 = s1[tid] - c1;
  int p2 = s2v[tid] - c2;
  if (tid == 0) count1[(bb<<4)+e] = tot1;
  int base = ((e<<2)+bb)*CAPN;
  #pragma unroll
  for (int i=0;i<4;i++){
    int t = tbase + i;
    if (m1[i]){
      if (p1 < CAPN){ ts1[t] = base+p1; slot_token[base+p1] = t; }
      else ts1[t] = -1;
      p1++;
    }
    if (m2[i]){
      if (r4[i]){
        int pos = tot1 + p2;
        if (pos < CAPN){ ts2[t] = base+pos; slot_token[base+pos] = t; }
        else ts2[t] = -1;
        p2++;
      } else ts2[t] = -1;
    }
  }
  int filled = min(CAPN, tot1 + tot2);
  if (tid < CAPN && tid >= filled) slot_token[base+tid] = -1;
}

// ---------------- gather + layernorm -> xin bf16
__global__ __launch_bounds__(256) void gather_ln_kernel(
    const float* __restrict__ xn, const int* __restrict__ slot_token,
    const float* __restrict__ ln_g, const float* __restrict__ ln_b,
    __hip_bfloat16* __restrict__ xin)
{
  int s = blockIdx.x; int tid = threadIdx.x;
  int t = slot_token[s];
  int e = s >> 9;
  if (t < 0){
    xin[(s<<9)+tid] = __float2bfloat16(0.f);
    xin[(s<<9)+256+tid] = __float2bfloat16(0.f);
    return;
  }
  float v0 = xn[(t<<9)+tid];
  float v1 = xn[(t<<9)+256+tid];
  float sm = v0+v1, sq = v0*v0+v1*v1;
  #pragma unroll
  for (int off=32; off>0; off>>=1){
    sm += __shfl_down(sm, off, 64);
    sq += __shfl_down(sq, off, 64);
  }
  __shared__ float s1[4], s2buf[4];
  if ((tid & 63) == 0){ s1[tid>>6] = sm; s2buf[tid>>6] = sq; }
  __syncthreads();
  float tsm = s1[0]+s1[1]+s1[2]+s1[3];
  float tsq = s2buf[0]+s2buf[1]+s2buf[2]+s2buf[3];
  float mean = tsm * (1.f/512.f);
  float var = tsq * (1.f/512.f) - mean*mean;
  float rstd = rsqrtf(var + 1e-5f);
  xin[(s<<9)+tid]     = __float2bfloat16((v0-mean)*rstd*ln_g[(e<<9)+tid]     + ln_b[(e<<9)+tid]);
  xin[(s<<9)+256+tid] = __float2bfloat16((v1-mean)*rstd*ln_g[(e<<9)+256+tid] + ln_b[(e<<9)+256+tid]);
}

// ---------------- combine (in-place)
__global__ __launch_bounds__(256) void combine_kernel(
    float* __restrict__ x, const float* __restrict__ h2,
    const int* __restrict__ ts1, const int* __restrict__ ts2,
    const float* __restrict__ gg1, const float* __restrict__ gg2)
{
  int idx = blockIdx.x*256 + threadIdx.x;
  int t = idx >> 9; int d = idx & 511;
  float v = x[idx];
  int s1 = ts1[t]; if (s1 >= 0) v += gg1[t]*h2[(s1<<9)+d];
  int s2 = ts2[t]; if (s2 >= 0) v += gg2[t]*h2[(s2<<9)+d];
  x[idx] = v;
}

// ---------------- aux losses
__global__ void aux_kernel(
    const float* __restrict__ sum_raw, const int* __restrict__ count1,
    const float* __restrict__ z_sum, float* __restrict__ out)
{
  int tid = threadIdx.x;
  float v = (sum_raw[tid] * (1.f/1024.f)) * ((float)count1[tid] * (1.f/1024.f));
  #pragma unroll
  for (int off=32; off>0; off>>=1) v += __shfl_down(v, off, 64);
  if (tid == 0){
    float bal = v * (1.f/64.f) * 256.f * 0.01f;
    float zl = (*z_sum) * (1.f/4096.f) * 0.001f;
    out[0] = bal + zl;
    out[1] = bal;
    out[2] = zl;
  }
}

extern "C" void kernel_launch(void* const* d_in, const int* in_sizes, int n_in,
                              void* d_out, int out_size, void* d_ws, size_t ws_size,
                              hipStream_t stream)
{
  const float* K_in   = (const float*)d_in[0];
  const float* V_in   = (const float*)d_in[1];
  const float* Q_in   = (const float*)d_in[2];
  const float* w_topo = (const float*)d_in[3];
  const float* b_topo = (const float*)d_in[4];
  const float* w_val  = (const float*)d_in[5];
  const float* b_val  = (const float*)d_in[6];
  const float* wq     = (const float*)d_in[7];
  const float* bq     = (const float*)d_in[8];
  const float* wk     = (const float*)d_in[9];
  const float* bk     = (const float*)d_in[10];
  const float* wv     = (const float*)d_in[11];
  const float* bv     = (const float*)d_in[12];
  const float* wo     = (const float*)d_in[13];
  const float* bo     = (const float*)d_in[14];
  const float* ffb_g  = (const float*)d_in[15];
  const float* ffb_w1 = (const float*)d_in[16];
  const float* ffb_b1 = (const float*)d_in[17];
  const float* ffb_mult=(const float*)d_in[18];
  const float* ffb_w2 = (const float*)d_in[19];
  const float* ffb_b2 = (const float*)d_in[20];
  const float* prenorm_g=(const float*)d_in[21];
  const float* gate_w = (const float*)d_in[22];
  const float* exp_ln_g=(const float*)d_in[23];
  const float* exp_ln_b=(const float*)d_in[24];
  const float* exp_w1 = (const float*)d_in[25];
  const float* exp_b1 = (const float*)d_in[26];
  const float* exp_w2 = (const float*)d_in[27];
  const float* exp_b2 = (const float*)d_in[28];
  const float* ffa_g  = (const float*)d_in[29];
  const float* ffa_w1 = (const float*)d_in[30];
  const float* ffa_b1 = (const float*)d_in[31];
  const float* ffa_mult=(const float*)d_in[32];
  const float* ffa_w2 = (const float*)d_in[33];
  const float* ffa_b2 = (const float*)d_in[34];
  const float* w_out  = (const float*)d_in[35];
  const float* b_out  = (const float*)d_in[36];
  float* dout = (float*)d_out;

  float* wsf = (float*)d_ws;
  int*   wsi = (int*)d_ws;

  // ---- layout (float offsets) ----
  const size_t A0 = 0;
  const size_t B0 = 11534336;
  const size_t OXA = 17301504;
  const size_t OXB = 19398656;
  const size_t OWP = 21495808;
  const size_t OMI = 21889024;

  __hip_bfloat16* qhi = (__hip_bfloat16*)(wsf + A0);
  __hip_bfloat16* khi = (__hip_bfloat16*)(wsf + A0 + 524288);
  __hip_bfloat16* vhi = (__hip_bfloat16*)(wsf + A0 + 1048576);
  __hip_bfloat16* qlo = (__hip_bfloat16*)(wsf + A0 + 1572864);
  __hip_bfloat16* klo = (__hip_bfloat16*)(wsf + A0 + 2097152);
  __hip_bfloat16* vlo = (__hip_bfloat16*)(wsf + A0 + 2621440);
  float* QP = wsf + A0 + 3145728;
  __hip_bfloat16* aohi = (__hip_bfloat16*)(wsf + A0 + 6291456);
  __hip_bfloat16* aolo = (__hip_bfloat16*)(wsf + A0 + 6815744);
  __hip_bfloat16* qsh = (__hip_bfloat16*)(wsf + A0);
  __hip_bfloat16* qsl = (__hip_bfloat16*)(wsf + A0 + 524288);
  __hip_bfloat16* ksh = (__hip_bfloat16*)(wsf + A0 + 1048576);
  __hip_bfloat16* ksl = (__hip_bfloat16*)(wsf + A0 + 1572864);
  __hip_bfloat16* vth = (__hip_bfloat16*)(wsf + A0 + 2097152);
  __hip_bfloat16* vtl = (__hip_bfloat16*)(wsf + A0 + 2621440);
  float* QF = wsf + B0 + 262144;
  float* Hb = wsf + A0;
  __hip_bfloat16* yh   = (__hip_bfloat16*)(wsf + B0);
  __hip_bfloat16* yl   = (__hip_bfloat16*)(wsf + B0 + 1048576);
  __hip_bfloat16* fw1h = (__hip_bfloat16*)(wsf + B0 + 2097152);
  __hip_bfloat16* fw1l = fw1h + 1441792;
  __hip_bfloat16* th   = (__hip_bfloat16*)(wsf + B0);
  __hip_bfloat16* tl   = (__hip_bfloat16*)(wsf + B0 + 2883584);
  __hip_bfloat16* fw2h = (__hip_bfloat16*)(wsf + A0);
  __hip_bfloat16* fw2l = fw2h + 720896;
  __hip_bfloat16* wte   = (__hip_bfloat16*)(wsf + A0);
  __hip_bfloat16* xin_bf= (__hip_bfloat16*)(wsf + A0 + 5767168);
  __hip_bfloat16* h1_bf = (__hip_bfloat16*)(wsf + A0 + 7864320);
  float* H2 = wsf + 13631488;
  float* YM = wsf + B0;
  __hip_bfloat16* y_bf = (__hip_bfloat16*)(wsf + A0);
  __hip_bfloat16* wf1  = (__hip_bfloat16*)(wsf + A0 + 1048576);
  __hip_bfloat16* h_bf = (__hip_bfloat16*)(wsf + A0 + 1769472);
  __hip_bfloat16* t_bf = (__hip_bfloat16*)(wsf + A0 + 7536640);
  __hip_bfloat16* wf2  = (__hip_bfloat16*)(wsf + A0 + 10420224);
  __hip_bfloat16* xah = (__hip_bfloat16*)(wsf + A0);
  __hip_bfloat16* xal = (__hip_bfloat16*)(wsf + A0 + 1048576);
  __hip_bfloat16* wp = (__hip_bfloat16*)(wsf + OWP);
  __hip_bfloat16* wqh = wp;            __hip_bfloat16* wkh = wp + 65536;
  __hip_bfloat16* wvh = wp + 131072;   __hip_bfloat16* wql = wp + 196608;
  __hip_bfloat16* wkl = wp + 262144;   __hip_bfloat16* wvl = wp + 327680;
  __hip_bfloat16* woh = wp + 393216;   __hip_bfloat16* wol = wp + 458752;
  __hip_bfloat16* wouth = wp + 524288; __hip_bfloat16* woutl = wp + 655360;

  int* idx1 = wsi + OMI + 0;
  int* idx2 = wsi + OMI + 4096;
  int* route= wsi + OMI + 8192;
  int* ts1  = wsi + OMI + 12288;
  int* ts2  = wsi + OMI + 16384;
  int* slot_token = wsi + OMI + 20480;
  int* count1     = wsi + OMI + 28672;
  float* sum_raw  = wsf + OMI + 28736;
  float* z_sum    = wsf + OMI + 28800;
  float* gg1      = wsf + OMI + 28864;
  float* gg2      = wsf + OMI + 32960;
  float* bias_qkv = wsf + OMI + 37056;

  // ---- phase 0: static weight conversions ----
  convT2_kernel<<<dim3(4,4),  256, 0, stream>>>(wq, 256, 256, wqh, wql, 256, 256, 0, 0);
  convT2_kernel<<<dim3(4,4),  256, 0, stream>>>(wk, 256, 256, wkh, wkl, 256, 256, 0, 0);
  convT2_kernel<<<dim3(4,4),  256, 0, stream>>>(wv, 256, 256, wvh, wvl, 256, 256, 0, 0);
  convT2_kernel<<<dim3(4,4),  256, 0, stream>>>(wo, 256, 256, woh, wol, 256, 256, 0, 0);
  convT2_kernel<<<dim3(4,8),  256, 0, stream>>>(w_out, 256, 512, wouth, woutl, 256, 512, 0, 0);
  convT2_kernel<<<dim3(44,8), 256, 0, stream>>>(ffb_w1, 2730, 512, fw1h, fw1l, 2816, 512, 1365, 1408);
  pack_bias_kernel<<<3, 256, 0, stream>>>(bq, bk, bv, bias_qkv);

  // ---- phase 1: topo / values ----
  topo_kernel<<<8192, 256, 0, stream>>>(K_in, Q_in, w_topo, b_topo, khi, klo, qhi, qlo, QF);
  values_kernel<<<4096, 256, 0, stream>>>(V_in, w_val, b_val, vhi, vlo);

  // ---- phase 2: QKV projections ----
  sgemm_kernel<<<dim3(2,32,3), 256, 0, stream>>>(
      qhi, qlo, 256, 1048576, wqh, wql, 256, 65536,
      bias_qkv, 256, 0, 0, 256, nullptr, 0, QP, 256, 1048576, 256, 0);

  // ---- phase 3: MFMA flash attention ----
  qksplit_kernel<<<4096, 256, 0, stream>>>(QP, qsh, qsl, ksh, ksl);
  vtrans_kernel<<<dim3(16,32), 256, 0, stream>>>(QP + 2097152, vth, vtl);
  attn_mfma_kernel<<<dim3(16,32), 256, 0, stream>>>(qsh, qsl, ksh, ksl, vth, vtl, aohi, aolo);

  // ---- phase 4: o-proj + concat ----
  sgemm_kernel<<<dim3(2,32,1), 256, 0, stream>>>(
      aohi, aolo, 256, 0, woh, wol, 256, 0,
      bo, 256, 0, 0, 0, nullptr, 0, wsf+OXA, 512, 0, 256, 0);
  concat_kernel<<<4096, 256, 0, stream>>>(QF, wsf+OXA);

  // ---- phase 5: ffb geglu ----
  rmsnorm_split_kernel<<<4096, 256, 0, stream>>>(wsf+OXA, ffb_g, yh, yl);
  sgemm_kernel<<<dim3(22,32,1), 256, 0, stream>>>(
      yh, yl, 512, 0, fw1h, fw1l, 512, 0,
      ffb_b1, 2730, 1365, 1408, 0, nullptr, 0, Hb, 2816, 0, 512, 0);
  glu_split_kernel<<<22528, 256, 0, stream>>>(Hb, ffb_mult, th, tl);
  convT2_kernel<<<dim3(8,22), 256, 0, stream>>>(ffb_w2, 512, 1365, fw2h, fw2l, 512, 1408, 0, 0);
  sgemm_kernel<<<dim3(4,32,1), 256, 0, stream>>>(
      th, tl, 1408, 0, fw2h, fw2l, 1408, 0,
      ffb_b2, 512, 0, 0, 0, wsf+OXA, 512, wsf+OXB, 512, 0, 1408, 0);

  // ---- phase 6: MoE ----
  rmsnorm_kernel<<<4096, 256, 0, stream>>>(wsf+OXB, prenorm_g, YM);
  moe_init_kernel<<<1, 64, 0, stream>>>(sum_raw, z_sum);
  gating_kernel<<<4096, 256, 0, stream>>>(YM, gate_w, idx1, idx2, route, gg1, gg2, sum_raw, z_sum);
  scan_kernel<<<64, 256, 0, stream>>>(idx1, idx2, route, ts1, ts2, slot_token, count1);
  gather_ln_kernel<<<8192, 256, 0, stream>>>(YM, slot_token, exp_ln_g, exp_ln_b, xin_bf);
  convT_kernel<<<dim3(22, 8, 16), 256, 0, stream>>>(exp_w1, 1365, 512, (long)512*1365,
                                                    wte, 1408, 512, (long)1408*512, 0, 0);
  bgemm_kernel<<<dim3(11,4,16), 256, 0, stream>>>(
      xin_bf, 512, (long)512*512, wte, 512, (long)1408*512,
      exp_b1, 1365, 0, 0, 1365, nullptr, 0, 0,
      h1_bf, 1408, (long)512*1408, 1, 512, 2);
  convT_kernel<<<dim3(8, 22, 16), 256, 0, stream>>>(exp_w2, 512, 1365, (long)1365*512,
                                                    wte, 512, 1408, (long)512*1408, 0, 0);
  bgemm_kernel<<<dim3(4,4,16), 256, 0, stream>>>(
      h1_bf, 1408, (long)512*1408, wte, 1408, (long)512*1408,
      exp_b2, 512, 0, 0, 512, nullptr, 0, 0,
      H2, 512, (long)512*512, 0, 1408, 0);
  combine_kernel<<<8192, 256, 0, stream>>>(wsf+OXB, H2, ts1, ts2, gg1, gg2);
  aux_kernel<<<1, 64, 0, stream>>>(sum_raw, count1, z_sum, dout + 4096*256);

  // ---- phase 7: ffa geglu ----
  rmsnorm_bf_kernel<<<4096, 256, 0, stream>>>(wsf+OXB, ffa_g, y_bf);
  convT_kernel<<<dim3(44, 8, 1), 256, 0, stream>>>(ffa_w1, 2730, 512, 0,
                                                   wf1, 2816, 512, 0, 1365, 1408);
  bgemm_kernel<<<dim3(22,32,1), 256, 0, stream>>>(
      y_bf, 512, 0, wf1, 512, 0,
      ffa_b1, 2730, 1365, 1408, 0, nullptr, 0, 0,
      h_bf, 2816, 0, 1, 512, 0);
  glu_bf_kernel<<<22528, 256, 0, stream>>>(h_bf, ffa_mult, t_bf);
  convT_kernel<<<dim3(8, 22, 1), 256, 0, stream>>>(ffa_w2, 512, 1365, 0,
                                                   wf2, 512, 1408, 0, 0, 0);
  bgemm_kernel<<<dim3(4,32,1), 256, 0, stream>>>(
      t_bf, 1408, 0, wf2, 1408, 0,
      ffa_b2, 512, 0, 0, 0, wsf+OXB, 512, 0,
      wsf+OXA, 512, 0, 0, 1408, 0);

  // ---- phase 8: out ----
  split32_kernel<<<8192, 256, 0, stream>>>(wsf+OXA, xah, xal);
  sgemm_kernel<<<dim3(2,32,1), 256, 0, stream>>>(
      xah, xal, 512, 0, wouth, woutl, 512, 0,
      b_out, 256, 0, 0, 0, nullptr, 0, dout, 256, 0, 512, 1);
}

// Round 8
// 858.320 us; speedup vs baseline: 3.5336x; 1.0789x over previous
//
#include <hip/hip_runtime.h>
#include <hip/hip_bf16.h>
#include <math.h>

// B=4 S=1024 DM=256 H=8 HD=32 CIN=23 E=16 D2=512 HE=1365 2HE=2730 CAP=128
#define CAPN 128

typedef short short8 __attribute__((ext_vector_type(8)));
typedef short short4v __attribute__((ext_vector_type(4)));
typedef float f32x4 __attribute__((ext_vector_type(4)));

__device__ __forceinline__ float gelu_f(float x){
  return 0.5f*x*(1.0f+erff(x*0.7071067811865476f));
}
__device__ __forceinline__ void split2(float v, __hip_bfloat16& h, __hip_bfloat16& l){
  h = __float2bfloat16(v);
  l = __float2bfloat16(v - __bfloat162float(h));
}
__device__ __forceinline__ void split2s(float v, short& h, short& l){
  __hip_bfloat16 hh = __float2bfloat16(v);
  __hip_bfloat16 ll = __float2bfloat16(v - __bfloat162float(hh));
  h = *(short*)&hh; l = *(short*)&ll;
}

// ---------------- topo
__global__ __launch_bounds__(256) void topo_kernel(
    const float* __restrict__ K, const float* __restrict__ Q,
    const float* __restrict__ w, const float* __restrict__ b,
    __hip_bfloat16* __restrict__ khi, __hip_bfloat16* __restrict__ klo,
    __hip_bfloat16* __restrict__ qhi, __hip_bfloat16* __restrict__ qlo,
    float* __restrict__ qf32)
{
  int idx = blockIdx.x*256 + threadIdx.x;   // 2M
  int d = idx & 255;
  int r = idx >> 8;
  int bb = r >> 11;
  int n  = r & 2047;
  const float* src = (n < 1024) ? (K + ((bb<<10) + n)*3)
                                : (Q + ((bb<<10) + (n-1024))*3);
  float v = b[d] + src[0]*w[d] + src[1]*w[256+d] + src[2]*w[512+d];
  v = gelu_f(v);
  int off = (((bb<<10) + (n & 1023))<<8) + d;
  __hip_bfloat16 h, l; split2(v, h, l);
  if (n < 1024){ khi[off] = h; klo[off] = l; }
  else         { qhi[off] = h; qlo[off] = l; qf32[off] = v; }
}

// ---------------- values
__global__ __launch_bounds__(256) void values_kernel(
    const float* __restrict__ V, const float* __restrict__ w,
    const float* __restrict__ b,
    __hip_bfloat16* __restrict__ vhi, __hip_bfloat16* __restrict__ vlo)
{
  int idx = blockIdx.x*256 + threadIdx.x;
  int d = idx & 255; int r = idx >> 8;
  const float* src = V + r*23;
  float acc = b[d];
  #pragma unroll
  for (int c=0;c<23;c++) acc += src[c]*w[c*256+d];
  acc = gelu_f(acc);
  __hip_bfloat16 h, l; split2(acc, h, l);
  vhi[idx] = h; vlo[idx] = l;
}

// ---------------- split-bf16 "fp32" MFMA GEMM (pipelined, optional split-K)
// splitK>1: blockIdx.z = zz*splitK + kc; raw partials go to P + blockIdx.z*pz.
#define SLP 40
__global__ __launch_bounds__(256) void sgemm_kernel(
    const __hip_bfloat16* __restrict__ Ah_, const __hip_bfloat16* __restrict__ Al_,
    int lda, long sA,
    const __hip_bfloat16* __restrict__ Wh_, const __hip_bfloat16* __restrict__ Wl_,
    int ldw, long sW,
    const float* __restrict__ bias, int nbias, int bsplit, int bsplitPad, long sB,
    const float* __restrict__ R, int ldr,
    float* __restrict__ C, int ldc, long sC,
    int K, int act,
    float* __restrict__ P, long pz, int splitK)
{
  int z = blockIdx.z / splitK;
  int kc = blockIdx.z - z*splitK;
  const short* Ah = (const short*)Ah_ + (long)z*sA;
  const short* Al = (const short*)Al_ + (long)z*sA;
  const short* Wh = (const short*)Wh_ + (long)z*sW;
  const short* Wl = (const short*)Wl_ + (long)z*sW;
  int bm = blockIdx.y*128, bn = blockIdx.x*128;
  int tid = threadIdx.x, lane = tid & 63, wave = tid >> 6;
  int wm = (wave & 1)*64, wn = (wave >> 1)*64;

  __shared__ short AsH[128*SLP], AsL[128*SLP], BsH[128*SLP], BsL[128*SLP];

  f32x4 acc[4][4];
  f32x4 zero4 = {0.f,0.f,0.f,0.f};
  #pragma unroll
  for (int i=0;i<4;i++)
    #pragma unroll
    for (int j=0;j<4;j++) acc[i][j] = zero4;

  int srow = tid >> 1, scol = (tid & 1)*16;
  int ml = lane & 15, q = lane >> 4;
  long abase = (long)(bm+srow)*lda + scol;
  long bbase = (long)(bn+srow)*ldw + scol;

  int Kc = K / splitK;
  int kbeg = kc * Kc, kend = kbeg + Kc;

  short8 ah0 = *(const short8*)&Ah[abase + kbeg];
  short8 ah1 = *(const short8*)&Ah[abase + kbeg + 8];
  short8 al0 = *(const short8*)&Al[abase + kbeg];
  short8 al1 = *(const short8*)&Al[abase + kbeg + 8];
  short8 bh0 = *(const short8*)&Wh[bbase + kbeg];
  short8 bh1 = *(const short8*)&Wh[bbase + kbeg + 8];
  short8 bl0 = *(const short8*)&Wl[bbase + kbeg];
  short8 bl1 = *(const short8*)&Wl[bbase + kbeg + 8];

  for (int k0 = kbeg; k0 < kend; k0 += 32){
    __syncthreads();
    *(short8*)&AsH[srow*SLP + scol]     = ah0;
    *(short8*)&AsH[srow*SLP + scol + 8] = ah1;
    *(short8*)&AsL[srow*SLP + scol]     = al0;
    *(short8*)&AsL[srow*SLP + scol + 8] = al1;
    *(short8*)&BsH[srow*SLP + scol]     = bh0;
    *(short8*)&BsH[srow*SLP + scol + 8] = bh1;
    *(short8*)&BsL[srow*SLP + scol]     = bl0;
    *(short8*)&BsL[srow*SLP + scol + 8] = bl1;
    __syncthreads();
    if (k0 + 32 < kend){
      long ab = abase + k0 + 32;
      long bb2 = bbase + k0 + 32;
      ah0 = *(const short8*)&Ah[ab];
      ah1 = *(const short8*)&Ah[ab + 8];
      al0 = *(const short8*)&Al[ab];
      al1 = *(const short8*)&Al[ab + 8];
      bh0 = *(const short8*)&Wh[bb2];
      bh1 = *(const short8*)&Wh[bb2 + 8];
      bl0 = *(const short8*)&Wl[bb2];
      bl1 = *(const short8*)&Wl[bb2 + 8];
    }
    short8 afh[4], afl[4], bfh[4], bfl[4];
    #pragma unroll
    for (int i=0;i<4;i++){
      afh[i] = *(const short8*)&AsH[(wm + 16*i + ml)*SLP + q*8];
      afl[i] = *(const short8*)&AsL[(wm + 16*i + ml)*SLP + q*8];
    }
    #pragma unroll
    for (int j=0;j<4;j++){
      bfh[j] = *(const short8*)&BsH[(wn + 16*j + ml)*SLP + q*8];
      bfl[j] = *(const short8*)&BsL[(wn + 16*j + ml)*SLP + q*8];
    }
    #pragma unroll
    for (int i=0;i<4;i++)
      #pragma unroll
      for (int j=0;j<4;j++){
        acc[i][j] = __builtin_amdgcn_mfma_f32_16x16x32_bf16(afh[i], bfh[j], acc[i][j], 0,0,0);
        acc[i][j] = __builtin_amdgcn_mfma_f32_16x16x32_bf16(afh[i], bfl[j], acc[i][j], 0,0,0);
        acc[i][j] = __builtin_amdgcn_mfma_f32_16x16x32_bf16(afl[i], bfh[j], acc[i][j], 0,0,0);
      }
  }

  if (P){   // raw partial store (split-K path)
    float* Pb = P + (long)blockIdx.z * pz;
    #pragma unroll
    for (int i=0;i<4;i++)
      #pragma unroll
      for (int r=0;r<4;r++){
        int gm = bm + wm + 16*i + q*4 + r;
        #pragma unroll
        for (int j=0;j<4;j++){
          int gn = bn + wn + 16*j + ml;
          Pb[(long)gm*ldc + gn] = acc[i][j][r];
        }
      }
    return;
  }

  const float* biasz = bias ? bias + (long)z*sB : nullptr;
  long coff = (long)z*sC;
  #pragma unroll
  for (int i=0;i<4;i++){
    #pragma unroll
    for (int r=0;r<4;r++){
      int gm = bm + wm + 16*i + q*4 + r;
      #pragma unroll
      for (int j=0;j<4;j++){
        int gn = bn + wn + 16*j + ml;
        float v = acc[i][j][r];
        if (biasz){
          int bi;
          if (bsplit){
            if (gn < bsplit) bi = gn;
            else if (gn >= bsplitPad && gn < bsplitPad + (nbias - bsplit)) bi = gn - (bsplitPad - bsplit);
            else bi = -1;
          } else bi = (gn < nbias) ? gn : -1;
          if (bi >= 0) v += biasz[bi];
        }
        if (act == 1) v = gelu_f(v);
        if (R) v += R[(long)gm*ldr + gn];
        C[coff + (long)gm*ldc + gn] = v;
      }
    }
  }
}

// ---------------- pure-bf16 MFMA GEMM (pipelined, optional split-K)
#define LP 56
__global__ __launch_bounds__(256) void bgemm_kernel(
    const __hip_bfloat16* __restrict__ A, int lda, long sA,
    const __hip_bfloat16* __restrict__ WT, int ldw, long sW,
    const float* __restrict__ bias, int nbias, int bsplit, int bsplitPad, long sB,
    const float* __restrict__ R, int ldr, long sR,
    void* __restrict__ C, int ldc, long sC, int cIsBf16,
    int K, int act,
    float* __restrict__ P, long pz, int splitK)
{
  int z = blockIdx.z / splitK;
  int kc = blockIdx.z - z*splitK;
  const short* Ab = (const short*)A + (long)z*sA;
  const short* Bb = (const short*)WT + (long)z*sW;
  int bm = blockIdx.y*128, bn = blockIdx.x*128;
  int tid = threadIdx.x, lane = tid & 63, wave = tid >> 6;
  int wm = (wave & 1)*64, wn = (wave >> 1)*64;

  __shared__ short As[128*LP];
  __shared__ short Bs[128*LP];

  f32x4 acc[4][4];
  f32x4 zero4 = {0.f,0.f,0.f,0.f};
  #pragma unroll
  for (int i=0;i<4;i++)
    #pragma unroll
    for (int j=0;j<4;j++) acc[i][j] = zero4;

  int g0 = tid, g1 = tid + 256;
  int r0 = g0 >> 2, c0 = (g0 & 3) * 8;
  int r1 = g1 >> 2, c1 = (g1 & 3) * 8;
  int ml = lane & 15, q = lane >> 4;
  long a0base = (long)(bm+r0)*lda + c0;
  long a1base = (long)(bm+r1)*lda + c1;
  long b0base = (long)(bn+r0)*ldw + c0;
  long b1base = (long)(bn+r1)*ldw + c1;

  int Kc = K / splitK;
  int kbeg = kc * Kc, kend = kbeg + Kc;

  short8 av0 = *(const short8*)&Ab[a0base + kbeg];
  short8 av1 = *(const short8*)&Ab[a1base + kbeg];
  short8 bv0 = *(const short8*)&Bb[b0base + kbeg];
  short8 bv1 = *(const short8*)&Bb[b1base + kbeg];

  for (int k0 = kbeg; k0 < kend; k0 += 32){
    __syncthreads();
    *(short8*)&As[r0*LP + c0] = av0;
    *(short8*)&As[r1*LP + c1] = av1;
    *(short8*)&Bs[r0*LP + c0] = bv0;
    *(short8*)&Bs[r1*LP + c1] = bv1;
    __syncthreads();
    if (k0 + 32 < kend){
      av0 = *(const short8*)&Ab[a0base + k0 + 32];
      av1 = *(const short8*)&Ab[a1base + k0 + 32];
      bv0 = *(const short8*)&Bb[b0base + k0 + 32];
      bv1 = *(const short8*)&Bb[b1base + k0 + 32];
    }
    short8 af[4], bfv[4];
    #pragma unroll
    for (int i=0;i<4;i++) af[i]  = *(const short8*)&As[(wm + 16*i + ml)*LP + q*8];
    #pragma unroll
    for (int j=0;j<4;j++) bfv[j] = *(const short8*)&Bs[(wn + 16*j + ml)*LP + q*8];
    #pragma unroll
    for (int i=0;i<4;i++)
      #pragma unroll
      for (int j=0;j<4;j++)
        acc[i][j] = __builtin_amdgcn_mfma_f32_16x16x32_bf16(af[i], bfv[j], acc[i][j], 0,0,0);
  }

  if (P){
    float* Pb = P + (long)blockIdx.z * pz;
    #pragma unroll
    for (int i=0;i<4;i++)
      #pragma unroll
      for (int r=0;r<4;r++){
        int gm = bm + wm + 16*i + q*4 + r;
        #pragma unroll
        for (int j=0;j<4;j++){
          int gn = bn + wn + 16*j + ml;
          Pb[(long)gm*ldc + gn] = acc[i][j][r];
        }
      }
    return;
  }

  const float* biasz = bias ? bias + (long)z*sB : nullptr;
  const float* Rz = R ? R + (long)z*sR : nullptr;
  long coff = (long)z*sC;
  #pragma unroll
  for (int i=0;i<4;i++){
    #pragma unroll
    for (int r=0;r<4;r++){
      int gm = bm + wm + 16*i + q*4 + r;
      #pragma unroll
      for (int j=0;j<4;j++){
        int gn = bn + wn + 16*j + ml;
        float v = acc[i][j][r];
        if (biasz){
          int bi;
          if (bsplit){
            if (gn < bsplit) bi = gn;
            else if (gn >= bsplitPad && gn < bsplitPad + (nbias - bsplit)) bi = gn - (bsplitPad - bsplit);
            else bi = -1;
          } else bi = (gn < nbias) ? gn : -1;
          if (bi >= 0) v += biasz[bi];
        }
        if (act == 2) v = (v > 0.f) ? v : 0.01f*v;
        if (Rz) v += Rz[(long)gm*ldr + gn];
        if (cIsBf16) ((__hip_bfloat16*)C)[coff + (long)gm*ldc + gn] = __float2bfloat16(v);
        else         ((float*)C)[coff + (long)gm*ldc + gn] = v;
      }
    }
  }
}

// ---------------- split-K reduce: out = act(sum_k P_k + bias) (+R)
__global__ __launch_bounds__(256) void reduce_kernel(
    const float* __restrict__ P, long zStride, int nsplit,
    const float* __restrict__ bias,
    const float* __restrict__ R, float* __restrict__ out,
    int Nmask, int logN, int ldOut, int act, long total)
{
  long idx = (long)blockIdx.x*256 + threadIdx.x;
  if (idx >= total) return;
  long zz = idx / zStride;
  long rem = idx - zz*zStride;
  const float* Pb = P + zz*(long)nsplit*zStride + rem;
  float v = 0.f;
  for (int k=0;k<nsplit;k++) v += Pb[(long)k*zStride];
  int n = (int)(idx & Nmask);
  long row = idx >> logN;
  if (bias) v += bias[n];
  if (act == 1) v = gelu_f(v);
  long o = row*(long)ldOut + n;
  if (R) v += R[o];
  out[o] = v;
}

// ---------------- weight transpose+convert (single bf16 out, z-batched)
__global__ __launch_bounds__(256) void convT_kernel(
    const float* __restrict__ W, int N, int K, long sW,
    __hip_bfloat16* __restrict__ out, int Npad, int Kpad, long sO,
    int split, int splitPad)
{
  int z = blockIdx.z;
  int n0 = blockIdx.x*64, k0 = blockIdx.y*64;
  int tid = threadIdx.x;
  __shared__ float lds[64][65];
  #pragma unroll
  for (int i=0;i<16;i++){
    int e = tid + i*256;
    int kl = e >> 6, c = e & 63;
    int np = n0 + c;
    int ns;
    if (split){
      if (np < split) ns = np;
      else if (np >= splitPad && np < splitPad + (N - split)) ns = np - (splitPad - split);
      else ns = -1;
    } else ns = (np < N) ? np : -1;
    int k = k0 + kl;
    float v = (ns >= 0 && k < K) ? W[(long)z*sW + (long)k*N + ns] : 0.f;
    lds[kl][c] = v;
  }
  __syncthreads();
  #pragma unroll
  for (int i=0;i<16;i++){
    int e = tid + i*256;
    int nl = e >> 6, kl = e & 63;
    out[(long)z*sO + (long)(n0+nl)*Kpad + k0 + kl] = __float2bfloat16(lds[kl][nl]);
  }
}

// ---------------- weight transpose+convert with hi/lo split
__global__ __launch_bounds__(256) void convT2_kernel(
    const float* __restrict__ W, int N, int K,
    __hip_bfloat16* __restrict__ outh, __hip_bfloat16* __restrict__ outl,
    int Npad, int Kpad, int split, int splitPad)
{
  int n0 = blockIdx.x*64, k0 = blockIdx.y*64;
  int tid = threadIdx.x;
  __shared__ float lds[64][65];
  #pragma unroll
  for (int i=0;i<16;i++){
    int e = tid + i*256;
    int kl = e >> 6, c = e & 63;
    int np = n0 + c;
    int ns;
    if (split){
      if (np < split) ns = np;
      else if (np >= splitPad && np < splitPad + (N - split)) ns = np - (splitPad - split);
      else ns = -1;
    } else ns = (np < N) ? np : -1;
    int k = k0 + kl;
    float v = (ns >= 0 && k < K) ? W[(long)k*N + ns] : 0.f;
    lds[kl][c] = v;
  }
  __syncthreads();
  #pragma unroll
  for (int i=0;i<16;i++){
    int e = tid + i*256;
    int nl = e >> 6, kl = e & 63;
    float v = lds[kl][nl];
    __hip_bfloat16 h, l; split2(v, h, l);
    long o = (long)(n0+nl)*Kpad + k0 + kl;
    outh[o] = h; outl[o] = l;
  }
}

// ---------------- bias pack for z-batched QKV
__global__ void pack_bias_kernel(const float* bq, const float* bk, const float* bv, float* out){
  int i = blockIdx.x*256 + threadIdx.x;
  if (i < 256) out[i] = bq[i];
  else if (i < 512) out[i] = bk[i-256];
  else if (i < 768) out[i] = bv[i-512];
}

// ---------------- attention prep: Q (scaled) and K fp32 -> hi/lo bf16
__global__ __launch_bounds__(256) void qksplit_kernel(
    const float* __restrict__ QP,
    __hip_bfloat16* __restrict__ qsh, __hip_bfloat16* __restrict__ qsl,
    __hip_bfloat16* __restrict__ ksh, __hip_bfloat16* __restrict__ ksl)
{
  int idx = blockIdx.x*256 + threadIdx.x;   // 1048576
  float qv = QP[idx] * 0.17677669529663687f;
  __hip_bfloat16 h, l;
  split2(qv, h, l); qsh[idx] = h; qsl[idx] = l;
  float kv = QP[1048576 + idx];
  split2(kv, h, l); ksh[idx] = h; ksl[idx] = l;
}

// ---------------- attention prep: V fp32 [s][256] -> V^T hi/lo [bh][32 d][1024 s]
__global__ __launch_bounds__(256) void vtrans_kernel(
    const float* __restrict__ VP,
    __hip_bfloat16* __restrict__ vth, __hip_bfloat16* __restrict__ vtl)
{
  int bh = blockIdx.y, bb = bh >> 3, h = bh & 7;
  int s0 = blockIdx.x*64;
  int tid = threadIdx.x;
  __shared__ float t[64][33];
  #pragma unroll
  for (int p=0;p<8;p++){
    int sl = (tid>>5) + p*8;
    int d = tid & 31;
    t[sl][d] = VP[((bb<<10)+s0+sl)*256 + h*32 + d];
  }
  __syncthreads();
  #pragma unroll
  for (int p=0;p<8;p++){
    int dl = (tid>>6) + p*4;
    int s = tid & 63;
    float v = t[s][dl];
    __hip_bfloat16 hh, ll; split2(v, hh, ll);
    vth[(bh*32+dl)*1024 + s0 + s] = hh;
    vtl[(bh*32+dl)*1024 + s0 + s] = ll;
  }
}

// ---------------- MFMA flash attention (split-bf16, online softmax)
#define KSP 40
__global__ __launch_bounds__(256) void attn_mfma_kernel(
    const __hip_bfloat16* __restrict__ qsh_, const __hip_bfloat16* __restrict__ qsl_,
    const __hip_bfloat16* __restrict__ ksh_, const __hip_bfloat16* __restrict__ ksl_,
    const __hip_bfloat16* __restrict__ vth_, const __hip_bfloat16* __restrict__ vtl_,
    __hip_bfloat16* __restrict__ aoh, __hip_bfloat16* __restrict__ aol)
{
  const short* qsh = (const short*)qsh_; const short* qsl = (const short*)qsl_;
  const short* ksh = (const short*)ksh_; const short* ksl = (const short*)ksl_;
  const short* vth = (const short*)vth_; const short* vtl = (const short*)vtl_;
  int bh = blockIdx.y, bb = bh >> 3, h = bh & 7;
  int tid = threadIdx.x, lane = tid & 63, wave = tid >> 6;
  int ml = lane & 15, quad = lane >> 4;
  int q0 = blockIdx.x*64 + wave*16;

  __shared__ short KhS[32*KSP], KlS[32*KSP], VhS[32*KSP], VlS[32*KSP];
  __shared__ short PhS[4][16*KSP], PlS[4][16*KSP];
  short* Phw = PhS[wave]; short* Plw = PlS[wave];

  int qrow = (bb<<10) + q0 + ml;
  short8 qfh = *(const short8*)&qsh[qrow*256 + h*32 + quad*8];
  short8 qfl = *(const short8*)&qsl[qrow*256 + h*32 + quad*8];

  f32x4 O0 = {0.f,0.f,0.f,0.f}, O1 = {0.f,0.f,0.f,0.f};
  float m_[4], l_[4];
  #pragma unroll
  for (int r=0;r<4;r++){ m_[r] = -INFINITY; l_[r] = 0.f; }

  int sr = tid >> 3, sc = (tid & 7)*4;
  for (int k0 = 0; k0 < 1024; k0 += 32){
    int krow = (bb<<10) + k0 + sr;
    short4v kvh = *(const short4v*)&ksh[krow*256 + h*32 + sc];
    short4v kvl = *(const short4v*)&ksl[krow*256 + h*32 + sc];
    short4v vvh = *(const short4v*)&vth[(bh*32+sr)*1024 + k0 + sc];
    short4v vvl = *(const short4v*)&vtl[(bh*32+sr)*1024 + k0 + sc];
    __syncthreads();
    *(short4v*)&KhS[sr*KSP + sc] = kvh;
    *(short4v*)&KlS[sr*KSP + sc] = kvl;
    *(short4v*)&VhS[sr*KSP + sc] = vvh;
    *(short4v*)&VlS[sr*KSP + sc] = vvl;
    __syncthreads();
    short8 kb0h = *(const short8*)&KhS[ml*KSP + quad*8];
    short8 kb0l = *(const short8*)&KlS[ml*KSP + quad*8];
    short8 kb1h = *(const short8*)&KhS[(16+ml)*KSP + quad*8];
    short8 kb1l = *(const short8*)&KlS[(16+ml)*KSP + quad*8];
    f32x4 S0 = {0.f,0.f,0.f,0.f}, S1 = {0.f,0.f,0.f,0.f};
    S0 = __builtin_amdgcn_mfma_f32_16x16x32_bf16(qfl, kb0h, S0, 0,0,0);
    S0 = __builtin_amdgcn_mfma_f32_16x16x32_bf16(qfh, kb0l, S0, 0,0,0);
    S0 = __builtin_amdgcn_mfma_f32_16x16x32_bf16(qfh, kb0h, S0, 0,0,0);
    S1 = __builtin_amdgcn_mfma_f32_16x16x32_bf16(qfl, kb1h, S1, 0,0,0);
    S1 = __builtin_amdgcn_mfma_f32_16x16x32_bf16(qfh, kb1l, S1, 0,0,0);
    S1 = __builtin_amdgcn_mfma_f32_16x16x32_bf16(qfh, kb1h, S1, 0,0,0);
    #pragma unroll
    for (int r=0;r<4;r++){
      float tm = fmaxf(S0[r], S1[r]);
      #pragma unroll
      for (int o=1;o<16;o<<=1) tm = fmaxf(tm, __shfl_xor(tm, o, 64));
      float nm = fmaxf(m_[r], tm);
      float alpha = expf(m_[r] - nm);
      float p0 = expf(S0[r] - nm);
      float p1 = expf(S1[r] - nm);
      float ps = p0 + p1;
      #pragma unroll
      for (int o=1;o<16;o<<=1) ps += __shfl_xor(ps, o, 64);
      l_[r] = l_[r]*alpha + ps;
      m_[r] = nm;
      O0[r] *= alpha; O1[r] *= alpha;
      short sh, sl2;
      split2s(p0, sh, sl2);
      Phw[(quad*4+r)*KSP + ml] = sh;  Plw[(quad*4+r)*KSP + ml] = sl2;
      split2s(p1, sh, sl2);
      Phw[(quad*4+r)*KSP + 16 + ml] = sh;  Plw[(quad*4+r)*KSP + 16 + ml] = sl2;
    }
    short8 pAh = *(const short8*)&Phw[ml*KSP + quad*8];
    short8 pAl = *(const short8*)&Plw[ml*KSP + quad*8];
    short8 vb0h = *(const short8*)&VhS[ml*KSP + quad*8];
    short8 vb0l = *(const short8*)&VlS[ml*KSP + quad*8];
    short8 vb1h = *(const short8*)&VhS[(16+ml)*KSP + quad*8];
    short8 vb1l = *(const short8*)&VlS[(16+ml)*KSP + quad*8];
    O0 = __builtin_amdgcn_mfma_f32_16x16x32_bf16(pAl, vb0h, O0, 0,0,0);
    O0 = __builtin_amdgcn_mfma_f32_16x16x32_bf16(pAh, vb0l, O0, 0,0,0);
    O0 = __builtin_amdgcn_mfma_f32_16x16x32_bf16(pAh, vb0h, O0, 0,0,0);
    O1 = __builtin_amdgcn_mfma_f32_16x16x32_bf16(pAl, vb1h, O1, 0,0,0);
    O1 = __builtin_amdgcn_mfma_f32_16x16x32_bf16(pAh, vb1l, O1, 0,0,0);
    O1 = __builtin_amdgcn_mfma_f32_16x16x32_bf16(pAh, vb1h, O1, 0,0,0);
  }
  #pragma unroll
  for (int r=0;r<4;r++){
    float inv = 1.f / l_[r];
    int row = (bb<<10) + q0 + quad*4 + r;
    __hip_bfloat16 hh, ll;
    split2(O0[r]*inv, hh, ll);
    aoh[row*256 + h*32 + ml] = hh;       aol[row*256 + h*32 + ml] = ll;
    split2(O1[r]*inv, hh, ll);
    aoh[row*256 + h*32 + 16 + ml] = hh;  aol[row*256 + h*32 + 16 + ml] = ll;
  }
}

// ---------------- concat queries into x[:, 256:512]
__global__ __launch_bounds__(256) void concat_kernel(
    const float* __restrict__ queries, float* __restrict__ x)
{
  int idx = blockIdx.x*256 + threadIdx.x;
  int d = idx & 255; int r = idx >> 8;
  x[(r<<9) + 256 + d] = queries[idx];
}

// ---------------- rmsnorm fp32 out
__global__ __launch_bounds__(256) void rmsnorm_kernel(
    const float* __restrict__ x, const float* __restrict__ g, float* __restrict__ y)
{
  int r = blockIdx.x; int tid = threadIdx.x;
  float v0 = x[(r<<9) + tid];
  float v1 = x[(r<<9) + 256 + tid];
  float ss = v0*v0 + v1*v1;
  #pragma unroll
  for (int off=32; off>0; off>>=1) ss += __shfl_down(ss, off, 64);
  __shared__ float wsum[4];
  if ((tid & 63) == 0) wsum[tid>>6] = ss;
  __syncthreads();
  float tot = wsum[0]+wsum[1]+wsum[2]+wsum[3];
  float scale = 22.62741699796952f / fmaxf(sqrtf(tot), 1e-12f);
  y[(r<<9) + tid]       = v0*scale*g[tid];
  y[(r<<9) + 256 + tid] = v1*scale*g[256+tid];
}

// ---------------- rmsnorm hi/lo out
__global__ __launch_bounds__(256) void rmsnorm_split_kernel(
    const float* __restrict__ x, const float* __restrict__ g,
    __hip_bfloat16* __restrict__ yh, __hip_bfloat16* __restrict__ yl)
{
  int r = blockIdx.x; int tid = threadIdx.x;
  float v0 = x[(r<<9) + tid];
  float v1 = x[(r<<9) + 256 + tid];
  float ss = v0*v0 + v1*v1;
  #pragma unroll
  for (int off=32; off>0; off>>=1) ss += __shfl_down(ss, off, 64);
  __shared__ float wsum[4];
  if ((tid & 63) == 0) wsum[tid>>6] = ss;
  __syncthreads();
  float tot = wsum[0]+wsum[1]+wsum[2]+wsum[3];
  float scale = 22.62741699796952f / fmaxf(sqrtf(tot), 1e-12f);
  float a = v0*scale*g[tid];
  float b = v1*scale*g[256+tid];
  __hip_bfloat16 h, l;
  split2(a, h, l); yh[(r<<9)+tid] = h;     yl[(r<<9)+tid] = l;
  split2(b, h, l); yh[(r<<9)+256+tid] = h; yl[(r<<9)+256+tid] = l;
}

// ---------------- rmsnorm bf16 out (ffa path)
__global__ __launch_bounds__(256) void rmsnorm_bf_kernel(
    const float* __restrict__ x, const float* __restrict__ g, __hip_bfloat16* __restrict__ y)
{
  int r = blockIdx.x; int tid = threadIdx.x;
  float v0 = x[(r<<9) + tid];
  float v1 = x[(r<<9) + 256 + tid];
  float ss = v0*v0 + v1*v1;
  #pragma unroll
  for (int off=32; off>0; off>>=1) ss += __shfl_down(ss, off, 64);
  __shared__ float wsum[4];
  if ((tid & 63) == 0) wsum[tid>>6] = ss;
  __syncthreads();
  float tot = wsum[0]+wsum[1]+wsum[2]+wsum[3];
  float scale = 22.62741699796952f / fmaxf(sqrtf(tot), 1e-12f);
  y[(r<<9) + tid]       = __float2bfloat16(v0*scale*g[tid]);
  y[(r<<9) + 256 + tid] = __float2bfloat16(v1*scale*g[256+tid]);
}

// ---------------- geglu glu: H fp32 padded [4096][2816] -> T hi/lo [4096][1408]
__global__ __launch_bounds__(256) void glu_split_kernel(
    const float* __restrict__ h, const float* __restrict__ mult,
    __hip_bfloat16* __restrict__ th, __hip_bfloat16* __restrict__ tl)
{
  int idx = blockIdx.x*256 + threadIdx.x;
  int r = idx / 1408; int j = idx - r*1408;
  float v = 0.f;
  if (j < 1365){
    float a  = h[(long)r*2816 + j];
    float gt = h[(long)r*2816 + 1408 + j];
    v = gelu_f(gt) * a * mult[j];
  }
  __hip_bfloat16 hh, ll; split2(v, hh, ll);
  th[idx] = hh; tl[idx] = ll;
}

// ---------------- geglu glu bf16 (ffa path)
__global__ __launch_bounds__(256) void glu_bf_kernel(
    const __hip_bfloat16* __restrict__ h, const float* __restrict__ mult,
    __hip_bfloat16* __restrict__ t)
{
  int idx = blockIdx.x*256 + threadIdx.x;
  int r = idx / 1408; int j = idx - r*1408;
  float v = 0.f;
  if (j < 1365){
    float a  = __bfloat162float(h[(long)r*2816 + j]);
    float gt = __bfloat162float(h[(long)r*2816 + 1408 + j]);
    v = gelu_f(gt) * a * mult[j];
  }
  t[idx] = __float2bfloat16(v);
}

// ---------------- split fp32 -> hi/lo
__global__ __launch_bounds__(256) void split32_kernel(
    const float* __restrict__ x, __hip_bfloat16* __restrict__ h, __hip_bfloat16* __restrict__ l)
{
  int idx = blockIdx.x*256 + threadIdx.x;
  float v = x[idx];
  __hip_bfloat16 hh, ll; split2(v, hh, ll);
  h[idx] = hh; l[idx] = ll;
}

// ---------------- MoE init
__global__ void moe_init_kernel(float* sum_raw, float* z_sum)
{
  int i = threadIdx.x;
  if (i < 64) sum_raw[i] = 0.f;
  if (i == 0) *z_sum = 0.f;
}

// ---------------- gating
__global__ __launch_bounds__(256) void gating_kernel(
    const float* __restrict__ xn, const float* __restrict__ gate_w,
    int* __restrict__ idx1, int* __restrict__ idx2, int* __restrict__ route,
    float* __restrict__ gg1, float* __restrict__ gg2,
    float* __restrict__ sum_raw, float* __restrict__ z_sum)
{
  int t = blockIdx.x; int tid = threadIdx.x;
  __shared__ float xrow[512];
  xrow[tid]     = xn[(t<<9)+tid];
  xrow[256+tid] = xn[(t<<9)+256+tid];
  __syncthreads();
  int e = tid >> 4, l16 = tid & 15;
  float p = 0.f;
  for (int d=l16; d<512; d+=16) p += xrow[d]*gate_w[(e<<9)+d];
  __shared__ float part[16][17];
  part[e][l16] = p;
  __syncthreads();
  __shared__ float raw[16];
  if (tid < 16){
    float s = 0.f;
    #pragma unroll
    for (int i=0;i<16;i++) s += part[tid][i];
    raw[tid] = s;
  }
  __syncthreads();
  if (tid == 0){
    float mx = -1e30f;
    #pragma unroll
    for (int i=0;i<16;i++) mx = fmaxf(mx, raw[i]);
    float r[16]; float sum = 0.f;
    #pragma unroll
    for (int i=0;i<16;i++){ r[i] = expf(raw[i]-mx); sum += r[i]; }
    float lse = mx + logf(sum);
    atomicAdd(z_sum, lse*lse);
    float inv = 1.f/sum;
    #pragma unroll
    for (int i=0;i<16;i++){ r[i] *= inv; raw[i] = r[i]; }
    int i1 = -1; float b1 = -1.f;
    #pragma unroll
    for (int i=0;i<16;i++) if (r[i] > b1){ b1 = r[i]; i1 = i; }
    int i2 = -1; float b2 = -1.f;
    #pragma unroll
    for (int i=0;i<16;i++) if (i != i1 && r[i] > b2){ b2 = r[i]; i2 = i; }
    float s2 = fmaxf(b1 + b2, 1e-9f);
    float g1n = b1/s2, g2n = b2/s2;
    idx1[t] = i1; idx2[t] = i2;
    route[t] = (g2n > 0.2f) ? 1 : 0;
    gg1[t] = g1n; gg2[t] = g2n;
  }
  __syncthreads();
  int bb = t >> 10;
  if (tid < 16) atomicAdd(&sum_raw[(bb<<4)+tid], raw[tid]);
}

// ---------------- capacity assignment: parallel segmented prefix scan
__global__ __launch_bounds__(256) void scan_kernel(
    const int* __restrict__ idx1, const int* __restrict__ idx2, const int* __restrict__ route,
    int* __restrict__ ts1, int* __restrict__ ts2, int* __restrict__ slot_token,
    int* __restrict__ count1)
{
  int bb = blockIdx.x >> 4;
  int e  = blockIdx.x & 15;
  int tid = threadIdx.x;
  int tbase = (bb<<10) + tid*4;
  int4 i1 = *(const int4*)&idx1[tbase];
  int4 i2 = *(const int4*)&idx2[tbase];
  int4 rt = *(const int4*)&route[tbase];
  int m1[4] = { i1.x==e, i1.y==e, i1.z==e, i1.w==e };
  int m2[4] = { i2.x==e, i2.y==e, i2.z==e, i2.w==e };
  int r4[4] = { rt.x, rt.y, rt.z, rt.w };
  int c1 = m1[0]+m1[1]+m1[2]+m1[3];
  int c2 = (m2[0]&&r4[0]) + (m2[1]&&r4[1]) + (m2[2]&&r4[2]) + (m2[3]&&r4[3]);
  __shared__ int s1[256], s2v[256];
  s1[tid] = c1; s2v[tid] = c2;
  __syncthreads();
  for (int off=1; off<256; off<<=1){
    int v1 = (tid>=off) ? s1[tid-off] : 0;
    int v2 = (tid>=off) ? s2v[tid-off] : 0;
    __syncthreads();
    s1[tid] += v1; s2v[tid] += v2;
    __syncthreads();
  }
  int tot1 = s1[255], tot2 = s2v[255];
  int p1 = s1[tid] - c1;
  int p2 = s2v[tid] - c2;
  if (tid == 0) count1[(bb<<4)+e] = tot1;
  int base = ((e<<2)+bb)*CAPN;
  #pragma unroll
  for (int i=0;i<4;i++){
    int t = tbase + i;
    if (m1[i]){
      if (p1 < CAPN){ ts1[t] = base+p1; slot_token[base+p1] = t; }
      else ts1[t] = -1;
      p1++;
    }
    if (m2[i]){
      if (r4[i]){
        int pos = tot1 + p2;
        if (pos < CAPN){ ts2[t] = base+pos; slot_token[base+pos] = t; }
        else ts2[t] = -1;
        p2++;
      } else ts2[t] = -1;
    }
  }
  int filled = min(CAPN, tot1 + tot2);
  if (tid < CAPN && tid >= filled) slot_token[base+tid] = -1;
}

// ---------------- gather + layernorm -> xin bf16
__global__ __launch_bounds__(256) void gather_ln_kernel(
    const float* __restrict__ xn, const int* __restrict__ slot_token,
    const float* __restrict__ ln_g, const float* __restrict__ ln_b,
    __hip_bfloat16* __restrict__ xin)
{
  int s = blockIdx.x; int tid = threadIdx.x;
  int t = slot_token[s];
  int e = s >> 9;
  if (t < 0){
    xin[(s<<9)+tid] = __float2bfloat16(0.f);
    xin[(s<<9)+256+tid] = __float2bfloat16(0.f);
    return;
  }
  float v0 = xn[(t<<9)+tid];
  float v1 = xn[(t<<9)+256+tid];
  float sm = v0+v1, sq = v0*v0+v1*v1;
  #pragma unroll
  for (int off=32; off>0; off>>=1){
    sm += __shfl_down(sm, off, 64);
    sq += __shfl_down(sq, off, 64);
  }
  __shared__ float s1[4], s2buf[4];
  if ((tid & 63) == 0){ s1[tid>>6] = sm; s2buf[tid>>6] = sq; }
  __syncthreads();
  float tsm = s1[0]+s1[1]+s1[2]+s1[3];
  float tsq = s2buf[0]+s2buf[1]+s2buf[2]+s2buf[3];
  float mean = tsm * (1.f/512.f);
  float var = tsq * (1.f/512.f) - mean*mean;
  float rstd = rsqrtf(var + 1e-5f);
  xin[(s<<9)+tid]     = __float2bfloat16((v0-mean)*rstd*ln_g[(e<<9)+tid]     + ln_b[(e<<9)+tid]);
  xin[(s<<9)+256+tid] = __float2bfloat16((v1-mean)*rstd*ln_g[(e<<9)+256+tid] + ln_b[(e<<9)+256+tid]);
}

// ---------------- combine (in-place)
__global__ __launch_bounds__(256) void combine_kernel(
    float* __restrict__ x, const float* __restrict__ h2,
    const int* __restrict__ ts1, const int* __restrict__ ts2,
    const float* __restrict__ gg1, const float* __restrict__ gg2)
{
  int idx = blockIdx.x*256 + threadIdx.x;
  int t = idx >> 9; int d = idx & 511;
  float v = x[idx];
  int s1 = ts1[t]; if (s1 >= 0) v += gg1[t]*h2[(s1<<9)+d];
  int s2 = ts2[t]; if (s2 >= 0) v += gg2[t]*h2[(s2<<9)+d];
  x[idx] = v;
}

// ---------------- aux losses
__global__ void aux_kernel(
    const float* __restrict__ sum_raw, const int* __restrict__ count1,
    const float* __restrict__ z_sum, float* __restrict__ out)
{
  int tid = threadIdx.x;
  float v = (sum_raw[tid] * (1.f/1024.f)) * ((float)count1[tid] * (1.f/1024.f));
  #pragma unroll
  for (int off=32; off>0; off>>=1) v += __shfl_down(v, off, 64);
  if (tid == 0){
    float bal = v * (1.f/64.f) * 256.f * 0.01f;
    float zl = (*z_sum) * (1.f/4096.f) * 0.001f;
    out[0] = bal + zl;
    out[1] = bal;
    out[2] = zl;
  }
}

extern "C" void kernel_launch(void* const* d_in, const int* in_sizes, int n_in,
                              void* d_out, int out_size, void* d_ws, size_t ws_size,
                              hipStream_t stream)
{
  const float* K_in   = (const float*)d_in[0];
  const float* V_in   = (const float*)d_in[1];
  const float* Q_in   = (const float*)d_in[2];
  const float* w_topo = (const float*)d_in[3];
  const float* b_topo = (const float*)d_in[4];
  const float* w_val  = (const float*)d_in[5];
  const float* b_val  = (const float*)d_in[6];
  const float* wq     = (const float*)d_in[7];
  const float* bq     = (const float*)d_in[8];
  const float* wk     = (const float*)d_in[9];
  const float* bk     = (const float*)d_in[10];
  const float* wv     = (const float*)d_in[11];
  const float* bv     = (const float*)d_in[12];
  const float* wo     = (const float*)d_in[13];
  const float* bo     = (const float*)d_in[14];
  const float* ffb_g  = (const float*)d_in[15];
  const float* ffb_w1 = (const float*)d_in[16];
  const float* ffb_b1 = (const float*)d_in[17];
  const float* ffb_mult=(const float*)d_in[18];
  const float* ffb_w2 = (const float*)d_in[19];
  const float* ffb_b2 = (const float*)d_in[20];
  const float* prenorm_g=(const float*)d_in[21];
  const float* gate_w = (const float*)d_in[22];
  const float* exp_ln_g=(const float*)d_in[23];
  const float* exp_ln_b=(const float*)d_in[24];
  const float* exp_w1 = (const float*)d_in[25];
  const float* exp_b1 = (const float*)d_in[26];
  const float* exp_w2 = (const float*)d_in[27];
  const float* exp_b2 = (const float*)d_in[28];
  const float* ffa_g  = (const float*)d_in[29];
  const float* ffa_w1 = (const float*)d_in[30];
  const float* ffa_b1 = (const float*)d_in[31];
  const float* ffa_mult=(const float*)d_in[32];
  const float* ffa_w2 = (const float*)d_in[33];
  const float* ffa_b2 = (const float*)d_in[34];
  const float* w_out  = (const float*)d_in[35];
  const float* b_out  = (const float*)d_in[36];
  float* dout = (float*)d_out;

  float* wsf = (float*)d_ws;
  int*   wsi = (int*)d_ws;

  // ---- layout (float offsets) ----
  const size_t A0 = 0;
  const size_t B0 = 11534336;
  const size_t OXA = 17301504;
  const size_t OXB = 19398656;
  const size_t OWP = 21495808;
  const size_t OMI = 21889024;

  __hip_bfloat16* qhi = (__hip_bfloat16*)(wsf + A0);
  __hip_bfloat16* khi = (__hip_bfloat16*)(wsf + A0 + 524288);
  __hip_bfloat16* vhi = (__hip_bfloat16*)(wsf + A0 + 1048576);
  __hip_bfloat16* qlo = (__hip_bfloat16*)(wsf + A0 + 1572864);
  __hip_bfloat16* klo = (__hip_bfloat16*)(wsf + A0 + 2097152);
  __hip_bfloat16* vlo = (__hip_bfloat16*)(wsf + A0 + 2621440);
  float* QP = wsf + A0 + 3145728;
  __hip_bfloat16* aohi = (__hip_bfloat16*)(wsf + A0 + 6291456);
  __hip_bfloat16* aolo = (__hip_bfloat16*)(wsf + A0 + 6815744);
  __hip_bfloat16* qsh = (__hip_bfloat16*)(wsf + A0);
  __hip_bfloat16* qsl = (__hip_bfloat16*)(wsf + A0 + 524288);
  __hip_bfloat16* ksh = (__hip_bfloat16*)(wsf + A0 + 1048576);
  __hip_bfloat16* ksl = (__hip_bfloat16*)(wsf + A0 + 1572864);
  __hip_bfloat16* vth = (__hip_bfloat16*)(wsf + A0 + 2097152);
  __hip_bfloat16* vtl = (__hip_bfloat16*)(wsf + A0 + 2621440);
  float* QF = wsf + B0 + 262144;
  float* Hb = wsf + A0;
  __hip_bfloat16* yh   = (__hip_bfloat16*)(wsf + B0);
  __hip_bfloat16* yl   = (__hip_bfloat16*)(wsf + B0 + 1048576);
  __hip_bfloat16* fw1h = (__hip_bfloat16*)(wsf + B0 + 2097152);
  __hip_bfloat16* fw1l = fw1h + 1441792;
  __hip_bfloat16* th   = (__hip_bfloat16*)(wsf + B0);
  __hip_bfloat16* tl   = (__hip_bfloat16*)(wsf + B0 + 2883584);
  __hip_bfloat16* fw2h = (__hip_bfloat16*)(wsf + A0);
  __hip_bfloat16* fw2l = fw2h + 720896;
  float* Pffb = wsf + A0 + 1048576;          // 4 x 2097152 = 8388608, ends 9437184
  __hip_bfloat16* wte   = (__hip_bfloat16*)(wsf + A0);
  __hip_bfloat16* xin_bf= (__hip_bfloat16*)(wsf + A0 + 5767168);
  __hip_bfloat16* h1_bf = (__hip_bfloat16*)(wsf + A0 + 7864320);
  float* H2 = wsf + 13631488;
  float* YM = wsf + B0;
  __hip_bfloat16* y_bf = (__hip_bfloat16*)(wsf + A0);
  __hip_bfloat16* wf1  = (__hip_bfloat16*)(wsf + A0 + 1048576);
  __hip_bfloat16* h_bf = (__hip_bfloat16*)(wsf + A0 + 1769472);
  __hip_bfloat16* t_bf = (__hip_bfloat16*)(wsf + A0 + 7536640);
  __hip_bfloat16* wf2  = (__hip_bfloat16*)(wsf + A0 + 10420224);
  float* Pffa = wsf + B0;                    // 2 x 2097152 = 4194304 (B free in phase 7)
  __hip_bfloat16* xah = (__hip_bfloat16*)(wsf + A0);
  __hip_bfloat16* xal = (__hip_bfloat16*)(wsf + A0 + 1048576);
  float* Pout = wsf + A0 + 2097152;          // 4 x 1048576 = 4194304, ends 6291456
  __hip_bfloat16* wp = (__hip_bfloat16*)(wsf + OWP);
  __hip_bfloat16* wqh = wp;            __hip_bfloat16* wkh = wp + 65536;
  __hip_bfloat16* wvh = wp + 131072;   __hip_bfloat16* wql = wp + 196608;
  __hip_bfloat16* wkl = wp + 262144;   __hip_bfloat16* wvl = wp + 327680;
  __hip_bfloat16* woh = wp + 393216;   __hip_bfloat16* wol = wp + 458752;
  __hip_bfloat16* wouth = wp + 524288; __hip_bfloat16* woutl = wp + 655360;

  int* idx1 = wsi + OMI + 0;
  int* idx2 = wsi + OMI + 4096;
  int* route= wsi + OMI + 8192;
  int* ts1  = wsi + OMI + 12288;
  int* ts2  = wsi + OMI + 16384;
  int* slot_token = wsi + OMI + 20480;
  int* count1     = wsi + OMI + 28672;
  float* sum_raw  = wsf + OMI + 28736;
  float* z_sum    = wsf + OMI + 28800;
  float* gg1      = wsf + OMI + 28864;
  float* gg2      = wsf + OMI + 32960;
  float* bias_qkv = wsf + OMI + 37056;

  // ---- phase 0: static weight conversions ----
  convT2_kernel<<<dim3(4,4),  256, 0, stream>>>(wq, 256, 256, wqh, wql, 256, 256, 0, 0);
  convT2_kernel<<<dim3(4,4),  256, 0, stream>>>(wk, 256, 256, wkh, wkl, 256, 256, 0, 0);
  convT2_kernel<<<dim3(4,4),  256, 0, stream>>>(wv, 256, 256, wvh, wvl, 256, 256, 0, 0);
  convT2_kernel<<<dim3(4,4),  256, 0, stream>>>(wo, 256, 256, woh, wol, 256, 256, 0, 0);
  convT2_kernel<<<dim3(4,8),  256, 0, stream>>>(w_out, 256, 512, wouth, woutl, 256, 512, 0, 0);
  convT2_kernel<<<dim3(44,8), 256, 0, stream>>>(ffb_w1, 2730, 512, fw1h, fw1l, 2816, 512, 1365, 1408);
  pack_bias_kernel<<<3, 256, 0, stream>>>(bq, bk, bv, bias_qkv);

  // ---- phase 1: topo / values ----
  topo_kernel<<<8192, 256, 0, stream>>>(K_in, Q_in, w_topo, b_topo, khi, klo, qhi, qlo, QF);
  values_kernel<<<4096, 256, 0, stream>>>(V_in, w_val, b_val, vhi, vlo);

  // ---- phase 2: QKV projections ----
  sgemm_kernel<<<dim3(2,32,3), 256, 0, stream>>>(
      qhi, qlo, 256, 1048576, wqh, wql, 256, 65536,
      bias_qkv, 256, 0, 0, 256, nullptr, 0, QP, 256, 1048576, 256, 0,
      nullptr, 0, 1);

  // ---- phase 3: MFMA flash attention ----
  qksplit_kernel<<<4096, 256, 0, stream>>>(QP, qsh, qsl, ksh, ksl);
  vtrans_kernel<<<dim3(16,32), 256, 0, stream>>>(QP + 2097152, vth, vtl);
  attn_mfma_kernel<<<dim3(16,32), 256, 0, stream>>>(qsh, qsl, ksh, ksl, vth, vtl, aohi, aolo);

  // ---- phase 4: o-proj + concat ----
  sgemm_kernel<<<dim3(2,32,1), 256, 0, stream>>>(
      aohi, aolo, 256, 0, woh, wol, 256, 0,
      bo, 256, 0, 0, 0, nullptr, 0, wsf+OXA, 512, 0, 256, 0,
      nullptr, 0, 1);
  concat_kernel<<<4096, 256, 0, stream>>>(QF, wsf+OXA);

  // ---- phase 5: ffb geglu ----
  rmsnorm_split_kernel<<<4096, 256, 0, stream>>>(wsf+OXA, ffb_g, yh, yl);
  sgemm_kernel<<<dim3(22,32,1), 256, 0, stream>>>(
      yh, yl, 512, 0, fw1h, fw1l, 512, 0,
      ffb_b1, 2730, 1365, 1408, 0, nullptr, 0, Hb, 2816, 0, 512, 0,
      nullptr, 0, 1);
  glu_split_kernel<<<22528, 256, 0, stream>>>(Hb, ffb_mult, th, tl);
  convT2_kernel<<<dim3(8,22), 256, 0, stream>>>(ffb_w2, 512, 1365, fw2h, fw2l, 512, 1408, 0, 0);
  // ffb_w2 with split-K=4: partials, then reduce (+bias +residual XA -> XB)
  sgemm_kernel<<<dim3(4,32,4), 256, 0, stream>>>(
      th, tl, 1408, 0, fw2h, fw2l, 1408, 0,
      nullptr, 0, 0, 0, 0, nullptr, 0, nullptr, 512, 0, 1408, 0,
      Pffb, 2097152, 4);
  reduce_kernel<<<8192, 256, 0, stream>>>(
      Pffb, 2097152, 4, ffb_b2, wsf+OXA, wsf+OXB, 511, 9, 512, 0, 2097152);

  // ---- phase 6: MoE ----
  rmsnorm_kernel<<<4096, 256, 0, stream>>>(wsf+OXB, prenorm_g, YM);
  moe_init_kernel<<<1, 64, 0, stream>>>(sum_raw, z_sum);
  gating_kernel<<<4096, 256, 0, stream>>>(YM, gate_w, idx1, idx2, route, gg1, gg2, sum_raw, z_sum);
  scan_kernel<<<64, 256, 0, stream>>>(idx1, idx2, route, ts1, ts2, slot_token, count1);
  gather_ln_kernel<<<8192, 256, 0, stream>>>(YM, slot_token, exp_ln_g, exp_ln_b, xin_bf);
  convT_kernel<<<dim3(22, 8, 16), 256, 0, stream>>>(exp_w1, 1365, 512, (long)512*1365,
                                                    wte, 1408, 512, (long)1408*512, 0, 0);
  bgemm_kernel<<<dim3(11,4,16), 256, 0, stream>>>(
      xin_bf, 512, (long)512*512, wte, 512, (long)1408*512,
      exp_b1, 1365, 0, 0, 1365, nullptr, 0, 0,
      h1_bf, 1408, (long)512*1408, 1, 512, 2,
      nullptr, 0, 1);
  convT_kernel<<<dim3(8, 22, 16), 256, 0, stream>>>(exp_w2, 512, 1365, (long)1365*512,
                                                    wte, 512, 1408, (long)512*1408, 0, 0);
  bgemm_kernel<<<dim3(4,4,16), 256, 0, stream>>>(
      h1_bf, 1408, (long)512*1408, wte, 1408, (long)512*1408,
      exp_b2, 512, 0, 0, 512, nullptr, 0, 0,
      H2, 512, (long)512*512, 0, 1408, 0,
      nullptr, 0, 1);
  combine_kernel<<<8192, 256, 0, stream>>>(wsf+OXB, H2, ts1, ts2, gg1, gg2);
  aux_kernel<<<1, 64, 0, stream>>>(sum_raw, count1, z_sum, dout + 4096*256);

  // ---- phase 7: ffa geglu ----
  rmsnorm_bf_kernel<<<4096, 256, 0, stream>>>(wsf+OXB, ffa_g, y_bf);
  convT_kernel<<<dim3(44, 8, 1), 256, 0, stream>>>(ffa_w1, 2730, 512, 0,
                                                   wf1, 2816, 512, 0, 1365, 1408);
  bgemm_kernel<<<dim3(22,32,1), 256, 0, stream>>>(
      y_bf, 512, 0, wf1, 512, 0,
      ffa_b1, 2730, 1365, 1408, 0, nullptr, 0, 0,
      h_bf, 2816, 0, 1, 512, 0,
      nullptr, 0, 1);
  glu_bf_kernel<<<22528, 256, 0, stream>>>(h_bf, ffa_mult, t_bf);
  convT_kernel<<<dim3(8, 22, 1), 256, 0, stream>>>(ffa_w2, 512, 1365, 0,
                                                   wf2, 512, 1408, 0, 0, 0);
  // ffa_w2 with split-K=2: partials in region B, reduce (+bias +residual XB -> XA)
  bgemm_kernel<<<dim3(4,32,2), 256, 0, stream>>>(
      t_bf, 1408, 0, wf2, 1408, 0,
      nullptr, 0, 0, 0, 0, nullptr, 0, 0,
      nullptr, 512, 0, 0, 1408, 0,
      Pffa, 2097152, 2);
  reduce_kernel<<<8192, 256, 0, stream>>>(
      Pffa, 2097152, 2, ffa_b2, wsf+OXB, wsf+OXA, 511, 9, 512, 0, 2097152);

  // ---- phase 8: out = gelu(XA @ w_out + b_out), split-K=4 ----
  split32_kernel<<<8192, 256, 0, stream>>>(wsf+OXA, xah, xal);
  sgemm_kernel<<<dim3(2,32,4), 256, 0, stream>>>(
      xah, xal, 512, 0, wouth, woutl, 512, 0,
      nullptr, 0, 0, 0, 0, nullptr, 0, nullptr, 256, 0, 512, 0,
      Pout, 1048576, 4);
  reduce_kernel<<<4096, 256, 0, stream>>>(
      Pout, 1048576, 4, b_out, nullptr, dout, 255, 8, 256, 1, 1048576);
}

// Round 9
// 839.042 us; speedup vs baseline: 3.6148x; 1.0230x over previous
//
#include <hip/hip_runtime.h>
#include <hip/hip_bf16.h>
#include <math.h>

// B=4 S=1024 DM=256 H=8 HD=32 CIN=23 E=16 D2=512 HE=1365 2HE=2730 CAP=128
#define CAPN 128

typedef short short8 __attribute__((ext_vector_type(8)));
typedef short short4v __attribute__((ext_vector_type(4)));
typedef float f32x4 __attribute__((ext_vector_type(4)));

__device__ __forceinline__ float gelu_f(float x){
  return 0.5f*x*(1.0f+erff(x*0.7071067811865476f));
}
__device__ __forceinline__ void split2(float v, __hip_bfloat16& h, __hip_bfloat16& l){
  h = __float2bfloat16(v);
  l = __float2bfloat16(v - __bfloat162float(h));
}
__device__ __forceinline__ void split2s(float v, short& h, short& l){
  __hip_bfloat16 hh = __float2bfloat16(v);
  __hip_bfloat16 ll = __float2bfloat16(v - __bfloat162float(hh));
  h = *(short*)&hh; l = *(short*)&ll;
}

// ---------------- topo
__global__ __launch_bounds__(256) void topo_kernel(
    const float* __restrict__ K, const float* __restrict__ Q,
    const float* __restrict__ w, const float* __restrict__ b,
    __hip_bfloat16* __restrict__ khi, __hip_bfloat16* __restrict__ klo,
    __hip_bfloat16* __restrict__ qhi, __hip_bfloat16* __restrict__ qlo,
    float* __restrict__ qf32)
{
  int idx = blockIdx.x*256 + threadIdx.x;   // 2M
  int d = idx & 255;
  int r = idx >> 8;
  int bb = r >> 11;
  int n  = r & 2047;
  const float* src = (n < 1024) ? (K + ((bb<<10) + n)*3)
                                : (Q + ((bb<<10) + (n-1024))*3);
  float v = b[d] + src[0]*w[d] + src[1]*w[256+d] + src[2]*w[512+d];
  v = gelu_f(v);
  int off = (((bb<<10) + (n & 1023))<<8) + d;
  __hip_bfloat16 h, l; split2(v, h, l);
  if (n < 1024){ khi[off] = h; klo[off] = l; }
  else         { qhi[off] = h; qlo[off] = l; qf32[off] = v; }
}

// ---------------- values
__global__ __launch_bounds__(256) void values_kernel(
    const float* __restrict__ V, const float* __restrict__ w,
    const float* __restrict__ b,
    __hip_bfloat16* __restrict__ vhi, __hip_bfloat16* __restrict__ vlo)
{
  int idx = blockIdx.x*256 + threadIdx.x;
  int d = idx & 255; int r = idx >> 8;
  const float* src = V + r*23;
  float acc = b[d];
  #pragma unroll
  for (int c=0;c<23;c++) acc += src[c]*w[c*256+d];
  acc = gelu_f(acc);
  __hip_bfloat16 h, l; split2(acc, h, l);
  vhi[idx] = h; vlo[idx] = l;
}

// ---------------- split-bf16 "fp32" MFMA GEMM (pipelined, optional split-K)
#define SLP 40
__global__ __launch_bounds__(256) void sgemm_kernel(
    const __hip_bfloat16* __restrict__ Ah_, const __hip_bfloat16* __restrict__ Al_,
    int lda, long sA,
    const __hip_bfloat16* __restrict__ Wh_, const __hip_bfloat16* __restrict__ Wl_,
    int ldw, long sW,
    const float* __restrict__ bias, int nbias, int bsplit, int bsplitPad, long sB,
    const float* __restrict__ R, int ldr,
    float* __restrict__ C, int ldc, long sC,
    int K, int act,
    float* __restrict__ P, long pz, int splitK)
{
  int z = blockIdx.z / splitK;
  int kc = blockIdx.z - z*splitK;
  const short* Ah = (const short*)Ah_ + (long)z*sA;
  const short* Al = (const short*)Al_ + (long)z*sA;
  const short* Wh = (const short*)Wh_ + (long)z*sW;
  const short* Wl = (const short*)Wl_ + (long)z*sW;
  int bm = blockIdx.y*128, bn = blockIdx.x*128;
  int tid = threadIdx.x, lane = tid & 63, wave = tid >> 6;
  int wm = (wave & 1)*64, wn = (wave >> 1)*64;

  __shared__ short AsH[128*SLP], AsL[128*SLP], BsH[128*SLP], BsL[128*SLP];

  f32x4 acc[4][4];
  f32x4 zero4 = {0.f,0.f,0.f,0.f};
  #pragma unroll
  for (int i=0;i<4;i++)
    #pragma unroll
    for (int j=0;j<4;j++) acc[i][j] = zero4;

  int srow = tid >> 1, scol = (tid & 1)*16;
  int ml = lane & 15, q = lane >> 4;
  long abase = (long)(bm+srow)*lda + scol;
  long bbase = (long)(bn+srow)*ldw + scol;

  int Kc = K / splitK;
  int kbeg = kc * Kc, kend = kbeg + Kc;

  short8 ah0 = *(const short8*)&Ah[abase + kbeg];
  short8 ah1 = *(const short8*)&Ah[abase + kbeg + 8];
  short8 al0 = *(const short8*)&Al[abase + kbeg];
  short8 al1 = *(const short8*)&Al[abase + kbeg + 8];
  short8 bh0 = *(const short8*)&Wh[bbase + kbeg];
  short8 bh1 = *(const short8*)&Wh[bbase + kbeg + 8];
  short8 bl0 = *(const short8*)&Wl[bbase + kbeg];
  short8 bl1 = *(const short8*)&Wl[bbase + kbeg + 8];

  for (int k0 = kbeg; k0 < kend; k0 += 32){
    __syncthreads();
    *(short8*)&AsH[srow*SLP + scol]     = ah0;
    *(short8*)&AsH[srow*SLP + scol + 8] = ah1;
    *(short8*)&AsL[srow*SLP + scol]     = al0;
    *(short8*)&AsL[srow*SLP + scol + 8] = al1;
    *(short8*)&BsH[srow*SLP + scol]     = bh0;
    *(short8*)&BsH[srow*SLP + scol + 8] = bh1;
    *(short8*)&BsL[srow*SLP + scol]     = bl0;
    *(short8*)&BsL[srow*SLP + scol + 8] = bl1;
    __syncthreads();
    if (k0 + 32 < kend){
      long ab = abase + k0 + 32;
      long bb2 = bbase + k0 + 32;
      ah0 = *(const short8*)&Ah[ab];
      ah1 = *(const short8*)&Ah[ab + 8];
      al0 = *(const short8*)&Al[ab];
      al1 = *(const short8*)&Al[ab + 8];
      bh0 = *(const short8*)&Wh[bb2];
      bh1 = *(const short8*)&Wh[bb2 + 8];
      bl0 = *(const short8*)&Wl[bb2];
      bl1 = *(const short8*)&Wl[bb2 + 8];
    }
    short8 afh[4], afl[4], bfh[4], bfl[4];
    #pragma unroll
    for (int i=0;i<4;i++){
      afh[i] = *(const short8*)&AsH[(wm + 16*i + ml)*SLP + q*8];
      afl[i] = *(const short8*)&AsL[(wm + 16*i + ml)*SLP + q*8];
    }
    #pragma unroll
    for (int j=0;j<4;j++){
      bfh[j] = *(const short8*)&BsH[(wn + 16*j + ml)*SLP + q*8];
      bfl[j] = *(const short8*)&BsL[(wn + 16*j + ml)*SLP + q*8];
    }
    #pragma unroll
    for (int i=0;i<4;i++)
      #pragma unroll
      for (int j=0;j<4;j++){
        acc[i][j] = __builtin_amdgcn_mfma_f32_16x16x32_bf16(afh[i], bfh[j], acc[i][j], 0,0,0);
        acc[i][j] = __builtin_amdgcn_mfma_f32_16x16x32_bf16(afh[i], bfl[j], acc[i][j], 0,0,0);
        acc[i][j] = __builtin_amdgcn_mfma_f32_16x16x32_bf16(afl[i], bfh[j], acc[i][j], 0,0,0);
      }
  }

  if (P){   // raw partial store (split-K path)
    float* Pb = P + (long)blockIdx.z * pz;
    #pragma unroll
    for (int i=0;i<4;i++)
      #pragma unroll
      for (int r=0;r<4;r++){
        int gm = bm + wm + 16*i + q*4 + r;
        #pragma unroll
        for (int j=0;j<4;j++){
          int gn = bn + wn + 16*j + ml;
          Pb[(long)gm*ldc + gn] = acc[i][j][r];
        }
      }
    return;
  }

  const float* biasz = bias ? bias + (long)z*sB : nullptr;
  long coff = (long)z*sC;
  #pragma unroll
  for (int i=0;i<4;i++){
    #pragma unroll
    for (int r=0;r<4;r++){
      int gm = bm + wm + 16*i + q*4 + r;
      #pragma unroll
      for (int j=0;j<4;j++){
        int gn = bn + wn + 16*j + ml;
        float v = acc[i][j][r];
        if (biasz){
          int bi;
          if (bsplit){
            if (gn < bsplit) bi = gn;
            else if (gn >= bsplitPad && gn < bsplitPad + (nbias - bsplit)) bi = gn - (bsplitPad - bsplit);
            else bi = -1;
          } else bi = (gn < nbias) ? gn : -1;
          if (bi >= 0) v += biasz[bi];
        }
        if (act == 1) v = gelu_f(v);
        if (R) v += R[(long)gm*ldr + gn];
        C[coff + (long)gm*ldc + gn] = v;
      }
    }
  }
}

// ---------------- pure-bf16 MFMA GEMM (pipelined, optional split-K)
#define LP 56
__global__ __launch_bounds__(256) void bgemm_kernel(
    const __hip_bfloat16* __restrict__ A, int lda, long sA,
    const __hip_bfloat16* __restrict__ WT, int ldw, long sW,
    const float* __restrict__ bias, int nbias, int bsplit, int bsplitPad, long sB,
    const float* __restrict__ R, int ldr, long sR,
    void* __restrict__ C, int ldc, long sC, int cIsBf16,
    int K, int act,
    float* __restrict__ P, long pz, int splitK)
{
  int z = blockIdx.z / splitK;
  int kc = blockIdx.z - z*splitK;
  const short* Ab = (const short*)A + (long)z*sA;
  const short* Bb = (const short*)WT + (long)z*sW;
  int bm = blockIdx.y*128, bn = blockIdx.x*128;
  int tid = threadIdx.x, lane = tid & 63, wave = tid >> 6;
  int wm = (wave & 1)*64, wn = (wave >> 1)*64;

  __shared__ short As[128*LP];
  __shared__ short Bs[128*LP];

  f32x4 acc[4][4];
  f32x4 zero4 = {0.f,0.f,0.f,0.f};
  #pragma unroll
  for (int i=0;i<4;i++)
    #pragma unroll
    for (int j=0;j<4;j++) acc[i][j] = zero4;

  int g0 = tid, g1 = tid + 256;
  int r0 = g0 >> 2, c0 = (g0 & 3) * 8;
  int r1 = g1 >> 2, c1 = (g1 & 3) * 8;
  int ml = lane & 15, q = lane >> 4;
  long a0base = (long)(bm+r0)*lda + c0;
  long a1base = (long)(bm+r1)*lda + c1;
  long b0base = (long)(bn+r0)*ldw + c0;
  long b1base = (long)(bn+r1)*ldw + c1;

  int Kc = K / splitK;
  int kbeg = kc * Kc, kend = kbeg + Kc;

  short8 av0 = *(const short8*)&Ab[a0base + kbeg];
  short8 av1 = *(const short8*)&Ab[a1base + kbeg];
  short8 bv0 = *(const short8*)&Bb[b0base + kbeg];
  short8 bv1 = *(const short8*)&Bb[b1base + kbeg];

  for (int k0 = kbeg; k0 < kend; k0 += 32){
    __syncthreads();
    *(short8*)&As[r0*LP + c0] = av0;
    *(short8*)&As[r1*LP + c1] = av1;
    *(short8*)&Bs[r0*LP + c0] = bv0;
    *(short8*)&Bs[r1*LP + c1] = bv1;
    __syncthreads();
    if (k0 + 32 < kend){
      av0 = *(const short8*)&Ab[a0base + k0 + 32];
      av1 = *(const short8*)&Ab[a1base + k0 + 32];
      bv0 = *(const short8*)&Bb[b0base + k0 + 32];
      bv1 = *(const short8*)&Bb[b1base + k0 + 32];
    }
    short8 af[4], bfv[4];
    #pragma unroll
    for (int i=0;i<4;i++) af[i]  = *(const short8*)&As[(wm + 16*i + ml)*LP + q*8];
    #pragma unroll
    for (int j=0;j<4;j++) bfv[j] = *(const short8*)&Bs[(wn + 16*j + ml)*LP + q*8];
    #pragma unroll
    for (int i=0;i<4;i++)
      #pragma unroll
      for (int j=0;j<4;j++)
        acc[i][j] = __builtin_amdgcn_mfma_f32_16x16x32_bf16(af[i], bfv[j], acc[i][j], 0,0,0);
  }

  if (P){
    float* Pb = P + (long)blockIdx.z * pz;
    #pragma unroll
    for (int i=0;i<4;i++)
      #pragma unroll
      for (int r=0;r<4;r++){
        int gm = bm + wm + 16*i + q*4 + r;
        #pragma unroll
        for (int j=0;j<4;j++){
          int gn = bn + wn + 16*j + ml;
          Pb[(long)gm*ldc + gn] = acc[i][j][r];
        }
      }
    return;
  }

  const float* biasz = bias ? bias + (long)z*sB : nullptr;
  const float* Rz = R ? R + (long)z*sR : nullptr;
  long coff = (long)z*sC;
  #pragma unroll
  for (int i=0;i<4;i++){
    #pragma unroll
    for (int r=0;r<4;r++){
      int gm = bm + wm + 16*i + q*4 + r;
      #pragma unroll
      for (int j=0;j<4;j++){
        int gn = bn + wn + 16*j + ml;
        float v = acc[i][j][r];
        if (biasz){
          int bi;
          if (bsplit){
            if (gn < bsplit) bi = gn;
            else if (gn >= bsplitPad && gn < bsplitPad + (nbias - bsplit)) bi = gn - (bsplitPad - bsplit);
            else bi = -1;
          } else bi = (gn < nbias) ? gn : -1;
          if (bi >= 0) v += biasz[bi];
        }
        if (act == 2) v = (v > 0.f) ? v : 0.01f*v;
        if (Rz) v += Rz[(long)gm*ldr + gn];
        if (cIsBf16) ((__hip_bfloat16*)C)[coff + (long)gm*ldc + gn] = __float2bfloat16(v);
        else         ((float*)C)[coff + (long)gm*ldc + gn] = v;
      }
    }
  }
}

// ---------------- split-K reduce
__global__ __launch_bounds__(256) void reduce_kernel(
    const float* __restrict__ P, long zStride, int nsplit,
    const float* __restrict__ bias,
    const float* __restrict__ R, float* __restrict__ out,
    int Nmask, int logN, int ldOut, int act, long total)
{
  long idx = (long)blockIdx.x*256 + threadIdx.x;
  if (idx >= total) return;
  long zz = idx / zStride;
  long rem = idx - zz*zStride;
  const float* Pb = P + zz*(long)nsplit*zStride + rem;
  float v = 0.f;
  for (int k=0;k<nsplit;k++) v += Pb[(long)k*zStride];
  int n = (int)(idx & Nmask);
  long row = idx >> logN;
  if (bias) v += bias[n];
  if (act == 1) v = gelu_f(v);
  long o = row*(long)ldOut + n;
  if (R) v += R[o];
  out[o] = v;
}

// ---------------- weight transpose+convert (single bf16 out, z-batched)
__global__ __launch_bounds__(256) void convT_kernel(
    const float* __restrict__ W, int N, int K, long sW,
    __hip_bfloat16* __restrict__ out, int Npad, int Kpad, long sO,
    int split, int splitPad)
{
  int z = blockIdx.z;
  int n0 = blockIdx.x*64, k0 = blockIdx.y*64;
  int tid = threadIdx.x;
  __shared__ float lds[64][65];
  #pragma unroll
  for (int i=0;i<16;i++){
    int e = tid + i*256;
    int kl = e >> 6, c = e & 63;
    int np = n0 + c;
    int ns;
    if (split){
      if (np < split) ns = np;
      else if (np >= splitPad && np < splitPad + (N - split)) ns = np - (splitPad - split);
      else ns = -1;
    } else ns = (np < N) ? np : -1;
    int k = k0 + kl;
    float v = (ns >= 0 && k < K) ? W[(long)z*sW + (long)k*N + ns] : 0.f;
    lds[kl][c] = v;
  }
  __syncthreads();
  #pragma unroll
  for (int i=0;i<16;i++){
    int e = tid + i*256;
    int nl = e >> 6, kl = e & 63;
    out[(long)z*sO + (long)(n0+nl)*Kpad + k0 + kl] = __float2bfloat16(lds[kl][nl]);
  }
}

// ---------------- weight transpose+convert with hi/lo split
__global__ __launch_bounds__(256) void convT2_kernel(
    const float* __restrict__ W, int N, int K,
    __hip_bfloat16* __restrict__ outh, __hip_bfloat16* __restrict__ outl,
    int Npad, int Kpad, int split, int splitPad)
{
  int n0 = blockIdx.x*64, k0 = blockIdx.y*64;
  int tid = threadIdx.x;
  __shared__ float lds[64][65];
  #pragma unroll
  for (int i=0;i<16;i++){
    int e = tid + i*256;
    int kl = e >> 6, c = e & 63;
    int np = n0 + c;
    int ns;
    if (split){
      if (np < split) ns = np;
      else if (np >= splitPad && np < splitPad + (N - split)) ns = np - (splitPad - split);
      else ns = -1;
    } else ns = (np < N) ? np : -1;
    int k = k0 + kl;
    float v = (ns >= 0 && k < K) ? W[(long)k*N + ns] : 0.f;
    lds[kl][c] = v;
  }
  __syncthreads();
  #pragma unroll
  for (int i=0;i<16;i++){
    int e = tid + i*256;
    int nl = e >> 6, kl = e & 63;
    float v = lds[kl][nl];
    __hip_bfloat16 h, l; split2(v, h, l);
    long o = (long)(n0+nl)*Kpad + k0 + kl;
    outh[o] = h; outl[o] = l;
  }
}

// ---------------- bias pack for z-batched QKV
__global__ void pack_bias_kernel(const float* bq, const float* bk, const float* bv, float* out){
  int i = blockIdx.x*256 + threadIdx.x;
  if (i < 256) out[i] = bq[i];
  else if (i < 512) out[i] = bk[i-256];
  else if (i < 768) out[i] = bv[i-512];
}

// ---------------- attention prep: Q (scaled) and K fp32 -> hi/lo bf16
__global__ __launch_bounds__(256) void qksplit_kernel(
    const float* __restrict__ QP,
    __hip_bfloat16* __restrict__ qsh, __hip_bfloat16* __restrict__ qsl,
    __hip_bfloat16* __restrict__ ksh, __hip_bfloat16* __restrict__ ksl)
{
  int idx = blockIdx.x*256 + threadIdx.x;   // 1048576
  float qv = QP[idx] * 0.17677669529663687f;
  __hip_bfloat16 h, l;
  split2(qv, h, l); qsh[idx] = h; qsl[idx] = l;
  float kv = QP[1048576 + idx];
  split2(kv, h, l); ksh[idx] = h; ksl[idx] = l;
}

// ---------------- attention prep: V fp32 [s][256] -> V^T hi/lo [bh][32 d][1024 s]
__global__ __launch_bounds__(256) void vtrans_kernel(
    const float* __restrict__ VP,
    __hip_bfloat16* __restrict__ vth, __hip_bfloat16* __restrict__ vtl)
{
  int bh = blockIdx.y, bb = bh >> 3, h = bh & 7;
  int s0 = blockIdx.x*64;
  int tid = threadIdx.x;
  __shared__ float t[64][33];
  #pragma unroll
  for (int p=0;p<8;p++){
    int sl = (tid>>5) + p*8;
    int d = tid & 31;
    t[sl][d] = VP[((bb<<10)+s0+sl)*256 + h*32 + d];
  }
  __syncthreads();
  #pragma unroll
  for (int p=0;p<8;p++){
    int dl = (tid>>6) + p*4;
    int s = tid & 63;
    float v = t[s][dl];
    __hip_bfloat16 hh, ll; split2(v, hh, ll);
    vth[(bh*32+dl)*1024 + s0 + s] = hh;
    vtl[(bh*32+dl)*1024 + s0 + s] = ll;
  }
}

// ---------------- MFMA flash attention v2: transposed-S softmax + MFMA row-sum
// S^T = K·Q^T so each lane owns one q-column (ml) -> row-max needs only 2 shuffles;
// l accumulated as an extra MFMA C-tile with B = ones (no sum shuffles).
#define KSP 40
__global__ __launch_bounds__(256) void attn_mfma_kernel(
    const __hip_bfloat16* __restrict__ qsh_, const __hip_bfloat16* __restrict__ qsl_,
    const __hip_bfloat16* __restrict__ ksh_, const __hip_bfloat16* __restrict__ ksl_,
    const __hip_bfloat16* __restrict__ vth_, const __hip_bfloat16* __restrict__ vtl_,
    __hip_bfloat16* __restrict__ aoh, __hip_bfloat16* __restrict__ aol)
{
  const short* qsh = (const short*)qsh_; const short* qsl = (const short*)qsl_;
  const short* ksh = (const short*)ksh_; const short* ksl = (const short*)ksl_;
  const short* vth = (const short*)vth_; const short* vtl = (const short*)vtl_;
  int bh = blockIdx.y, bb = bh >> 3, h = bh & 7;
  int tid = threadIdx.x, lane = tid & 63, wave = tid >> 6;
  int ml = lane & 15, quad = lane >> 4;
  int q0 = blockIdx.x*64 + wave*16;

  __shared__ short KhS[32*KSP], KlS[32*KSP], VhS[32*KSP], VlS[32*KSP];
  __shared__ short PhS[4][16*KSP], PlS[4][16*KSP];
  short* Phw = PhS[wave]; short* Plw = PlS[wave];

  int qrow = (bb<<10) + q0 + ml;
  short8 qfh = *(const short8*)&qsh[qrow*256 + h*32 + quad*8];
  short8 qfl = *(const short8*)&qsl[qrow*256 + h*32 + quad*8];

  short8 ones;
  #pragma unroll
  for (int i=0;i<8;i++) ones[i] = (short)0x3F80;   // bf16 1.0

  f32x4 O0 = {0.f,0.f,0.f,0.f}, O1 = {0.f,0.f,0.f,0.f};
  f32x4 Lacc = {0.f,0.f,0.f,0.f};
  float m_s = -INFINITY;   // running max for q = ml (replicated across quads)

  int sr = tid >> 3, sc = (tid & 7)*4;
  for (int k0 = 0; k0 < 1024; k0 += 32){
    int krow = (bb<<10) + k0 + sr;
    short4v kvh = *(const short4v*)&ksh[krow*256 + h*32 + sc];
    short4v kvl = *(const short4v*)&ksl[krow*256 + h*32 + sc];
    short4v vvh = *(const short4v*)&vth[(bh*32+sr)*1024 + k0 + sc];
    short4v vvl = *(const short4v*)&vtl[(bh*32+sr)*1024 + k0 + sc];
    __syncthreads();
    *(short4v*)&KhS[sr*KSP + sc] = kvh;
    *(short4v*)&KlS[sr*KSP + sc] = kvl;
    *(short4v*)&VhS[sr*KSP + sc] = vvh;
    *(short4v*)&VlS[sr*KSP + sc] = vvl;
    __syncthreads();
    // ---- S^T = K·Q^T : rows = keys, cols = q. A = K fragments, B = Q fragment.
    short8 kb0h = *(const short8*)&KhS[ml*KSP + quad*8];
    short8 kb0l = *(const short8*)&KlS[ml*KSP + quad*8];
    short8 kb1h = *(const short8*)&KhS[(16+ml)*KSP + quad*8];
    short8 kb1l = *(const short8*)&KlS[(16+ml)*KSP + quad*8];
    f32x4 S0 = {0.f,0.f,0.f,0.f}, S1 = {0.f,0.f,0.f,0.f};
    S0 = __builtin_amdgcn_mfma_f32_16x16x32_bf16(kb0l, qfh, S0, 0,0,0);
    S0 = __builtin_amdgcn_mfma_f32_16x16x32_bf16(kb0h, qfl, S0, 0,0,0);
    S0 = __builtin_amdgcn_mfma_f32_16x16x32_bf16(kb0h, qfh, S0, 0,0,0);
    S1 = __builtin_amdgcn_mfma_f32_16x16x32_bf16(kb1l, qfh, S1, 0,0,0);
    S1 = __builtin_amdgcn_mfma_f32_16x16x32_bf16(kb1h, qfl, S1, 0,0,0);
    S1 = __builtin_amdgcn_mfma_f32_16x16x32_bf16(kb1h, qfh, S1, 0,0,0);
    // ---- per-q (lane-owned) online softmax: lane holds 8 key-scores for q=ml
    float tm = fmaxf(fmaxf(fmaxf(S0[0],S0[1]), fmaxf(S0[2],S0[3])),
                     fmaxf(fmaxf(S1[0],S1[1]), fmaxf(S1[2],S1[3])));
    tm = fmaxf(tm, __shfl_xor(tm, 16, 64));
    tm = fmaxf(tm, __shfl_xor(tm, 32, 64));
    float nm = fmaxf(m_s, tm);
    float alpha = expf(m_s - nm);
    m_s = nm;
    #pragma unroll
    for (int r=0;r<4;r++){
      float p0 = expf(S0[r] - nm);   // key = quad*4+r
      float p1 = expf(S1[r] - nm);   // key = 16+quad*4+r
      short sh, sl2;
      split2s(p0, sh, sl2);
      Phw[ml*KSP + quad*4 + r] = sh;       Plw[ml*KSP + quad*4 + r] = sl2;
      split2s(p1, sh, sl2);
      Phw[ml*KSP + 16 + quad*4 + r] = sh;  Plw[ml*KSP + 16 + quad*4 + r] = sl2;
    }
    // ---- rescale O/L with per-row alpha (broadcast from lane ml = row)
    #pragma unroll
    for (int r=0;r<4;r++){
      float ar = __shfl(alpha, quad*4 + r, 16);
      O0[r] *= ar; O1[r] *= ar; Lacc[r] *= ar;
    }
    // ---- PV: A = P (A-layout from LDS), B = V^T fragments
    short8 pAh = *(const short8*)&Phw[ml*KSP + quad*8];
    short8 pAl = *(const short8*)&Plw[ml*KSP + quad*8];
    short8 vb0h = *(const short8*)&VhS[ml*KSP + quad*8];
    short8 vb0l = *(const short8*)&VlS[ml*KSP + quad*8];
    short8 vb1h = *(const short8*)&VhS[(16+ml)*KSP + quad*8];
    short8 vb1l = *(const short8*)&VlS[(16+ml)*KSP + quad*8];
    O0 = __builtin_amdgcn_mfma_f32_16x16x32_bf16(pAl, vb0h, O0, 0,0,0);
    O0 = __builtin_amdgcn_mfma_f32_16x16x32_bf16(pAh, vb0l, O0, 0,0,0);
    O0 = __builtin_amdgcn_mfma_f32_16x16x32_bf16(pAh, vb0h, O0, 0,0,0);
    O1 = __builtin_amdgcn_mfma_f32_16x16x32_bf16(pAl, vb1h, O1, 0,0,0);
    O1 = __builtin_amdgcn_mfma_f32_16x16x32_bf16(pAh, vb1l, O1, 0,0,0);
    O1 = __builtin_amdgcn_mfma_f32_16x16x32_bf16(pAh, vb1h, O1, 0,0,0);
    // ---- L += P·1 (row-sum via MFMA; every lane gets its rows' sums)
    Lacc = __builtin_amdgcn_mfma_f32_16x16x32_bf16(pAh, ones, Lacc, 0,0,0);
    Lacc = __builtin_amdgcn_mfma_f32_16x16x32_bf16(pAl, ones, Lacc, 0,0,0);
  }
  #pragma unroll
  for (int r=0;r<4;r++){
    float inv = 1.f / Lacc[r];
    int row = (bb<<10) + q0 + quad*4 + r;
    __hip_bfloat16 hh, ll;
    split2(O0[r]*inv, hh, ll);
    aoh[row*256 + h*32 + ml] = hh;       aol[row*256 + h*32 + ml] = ll;
    split2(O1[r]*inv, hh, ll);
    aoh[row*256 + h*32 + 16 + ml] = hh;  aol[row*256 + h*32 + 16 + ml] = ll;
  }
}

// ---------------- concat queries into x[:, 256:512]
__global__ __launch_bounds__(256) void concat_kernel(
    const float* __restrict__ queries, float* __restrict__ x)
{
  int idx = blockIdx.x*256 + threadIdx.x;
  int d = idx & 255; int r = idx >> 8;
  x[(r<<9) + 256 + d] = queries[idx];
}

// ---------------- rmsnorm fp32 out
__global__ __launch_bounds__(256) void rmsnorm_kernel(
    const float* __restrict__ x, const float* __restrict__ g, float* __restrict__ y)
{
  int r = blockIdx.x; int tid = threadIdx.x;
  float v0 = x[(r<<9) + tid];
  float v1 = x[(r<<9) + 256 + tid];
  float ss = v0*v0 + v1*v1;
  #pragma unroll
  for (int off=32; off>0; off>>=1) ss += __shfl_down(ss, off, 64);
  __shared__ float wsum[4];
  if ((tid & 63) == 0) wsum[tid>>6] = ss;
  __syncthreads();
  float tot = wsum[0]+wsum[1]+wsum[2]+wsum[3];
  float scale = 22.62741699796952f / fmaxf(sqrtf(tot), 1e-12f);
  y[(r<<9) + tid]       = v0*scale*g[tid];
  y[(r<<9) + 256 + tid] = v1*scale*g[256+tid];
}

// ---------------- rmsnorm hi/lo out
__global__ __launch_bounds__(256) void rmsnorm_split_kernel(
    const float* __restrict__ x, const float* __restrict__ g,
    __hip_bfloat16* __restrict__ yh, __hip_bfloat16* __restrict__ yl)
{
  int r = blockIdx.x; int tid = threadIdx.x;
  float v0 = x[(r<<9) + tid];
  float v1 = x[(r<<9) + 256 + tid];
  float ss = v0*v0 + v1*v1;
  #pragma unroll
  for (int off=32; off>0; off>>=1) ss += __shfl_down(ss, off, 64);
  __shared__ float wsum[4];
  if ((tid & 63) == 0) wsum[tid>>6] = ss;
  __syncthreads();
  float tot = wsum[0]+wsum[1]+wsum[2]+wsum[3];
  float scale = 22.62741699796952f / fmaxf(sqrtf(tot), 1e-12f);
  float a = v0*scale*g[tid];
  float b = v1*scale*g[256+tid];
  __hip_bfloat16 h, l;
  split2(a, h, l); yh[(r<<9)+tid] = h;     yl[(r<<9)+tid] = l;
  split2(b, h, l); yh[(r<<9)+256+tid] = h; yl[(r<<9)+256+tid] = l;
}

// ---------------- rmsnorm bf16 out (ffa path)
__global__ __launch_bounds__(256) void rmsnorm_bf_kernel(
    const float* __restrict__ x, const float* __restrict__ g, __hip_bfloat16* __restrict__ y)
{
  int r = blockIdx.x; int tid = threadIdx.x;
  float v0 = x[(r<<9) + tid];
  float v1 = x[(r<<9) + 256 + tid];
  float ss = v0*v0 + v1*v1;
  #pragma unroll
  for (int off=32; off>0; off>>=1) ss += __shfl_down(ss, off, 64);
  __shared__ float wsum[4];
  if ((tid & 63) == 0) wsum[tid>>6] = ss;
  __syncthreads();
  float tot = wsum[0]+wsum[1]+wsum[2]+wsum[3];
  float scale = 22.62741699796952f / fmaxf(sqrtf(tot), 1e-12f);
  y[(r<<9) + tid]       = __float2bfloat16(v0*scale*g[tid]);
  y[(r<<9) + 256 + tid] = __float2bfloat16(v1*scale*g[256+tid]);
}

// ---------------- geglu glu: H fp32 padded [4096][2816] -> T hi/lo [4096][1408]
__global__ __launch_bounds__(256) void glu_split_kernel(
    const float* __restrict__ h, const float* __restrict__ mult,
    __hip_bfloat16* __restrict__ th, __hip_bfloat16* __restrict__ tl)
{
  int idx = blockIdx.x*256 + threadIdx.x;
  int r = idx / 1408; int j = idx - r*1408;
  float v = 0.f;
  if (j < 1365){
    float a  = h[(long)r*2816 + j];
    float gt = h[(long)r*2816 + 1408 + j];
    v = gelu_f(gt) * a * mult[j];
  }
  __hip_bfloat16 hh, ll; split2(v, hh, ll);
  th[idx] = hh; tl[idx] = ll;
}

// ---------------- geglu glu bf16 (ffa path)
__global__ __launch_bounds__(256) void glu_bf_kernel(
    const __hip_bfloat16* __restrict__ h, const float* __restrict__ mult,
    __hip_bfloat16* __restrict__ t)
{
  int idx = blockIdx.x*256 + threadIdx.x;
  int r = idx / 1408; int j = idx - r*1408;
  float v = 0.f;
  if (j < 1365){
    float a  = __bfloat162float(h[(long)r*2816 + j]);
    float gt = __bfloat162float(h[(long)r*2816 + 1408 + j]);
    v = gelu_f(gt) * a * mult[j];
  }
  t[idx] = __float2bfloat16(v);
}

// ---------------- split fp32 -> hi/lo
__global__ __launch_bounds__(256) void split32_kernel(
    const float* __restrict__ x, __hip_bfloat16* __restrict__ h, __hip_bfloat16* __restrict__ l)
{
  int idx = blockIdx.x*256 + threadIdx.x;
  float v = x[idx];
  __hip_bfloat16 hh, ll; split2(v, hh, ll);
  h[idx] = hh; l[idx] = ll;
}

// ---------------- MoE init
__global__ void moe_init_kernel(float* sum_raw, float* z_sum)
{
  int i = threadIdx.x;
  if (i < 64) sum_raw[i] = 0.f;
  if (i == 0) *z_sum = 0.f;
}

// ---------------- gating
__global__ __launch_bounds__(256) void gating_kernel(
    const float* __restrict__ xn, const float* __restrict__ gate_w,
    int* __restrict__ idx1, int* __restrict__ idx2, int* __restrict__ route,
    float* __restrict__ gg1, float* __restrict__ gg2,
    float* __restrict__ sum_raw, float* __restrict__ z_sum)
{
  int t = blockIdx.x; int tid = threadIdx.x;
  __shared__ float xrow[512];
  xrow[tid]     = xn[(t<<9)+tid];
  xrow[256+tid] = xn[(t<<9)+256+tid];
  __syncthreads();
  int e = tid >> 4, l16 = tid & 15;
  float p = 0.f;
  for (int d=l16; d<512; d+=16) p += xrow[d]*gate_w[(e<<9)+d];
  __shared__ float part[16][17];
  part[e][l16] = p;
  __syncthreads();
  __shared__ float raw[16];
  if (tid < 16){
    float s = 0.f;
    #pragma unroll
    for (int i=0;i<16;i++) s += part[tid][i];
    raw[tid] = s;
  }
  __syncthreads();
  if (tid == 0){
    float mx = -1e30f;
    #pragma unroll
    for (int i=0;i<16;i++) mx = fmaxf(mx, raw[i]);
    float r[16]; float sum = 0.f;
    #pragma unroll
    for (int i=0;i<16;i++){ r[i] = expf(raw[i]-mx); sum += r[i]; }
    float lse = mx + logf(sum);
    atomicAdd(z_sum, lse*lse);
    float inv = 1.f/sum;
    #pragma unroll
    for (int i=0;i<16;i++){ r[i] *= inv; raw[i] = r[i]; }
    int i1 = -1; float b1 = -1.f;
    #pragma unroll
    for (int i=0;i<16;i++) if (r[i] > b1){ b1 = r[i]; i1 = i; }
    int i2 = -1; float b2 = -1.f;
    #pragma unroll
    for (int i=0;i<16;i++) if (i != i1 && r[i] > b2){ b2 = r[i]; i2 = i; }
    float s2 = fmaxf(b1 + b2, 1e-9f);
    float g1n = b1/s2, g2n = b2/s2;
    idx1[t] = i1; idx2[t] = i2;
    route[t] = (g2n > 0.2f) ? 1 : 0;
    gg1[t] = g1n; gg2[t] = g2n;
  }
  __syncthreads();
  int bb = t >> 10;
  if (tid < 16) atomicAdd(&sum_raw[(bb<<4)+tid], raw[tid]);
}

// ---------------- capacity assignment: parallel segmented prefix scan
__global__ __launch_bounds__(256) void scan_kernel(
    const int* __restrict__ idx1, const int* __restrict__ idx2, const int* __restrict__ route,
    int* __restrict__ ts1, int* __restrict__ ts2, int* __restrict__ slot_token,
    int* __restrict__ count1)
{
  int bb = blockIdx.x >> 4;
  int e  = blockIdx.x & 15;
  int tid = threadIdx.x;
  int tbase = (bb<<10) + tid*4;
  int4 i1 = *(const int4*)&idx1[tbase];
  int4 i2 = *(const int4*)&idx2[tbase];
  int4 rt = *(const int4*)&route[tbase];
  int m1[4] = { i1.x==e, i1.y==e, i1.z==e, i1.w==e };
  int m2[4] = { i2.x==e, i2.y==e, i2.z==e, i2.w==e };
  int r4[4] = { rt.x, rt.y, rt.z, rt.w };
  int c1 = m1[0]+m1[1]+m1[2]+m1[3];
  int c2 = (m2[0]&&r4[0]) + (m2[1]&&r4[1]) + (m2[2]&&r4[2]) + (m2[3]&&r4[3]);
  __shared__ int s1[256], s2v[256];
  s1[tid] = c1; s2v[tid] = c2;
  __syncthreads();
  for (int off=1; off<256; off<<=1){
    int v1 = (tid>=off) ? s1[tid-off] : 0;
    int v2 = (tid>=off) ? s2v[tid-off] : 0;
    __syncthreads();
    s1[tid] += v1; s2v[tid] += v2;
    __syncthreads();
  }
  int tot1 = s1[255], tot2 = s2v[255];
  int p1 = s1[tid] - c1;
  int p2 = s2v[tid] - c2;
  if (tid == 0) count1[(bb<<4)+e] = tot1;
  int base = ((e<<2)+bb)*CAPN;
  #pragma unroll
  for (int i=0;i<4;i++){
    int t = tbase + i;
    if (m1[i]){
      if (p1 < CAPN){ ts1[t] = base+p1; slot_token[base+p1] = t; }
      else ts1[t] = -1;
      p1++;
    }
    if (m2[i]){
      if (r4[i]){
        int pos = tot1 + p2;
        if (pos < CAPN){ ts2[t] = base+pos; slot_token[base+pos] = t; }
        else ts2[t] = -1;
        p2++;
      } else ts2[t] = -1;
    }
  }
  int filled = min(CAPN, tot1 + tot2);
  if (tid < CAPN && tid >= filled) slot_token[base+tid] = -1;
}

// ---------------- gather + layernorm -> xin bf16
__global__ __launch_bounds__(256) void gather_ln_kernel(
    const float* __restrict__ xn, const int* __restrict__ slot_token,
    const float* __restrict__ ln_g, const float* __restrict__ ln_b,
    __hip_bfloat16* __restrict__ xin)
{
  int s = blockIdx.x; int tid = threadIdx.x;
  int t = slot_token[s];
  int e = s >> 9;
  if (t < 0){
    xin[(s<<9)+tid] = __float2bfloat16(0.f);
    xin[(s<<9)+256+tid] = __float2bfloat16(0.f);
    return;
  }
  float v0 = xn[(t<<9)+tid];
  float v1 = xn[(t<<9)+256+tid];
  float sm = v0+v1, sq = v0*v0+v1*v1;
  #pragma unroll
  for (int off=32; off>0; off>>=1){
    sm += __shfl_down(sm, off, 64);
    sq += __shfl_down(sq, off, 64);
  }
  __shared__ float s1[4], s2buf[4];
  if ((tid & 63) == 0){ s1[tid>>6] = sm; s2buf[tid>>6] = sq; }
  __syncthreads();
  float tsm = s1[0]+s1[1]+s1[2]+s1[3];
  float tsq = s2buf[0]+s2buf[1]+s2buf[2]+s2buf[3];
  float mean = tsm * (1.f/512.f);
  float var = tsq * (1.f/512.f) - mean*mean;
  float rstd = rsqrtf(var + 1e-5f);
  xin[(s<<9)+tid]     = __float2bfloat16((v0-mean)*rstd*ln_g[(e<<9)+tid]     + ln_b[(e<<9)+tid]);
  xin[(s<<9)+256+tid] = __float2bfloat16((v1-mean)*rstd*ln_g[(e<<9)+256+tid] + ln_b[(e<<9)+256+tid]);
}

// ---------------- combine (in-place)
__global__ __launch_bounds__(256) void combine_kernel(
    float* __restrict__ x, const float* __restrict__ h2,
    const int* __restrict__ ts1, const int* __restrict__ ts2,
    const float* __restrict__ gg1, const float* __restrict__ gg2)
{
  int idx = blockIdx.x*256 + threadIdx.x;
  int t = idx >> 9; int d = idx & 511;
  float v = x[idx];
  int s1 = ts1[t]; if (s1 >= 0) v += gg1[t]*h2[(s1<<9)+d];
  int s2 = ts2[t]; if (s2 >= 0) v += gg2[t]*h2[(s2<<9)+d];
  x[idx] = v;
}

// ---------------- aux losses
__global__ void aux_kernel(
    const float* __restrict__ sum_raw, const int* __restrict__ count1,
    const float* __restrict__ z_sum, float* __restrict__ out)
{
  int tid = threadIdx.x;
  float v = (sum_raw[tid] * (1.f/1024.f)) * ((float)count1[tid] * (1.f/1024.f));
  #pragma unroll
  for (int off=32; off>0; off>>=1) v += __shfl_down(v, off, 64);
  if (tid == 0){
    float bal = v * (1.f/64.f) * 256.f * 0.01f;
    float zl = (*z_sum) * (1.f/4096.f) * 0.001f;
    out[0] = bal + zl;
    out[1] = bal;
    out[2] = zl;
  }
}

extern "C" void kernel_launch(void* const* d_in, const int* in_sizes, int n_in,
                              void* d_out, int out_size, void* d_ws, size_t ws_size,
                              hipStream_t stream)
{
  const float* K_in   = (const float*)d_in[0];
  const float* V_in   = (const float*)d_in[1];
  const float* Q_in   = (const float*)d_in[2];
  const float* w_topo = (const float*)d_in[3];
  const float* b_topo = (const float*)d_in[4];
  const float* w_val  = (const float*)d_in[5];
  const float* b_val  = (const float*)d_in[6];
  const float* wq     = (const float*)d_in[7];
  const float* bq     = (const float*)d_in[8];
  const float* wk     = (const float*)d_in[9];
  const float* bk     = (const float*)d_in[10];
  const float* wv     = (const float*)d_in[11];
  const float* bv     = (const float*)d_in[12];
  const float* wo     = (const float*)d_in[13];
  const float* bo     = (const float*)d_in[14];
  const float* ffb_g  = (const float*)d_in[15];
  const float* ffb_w1 = (const float*)d_in[16];
  const float* ffb_b1 = (const float*)d_in[17];
  const float* ffb_mult=(const float*)d_in[18];
  const float* ffb_w2 = (const float*)d_in[19];
  const float* ffb_b2 = (const float*)d_in[20];
  const float* prenorm_g=(const float*)d_in[21];
  const float* gate_w = (const float*)d_in[22];
  const float* exp_ln_g=(const float*)d_in[23];
  const float* exp_ln_b=(const float*)d_in[24];
  const float* exp_w1 = (const float*)d_in[25];
  const float* exp_b1 = (const float*)d_in[26];
  const float* exp_w2 = (const float*)d_in[27];
  const float* exp_b2 = (const float*)d_in[28];
  const float* ffa_g  = (const float*)d_in[29];
  const float* ffa_w1 = (const float*)d_in[30];
  const float* ffa_b1 = (const float*)d_in[31];
  const float* ffa_mult=(const float*)d_in[32];
  const float* ffa_w2 = (const float*)d_in[33];
  const float* ffa_b2 = (const float*)d_in[34];
  const float* w_out  = (const float*)d_in[35];
  const float* b_out  = (const float*)d_in[36];
  float* dout = (float*)d_out;

  float* wsf = (float*)d_ws;
  int*   wsi = (int*)d_ws;

  // ---- layout (float offsets) ----
  const size_t A0 = 0;
  const size_t B0 = 11534336;
  const size_t OXA = 17301504;
  const size_t OXB = 19398656;
  const size_t OWP = 21495808;
  const size_t OMI = 21889024;

  __hip_bfloat16* qhi = (__hip_bfloat16*)(wsf + A0);
  __hip_bfloat16* khi = (__hip_bfloat16*)(wsf + A0 + 524288);
  __hip_bfloat16* vhi = (__hip_bfloat16*)(wsf + A0 + 1048576);
  __hip_bfloat16* qlo = (__hip_bfloat16*)(wsf + A0 + 1572864);
  __hip_bfloat16* klo = (__hip_bfloat16*)(wsf + A0 + 2097152);
  __hip_bfloat16* vlo = (__hip_bfloat16*)(wsf + A0 + 2621440);
  float* QP = wsf + A0 + 3145728;
  __hip_bfloat16* aohi = (__hip_bfloat16*)(wsf + A0 + 6291456);
  __hip_bfloat16* aolo = (__hip_bfloat16*)(wsf + A0 + 6815744);
  __hip_bfloat16* qsh = (__hip_bfloat16*)(wsf + A0);
  __hip_bfloat16* qsl = (__hip_bfloat16*)(wsf + A0 + 524288);
  __hip_bfloat16* ksh = (__hip_bfloat16*)(wsf + A0 + 1048576);
  __hip_bfloat16* ksl = (__hip_bfloat16*)(wsf + A0 + 1572864);
  __hip_bfloat16* vth = (__hip_bfloat16*)(wsf + A0 + 2097152);
  __hip_bfloat16* vtl = (__hip_bfloat16*)(wsf + A0 + 2621440);
  float* QF = wsf + B0 + 262144;
  float* Hb = wsf + A0;
  __hip_bfloat16* yh   = (__hip_bfloat16*)(wsf + B0);
  __hip_bfloat16* yl   = (__hip_bfloat16*)(wsf + B0 + 1048576);
  __hip_bfloat16* fw1h = (__hip_bfloat16*)(wsf + B0 + 2097152);
  __hip_bfloat16* fw1l = fw1h + 1441792;
  __hip_bfloat16* th   = (__hip_bfloat16*)(wsf + B0);
  __hip_bfloat16* tl   = (__hip_bfloat16*)(wsf + B0 + 2883584);
  __hip_bfloat16* fw2h = (__hip_bfloat16*)(wsf + A0);
  __hip_bfloat16* fw2l = fw2h + 720896;
  float* Pffb = wsf + A0 + 1048576;
  __hip_bfloat16* wte   = (__hip_bfloat16*)(wsf + A0);
  __hip_bfloat16* xin_bf= (__hip_bfloat16*)(wsf + A0 + 5767168);
  __hip_bfloat16* h1_bf = (__hip_bfloat16*)(wsf + A0 + 7864320);
  float* H2 = wsf + 13631488;
  float* YM = wsf + B0;
  __hip_bfloat16* y_bf = (__hip_bfloat16*)(wsf + A0);
  __hip_bfloat16* wf1  = (__hip_bfloat16*)(wsf + A0 + 1048576);
  __hip_bfloat16* h_bf = (__hip_bfloat16*)(wsf + A0 + 1769472);
  __hip_bfloat16* t_bf = (__hip_bfloat16*)(wsf + A0 + 7536640);
  __hip_bfloat16* wf2  = (__hip_bfloat16*)(wsf + A0 + 10420224);
  float* Pffa = wsf + B0;
  __hip_bfloat16* xah = (__hip_bfloat16*)(wsf + A0);
  __hip_bfloat16* xal = (__hip_bfloat16*)(wsf + A0 + 1048576);
  float* Pout = wsf + A0 + 2097152;
  __hip_bfloat16* wp = (__hip_bfloat16*)(wsf + OWP);
  __hip_bfloat16* wqh = wp;            __hip_bfloat16* wkh = wp + 65536;
  __hip_bfloat16* wvh = wp + 131072;   __hip_bfloat16* wql = wp + 196608;
  __hip_bfloat16* wkl = wp + 262144;   __hip_bfloat16* wvl = wp + 327680;
  __hip_bfloat16* woh = wp + 393216;   __hip_bfloat16* wol = wp + 458752;
  __hip_bfloat16* wouth = wp + 524288; __hip_bfloat16* woutl = wp + 655360;

  int* idx1 = wsi + OMI + 0;
  int* idx2 = wsi + OMI + 4096;
  int* route= wsi + OMI + 8192;
  int* ts1  = wsi + OMI + 12288;
  int* ts2  = wsi + OMI + 16384;
  int* slot_token = wsi + OMI + 20480;
  int* count1     = wsi + OMI + 28672;
  float* sum_raw  = wsf + OMI + 28736;
  float* z_sum    = wsf + OMI + 28800;
  float* gg1      = wsf + OMI + 28864;
  float* gg2      = wsf + OMI + 32960;
  float* bias_qkv = wsf + OMI + 37056;

  // ---- phase 0: static weight conversions ----
  convT2_kernel<<<dim3(4,4),  256, 0, stream>>>(wq, 256, 256, wqh, wql, 256, 256, 0, 0);
  convT2_kernel<<<dim3(4,4),  256, 0, stream>>>(wk, 256, 256, wkh, wkl, 256, 256, 0, 0);
  convT2_kernel<<<dim3(4,4),  256, 0, stream>>>(wv, 256, 256, wvh, wvl, 256, 256, 0, 0);
  convT2_kernel<<<dim3(4,4),  256, 0, stream>>>(wo, 256, 256, woh, wol, 256, 256, 0, 0);
  convT2_kernel<<<dim3(4,8),  256, 0, stream>>>(w_out, 256, 512, wouth, woutl, 256, 512, 0, 0);
  convT2_kernel<<<dim3(44,8), 256, 0, stream>>>(ffb_w1, 2730, 512, fw1h, fw1l, 2816, 512, 1365, 1408);
  pack_bias_kernel<<<3, 256, 0, stream>>>(bq, bk, bv, bias_qkv);

  // ---- phase 1: topo / values ----
  topo_kernel<<<8192, 256, 0, stream>>>(K_in, Q_in, w_topo, b_topo, khi, klo, qhi, qlo, QF);
  values_kernel<<<4096, 256, 0, stream>>>(V_in, w_val, b_val, vhi, vlo);

  // ---- phase 2: QKV projections ----
  sgemm_kernel<<<dim3(2,32,3), 256, 0, stream>>>(
      qhi, qlo, 256, 1048576, wqh, wql, 256, 65536,
      bias_qkv, 256, 0, 0, 256, nullptr, 0, QP, 256, 1048576, 256, 0,
      nullptr, 0, 1);

  // ---- phase 3: MFMA flash attention ----
  qksplit_kernel<<<4096, 256, 0, stream>>>(QP, qsh, qsl, ksh, ksl);
  vtrans_kernel<<<dim3(16,32), 256, 0, stream>>>(QP + 2097152, vth, vtl);
  attn_mfma_kernel<<<dim3(16,32), 256, 0, stream>>>(qsh, qsl, ksh, ksl, vth, vtl, aohi, aolo);

  // ---- phase 4: o-proj + concat ----
  sgemm_kernel<<<dim3(2,32,1), 256, 0, stream>>>(
      aohi, aolo, 256, 0, woh, wol, 256, 0,
      bo, 256, 0, 0, 0, nullptr, 0, wsf+OXA, 512, 0, 256, 0,
      nullptr, 0, 1);
  concat_kernel<<<4096, 256, 0, stream>>>(QF, wsf+OXA);

  // ---- phase 5: ffb geglu ----
  rmsnorm_split_kernel<<<4096, 256, 0, stream>>>(wsf+OXA, ffb_g, yh, yl);
  sgemm_kernel<<<dim3(22,32,1), 256, 0, stream>>>(
      yh, yl, 512, 0, fw1h, fw1l, 512, 0,
      ffb_b1, 2730, 1365, 1408, 0, nullptr, 0, Hb, 2816, 0, 512, 0,
      nullptr, 0, 1);
  glu_split_kernel<<<22528, 256, 0, stream>>>(Hb, ffb_mult, th, tl);
  convT2_kernel<<<dim3(8,22), 256, 0, stream>>>(ffb_w2, 512, 1365, fw2h, fw2l, 512, 1408, 0, 0);
  sgemm_kernel<<<dim3(4,32,4), 256, 0, stream>>>(
      th, tl, 1408, 0, fw2h, fw2l, 1408, 0,
      nullptr, 0, 0, 0, 0, nullptr, 0, nullptr, 512, 0, 1408, 0,
      Pffb, 2097152, 4);
  reduce_kernel<<<8192, 256, 0, stream>>>(
      Pffb, 2097152, 4, ffb_b2, wsf+OXA, wsf+OXB, 511, 9, 512, 0, 2097152);

  // ---- phase 6: MoE ----
  rmsnorm_kernel<<<4096, 256, 0, stream>>>(wsf+OXB, prenorm_g, YM);
  moe_init_kernel<<<1, 64, 0, stream>>>(sum_raw, z_sum);
  gating_kernel<<<4096, 256, 0, stream>>>(YM, gate_w, idx1, idx2, route, gg1, gg2, sum_raw, z_sum);
  scan_kernel<<<64, 256, 0, stream>>>(idx1, idx2, route, ts1, ts2, slot_token, count1);
  gather_ln_kernel<<<8192, 256, 0, stream>>>(YM, slot_token, exp_ln_g, exp_ln_b, xin_bf);
  convT_kernel<<<dim3(22, 8, 16), 256, 0, stream>>>(exp_w1, 1365, 512, (long)512*1365,
                                                    wte, 1408, 512, (long)1408*512, 0, 0);
  bgemm_kernel<<<dim3(11,4,16), 256, 0, stream>>>(
      xin_bf, 512, (long)512*512, wte, 512, (long)1408*512,
      exp_b1, 1365, 0, 0, 1365, nullptr, 0, 0,
      h1_bf, 1408, (long)512*1408, 1, 512, 2,
      nullptr, 0, 1);
  convT_kernel<<<dim3(8, 22, 16), 256, 0, stream>>>(exp_w2, 512, 1365, (long)1365*512,
                                                    wte, 512, 1408, (long)512*1408, 0, 0);
  bgemm_kernel<<<dim3(4,4,16), 256, 0, stream>>>(
      h1_bf, 1408, (long)512*1408, wte, 1408, (long)512*1408,
      exp_b2, 512, 0, 0, 512, nullptr, 0, 0,
      H2, 512, (long)512*512, 0, 1408, 0,
      nullptr, 0, 1);
  combine_kernel<<<8192, 256, 0, stream>>>(wsf+OXB, H2, ts1, ts2, gg1, gg2);
  aux_kernel<<<1, 64, 0, stream>>>(sum_raw, count1, z_sum, dout + 4096*256);

  // ---- phase 7: ffa geglu ----
  rmsnorm_bf_kernel<<<4096, 256, 0, stream>>>(wsf+OXB, ffa_g, y_bf);
  convT_kernel<<<dim3(44, 8, 1), 256, 0, stream>>>(ffa_w1, 2730, 512, 0,
                                                   wf1, 2816, 512, 0, 1365, 1408);
  bgemm_kernel<<<dim3(22,32,1), 256, 0, stream>>>(
      y_bf, 512, 0, wf1, 512, 0,
      ffa_b1, 2730, 1365, 1408, 0, nullptr, 0, 0,
      h_bf, 2816, 0, 1, 512, 0,
      nullptr, 0, 1);
  glu_bf_kernel<<<22528, 256, 0, stream>>>(h_bf, ffa_mult, t_bf);
  convT_kernel<<<dim3(8, 22, 1), 256, 0, stream>>>(ffa_w2, 512, 1365, 0,
                                                   wf2, 512, 1408, 0, 0, 0);
  bgemm_kernel<<<dim3(4,32,2), 256, 0, stream>>>(
      t_bf, 1408, 0, wf2, 1408, 0,
      nullptr, 0, 0, 0, 0, nullptr, 0, 0,
      nullptr, 512, 0, 0, 1408, 0,
      Pffa, 2097152, 2);
  reduce_kernel<<<8192, 256, 0, stream>>>(
      Pffa, 2097152, 2, ffa_b2, wsf+OXB, wsf+OXA, 511, 9, 512, 0, 2097152);

  // ---- phase 8: out = gelu(XA @ w_out + b_out), split-K=4 ----
  split32_kernel<<<8192, 256, 0, stream>>>(wsf+OXA, xah, xal);
  sgemm_kernel<<<dim3(2,32,4), 256, 0, stream>>>(
      xah, xal, 512, 0, wouth, woutl, 512, 0,
      nullptr, 0, 0, 0, 0, nullptr, 0, nullptr, 256, 0, 512, 0,
      Pout, 1048576, 4);
  reduce_kernel<<<4096, 256, 0, stream>>>(
      Pout, 1048576, 4, b_out, nullptr, dout, 255, 8, 256, 1, 1048576);
}